// Round 2
// baseline (4471.354 us; speedup 1.0000x reference)
//
#include <hip/hip_runtime.h>
#include <hip/hip_bf16.h>

typedef unsigned short ushort_t;

// ---------------- constants ----------------
#define N_AC 40000
#define N_W  20000
#define D_IN 128
#define NH   4
#define HD   256   // NH*DH
#define DOUT 64
#define E_TIC 400000
#define E_W   200000
#define E_REL 400000
#define NEG 0.2f

__device__ __forceinline__ float bf2f(ushort_t u) {
    return __uint_as_float(((unsigned int)u) << 16);
}
__device__ __forceinline__ ushort_t f2bf(float v) {
    unsigned u = __float_as_uint(v);
    unsigned r = (u + 0x7fffu + ((u >> 16) & 1u)) >> 16;
    return (ushort_t)r;
}
// flag-branched float load: f==1 -> f32 source, f==0 -> bf16 source
__device__ __forceinline__ float ldf(const void* p, size_t i, int f) {
    return f ? ((const float*)p)[i] : bf2f(((const ushort_t*)p)[i]);
}

// ---------------- dtype autodetect ----------------
// bf16 N(0,1)-ish data: |v| <= ~6. f32 misread as bf16: even ushorts carry
// random exponent bits -> |v|>1e4 or NaN with ~44% probability each.
__global__ void detect_dtype(const ushort_t* __restrict__ x, int* __restrict__ flag) {
    __shared__ int hit;
    if (threadIdx.x == 0) hit = 0;
    __syncthreads();
    for (int i = threadIdx.x; i < 4096; i += 256) {
        float v = bf2f(x[i]);
        if (!(fabsf(v) <= 1e4f)) atomicOr(&hit, 1);   // catches huge AND NaN
    }
    __syncthreads();
    if (threadIdx.x == 0) flag[0] = hit ? 1 : 0;
}

// ---------------- canonicalize 27 float inputs to f32 params region ----------------
struct CvtTab { const void* src[27]; int n[27]; int off[27]; };
__global__ __launch_bounds__(256) void cvt_inputs(CvtTab t, float* __restrict__ par,
                                                  const int* __restrict__ flagp) {
    int ent = blockIdx.x >> 3, sub = blockIdx.x & 7;
    int f = flagp[0];
    const void* s = t.src[ent];
    int n = t.n[ent];
    float* d = par + t.off[ent];
    for (int i = sub * 256 + threadIdx.x; i < n; i += 8 * 256)
        d[i] = f ? ((const float*)s)[i] : bf2f(((const ushort_t*)s)[i]);
}

// ---------------- q vectors: q[k][h] = sum_d W[k, h*64+d] * a[h*64+d] ----------------
struct QTab { int woff[12]; int aoff[12]; int qoff[12]; int K[12]; int Hh[12]; };
__global__ __launch_bounds__(256) void make_q(QTab t, float* __restrict__ par) {
    int b = blockIdx.x;
    int k = threadIdx.x;
    int K = t.K[b], Hh = t.Hh[b];
    if (k >= K) return;
    const float* W = par + t.woff[b];
    const float* a = par + t.aoff[b];
    float* q = par + t.qoff[b];
    int HDc = Hh * 64;
    for (int h = 0; h < Hh; ++h) {
        float s = 0.f;
        for (int d = 0; d < 64; ++d) s += W[(size_t)k * HDc + h * 64 + d] * a[h * 64 + d];
        q[k * Hh + h] = s;
    }
}

// ---------------- GEMM L1: X(N x 128) @ Wf32(128 x 256) -> Zb(bf16 N x 256)
__global__ __launch_bounds__(256) void gemm1(const void* __restrict__ X,
                                             const int* __restrict__ flagp,
                                             const float* __restrict__ Wf,
                                             ushort_t* __restrict__ Zb) {
    __shared__ alignas(16) float Wl[32 * 256];   // 32 KB K-tile
    __shared__ alignas(16) float xs[128][8];     // 4 KB
    const int row0 = blockIdx.x * 8;
    const int tid = threadIdx.x;
    const int f = flagp[0];

    for (int idx = tid; idx < 8 * 128; idx += 256) {
        int r = idx >> 7, k = idx & 127;
        xs[k][r] = ldf(X, (size_t)(row0 + r) * D_IN + k, f);
    }
    float acc[8] = {0.f,0.f,0.f,0.f,0.f,0.f,0.f,0.f};
    for (int kt = 0; kt < 128; kt += 32) {
        for (int idx = tid; idx < (32 * 256) / 4; idx += 256)
            ((float4*)Wl)[idx] = ((const float4*)(Wf + (size_t)kt * 256))[idx];
        __syncthreads();
        #pragma unroll
        for (int k = 0; k < 32; ++k) {
            float w = Wl[k * 256 + tid];
            float4 xa = *(const float4*)&xs[kt + k][0];
            float4 xb = *(const float4*)&xs[kt + k][4];
            acc[0] += xa.x * w; acc[1] += xa.y * w;
            acc[2] += xa.z * w; acc[3] += xa.w * w;
            acc[4] += xb.x * w; acc[5] += xb.y * w;
            acc[6] += xb.z * w; acc[7] += xb.w * w;
        }
        __syncthreads();
    }
    #pragma unroll
    for (int r = 0; r < 8; ++r)
        Zb[(size_t)(row0 + r) * HD + tid] = f2bf(acc[r]);
}

// ---------------- GEMM L2: Hb(bf16 N x 256) @ Wf32(256 x 64) -> Zb(bf16 N x 64)
__global__ __launch_bounds__(256) void gemm2(const ushort_t* __restrict__ Hb,
                                             const float* __restrict__ Wf,
                                             ushort_t* __restrict__ Zb) {
    __shared__ alignas(16) float Wl[128 * 64];     // 32 KB
    __shared__ alignas(16) ushort_t As[16 * 256];  // 8 KB
    const int row0 = blockIdx.x * 16;
    const int tid = threadIdx.x;

    for (int idx = tid; idx < (16 * 256) / 8; idx += 256)
        ((uint4*)As)[idx] = ((const uint4*)(Hb + (size_t)row0 * HD))[idx];

    const int col = tid & 63, rq = tid >> 6;
    float acc[4] = {0.f,0.f,0.f,0.f};
    for (int kt = 0; kt < 256; kt += 128) {
        for (int idx = tid; idx < (128 * 64) / 4; idx += 256)
            ((float4*)Wl)[idx] = ((const float4*)(Wf + (size_t)kt * 64))[idx];
        __syncthreads();
        #pragma unroll 8
        for (int k = 0; k < 128; ++k) {
            float w = Wl[k * 64 + col];
            #pragma unroll
            for (int i = 0; i < 4; ++i)
                acc[i] += bf2f(As[(rq * 4 + i) * HD + kt + k]) * w;
        }
        __syncthreads();
    }
    #pragma unroll
    for (int i = 0; i < 4; ++i)
        Zb[(size_t)(row0 + rq * 4 + i) * DOUT + col] = f2bf(acc[i]);
}

// ---------------- el/er: out[n][h] = x[n] . q[:,h]  (one wave per node)
__global__ __launch_bounds__(256) void elr(const void* __restrict__ X,
                                           const int* __restrict__ flagp,
                                           const float* __restrict__ qL,
                                           const float* __restrict__ qR,
                                           float* __restrict__ el,
                                           float* __restrict__ er,
                                           int N, int D, int Hh) {
    __shared__ float qsL[512], qsR[512];
    const int tid = threadIdx.x;
    const int f = flagp ? flagp[0] : 0;
    const int tot = D * Hh;
    for (int i = tid; i < tot; i += 256) {
        qsL[i] = qL[i];
        if (qR) qsR[i] = qR[i];
    }
    __syncthreads();
    const int wid = tid >> 6, lane = tid & 63;
    const int n = blockIdx.x * 4 + wid;
    if (n >= N) return;
    const int J = D >> 6;
    float x[4];
    for (int j = 0; j < J; ++j) x[j] = ldf(X, (size_t)n * D + j * 64 + lane, f);
    for (int h = 0; h < Hh; ++h) {
        float v = 0.f;
        for (int j = 0; j < J; ++j) v += x[j] * qsL[(j * 64 + lane) * Hh + h];
        #pragma unroll
        for (int o = 32; o > 0; o >>= 1) v += __shfl_down(v, o, 64);
        if (lane == 0) el[n * Hh + h] = v;
        if (qR) {
            float u = 0.f;
            for (int j = 0; j < J; ++j) u += x[j] * qsR[(j * 64 + lane) * Hh + h];
            #pragma unroll
            for (int o = 32; o > 0; o >>= 1) u += __shfl_down(u, o, 64);
            if (lane == 0) er[n * Hh + h] = u;
        }
    }
}

// ---------------- edge pass: softmax denominator
template <int HH>
__global__ __launch_bounds__(256) void epass(const int* __restrict__ src,
                                             const int* __restrict__ dst,
                                             const float* __restrict__ el,
                                             const float* __restrict__ er,
                                             float* __restrict__ s, int E) {
    int e = blockIdx.x * 256 + threadIdx.x;
    if (e >= E) return;
    int sn = src[e], dn = dst[e];
    #pragma unroll
    for (int h = 0; h < HH; ++h) {
        float v = el[sn * HH + h] + er[dn * HH + h];
        v = v > 0.f ? v : NEG * v;
        atomicAdd(&s[dn * HH + h], __expf(v));
    }
}

// ---------------- edge scatter L1 (H=4, D=256), dst-range masked
__global__ __launch_bounds__(256) void scat1(const int* __restrict__ src,
                                             const int* __restrict__ dst,
                                             const ushort_t* __restrict__ zb,
                                             const float* __restrict__ el,
                                             const float* __restrict__ er,
                                             const float* __restrict__ s,
                                             const float* __restrict__ ew,
                                             float* __restrict__ acc, int E,
                                             int dst0, int dst1) {
    int e = blockIdx.x * 4 + (threadIdx.x >> 6);
    if (e >= E) return;
    int dn = dst[e];
    if (dn < dst0 || dn >= dst1) return;
    int sn = src[e];
    int lane = threadIdx.x & 63;
    int h = lane >> 4;
    float v = el[sn * 4 + h] + er[dn * 4 + h];
    v = v > 0.f ? v : NEG * v;
    float a = __expf(v) / (s[dn * 4 + h] + 1e-9f) * ew[e];
    ushort4 zv = *(const ushort4*)(zb + (size_t)sn * HD + lane * 4);
    float* ap = acc + (size_t)(dn - dst0) * HD + lane * 4;
    atomicAdd(ap + 0, bf2f(zv.x) * a);
    atomicAdd(ap + 1, bf2f(zv.y) * a);
    atomicAdd(ap + 2, bf2f(zv.z) * a);
    atomicAdd(ap + 3, bf2f(zv.w) * a);
}

// ---------------- edge scatter L2 (H=1, D=64)
__global__ __launch_bounds__(256) void scat2(const int* __restrict__ src,
                                             const int* __restrict__ dst,
                                             const ushort_t* __restrict__ zb,
                                             const float* __restrict__ el,
                                             const float* __restrict__ er,
                                             const float* __restrict__ s,
                                             const float* __restrict__ ew,
                                             float* __restrict__ acc, int E) {
    int e = blockIdx.x * 4 + (threadIdx.x >> 6);
    if (e >= E) return;
    int lane = threadIdx.x & 63;
    int sn = src[e], dn = dst[e];
    float v = el[sn] + er[dn];
    v = v > 0.f ? v : NEG * v;
    float a = __expf(v) / (s[dn] + 1e-9f) * ew[e];
    float z = bf2f(zb[(size_t)sn * DOUT + lane]);
    atomicAdd(acc + (size_t)dn * DOUT + lane, z * a);
}

// ---------------- epilogues ----------------
// h_ac slice: relu(elu(acc+b)) == max(acc+b,0) -> bf16
__global__ __launch_bounds__(256) void post_relu_bf16(const float* __restrict__ acc,
                                                      const float* __restrict__ b,
                                                      ushort_t* __restrict__ h,
                                                      int rowbase, int total) {
    int i = blockIdx.x * 256 + threadIdx.x;
    if (i >= total) return;
    float v = acc[i] + b[i & 255];
    h[(size_t)rowbase * HD + i] = f2bf(v > 0.f ? v : 0.f);
}
// h_w1 = elu(acc+b) -> bf16
__global__ __launch_bounds__(256) void post_elu_bf16(const float* __restrict__ acc,
                                                     const float* __restrict__ b,
                                                     ushort_t* __restrict__ h, int total) {
    int i = blockIdx.x * 256 + threadIdx.x;
    if (i >= total) return;
    float v = acc[i] + b[i & 255];
    h[i] = f2bf(v > 0.f ? v : expm1f(v));
}
// h_word = relu((h_w1 + elu(acc_rel+b))*0.5) -> bf16 (in place over h_w1)
__global__ __launch_bounds__(256) void combine_word(const float* __restrict__ acc,
                                                    const float* __restrict__ b,
                                                    ushort_t* __restrict__ hw, int total) {
    int i = blockIdx.x * 256 + threadIdx.x;
    if (i >= total) return;
    float r = acc[i] + b[i & 255];
    r = r > 0.f ? r : expm1f(r);
    float v = (bf2f(hw[i]) + r) * 0.5f;
    hw[i] = f2bf(v > 0.f ? v : 0.f);
}

__global__ __launch_bounds__(256) void out_tic(const float* __restrict__ acc,
                                               const float* __restrict__ b,
                                               void* __restrict__ out,
                                               const int* __restrict__ flagp, int total) {
    int i = blockIdx.x * 256 + threadIdx.x;
    if (i >= total) return;
    float v = acc[i] + b[i & 63];
    if (flagp[0]) ((float*)out)[i] = v;
    else ((ushort_t*)out)[i] = f2bf(v);
}

__global__ __launch_bounds__(256) void out_word(const float* __restrict__ aw,
                                                const float* __restrict__ bw,
                                                const float* __restrict__ ar_,
                                                const float* __restrict__ br,
                                                void* __restrict__ out,
                                                const int* __restrict__ flagp, int total) {
    int i = blockIdx.x * 256 + threadIdx.x;
    if (i >= total) return;
    int c = i & 63;
    float v = ((aw[i] + bw[c]) + (ar_[i] + br[c])) * 0.5f;
    size_t o = (size_t)N_AC * DOUT + i;
    if (flagp[0]) ((float*)out)[o] = v;
    else ((ushort_t*)out)[o] = f2bf(v);
}

// ---------------- host launch ----------------
extern "C" void kernel_launch(void* const* d_in, const int* in_sizes, int n_in,
                              void* d_out, int out_size, void* d_ws, size_t ws_size,
                              hipStream_t stream) {
    (void)in_sizes; (void)n_in; (void)out_size; (void)ws_size;

    // input indices per setup_inputs order
    const void* x_ac = d_in[0];
    const void* x_w  = d_in[1];
    const int* src_tic = (const int*)d_in[29];
    const int* dst_tic = (const int*)d_in[30];
    const int* src_w   = (const int*)d_in[31];
    const int* dst_w   = (const int*)d_in[32];
    const int* src_rel = (const int*)d_in[33];
    const int* dst_rel = (const int*)d_in[34];

    float* ws = (float*)d_ws;
    int* FLAG = (int*)ws;                        // slot 0

    // params region (canonical f32), offsets within PAR
    float* PAR = ws + 16;
    const int o_wtic = 0, o_ww = 400000, o_wrel = 600000;
    const int o_W1t = 1000000, o_W1w = 1032768, o_W1r = 1065536;
    const int o_W2t = 1098304, o_W2w = 1114688, o_W2r = 1131072;
    const int o_al1t = 1147456, o_ar1t = 1147712, o_al1w = 1147968, o_ar1w = 1148224,
              o_al1r = 1148480, o_ar1r = 1148736;
    const int o_b1t = 1148992, o_b1w = 1149248, o_b1r = 1149504;
    const int o_al2t = 1149760, o_ar2t = 1149824, o_al2w = 1149888, o_ar2w = 1149952,
              o_al2r = 1150016, o_ar2r = 1150080;
    const int o_b2t = 1150144, o_b2w = 1150208, o_b2r = 1150272;
    // q vectors
    const int o_qel1t = 1150400, o_qer1t = 1150912, o_qel1w = 1151424, o_qer1w = 1151936,
              o_qel1r = 1152448, o_qer1r = 1152960;
    const int o_qel2t = 1153472, o_qer2t = 1153728, o_qel2w = 1153984, o_qer2w = 1154240,
              o_qel2r = 1154496, o_qer2r = 1154752;

    float* ACC = ws + 1200016;                   // 5,120,000 f32
    ushort_t* Zb = (ushort_t*)(ws + 6320016);    // 10,240,000 bf16
    ushort_t* Hac = (ushort_t*)(ws + 11440016);  // 40000 x 256 bf16
    ushort_t* Hw  = (ushort_t*)(ws + 16560016);  // 20000 x 256 bf16
    float* EL = ws + 19120016;                   // 160,000
    float* ER = ws + 19280016;                   // 160,000
    float* S  = ws + 19440016;                   // 160,000
    // total: 19,600,016 f32 = 78.4 MB

    // ---- P0: detect dtype, canonicalize params, build q vectors ----
    detect_dtype<<<1, 256, 0, stream>>>((const ushort_t*)x_ac, FLAG);

    CvtTab ct;
    const int srcIdx[27] = {2,3,4, 5,6,7,8, 9,10,11,12, 13,14,15,16,
                            17,18,19,20, 21,22,23,24, 25,26,27,28};
    const int sizes[27] = {E_TIC, E_W, E_REL,
                           32768,256,256,256, 32768,256,256,256, 32768,256,256,256,
                           16384,64,64,64, 16384,64,64,64, 16384,64,64,64};
    const int offs[27] = {o_wtic,o_ww,o_wrel,
                          o_W1t,o_al1t,o_ar1t,o_b1t, o_W1w,o_al1w,o_ar1w,o_b1w,
                          o_W1r,o_al1r,o_ar1r,o_b1r,
                          o_W2t,o_al2t,o_ar2t,o_b2t, o_W2w,o_al2w,o_ar2w,o_b2w,
                          o_W2r,o_al2r,o_ar2r,o_b2r};
    for (int i = 0; i < 27; ++i) { ct.src[i] = d_in[srcIdx[i]]; ct.n[i] = sizes[i]; ct.off[i] = offs[i]; }
    cvt_inputs<<<27 * 8, 256, 0, stream>>>(ct, PAR, FLAG);

    QTab qt;
    const int qw[12] = {o_W1t,o_W1t, o_W1w,o_W1w, o_W1r,o_W1r, o_W2t,o_W2t, o_W2w,o_W2w, o_W2r,o_W2r};
    const int qa[12] = {o_al1t,o_ar1t, o_al1w,o_ar1w, o_al1r,o_ar1r,
                        o_al2t,o_ar2t, o_al2w,o_ar2w, o_al2r,o_ar2r};
    const int qq[12] = {o_qel1t,o_qer1t, o_qel1w,o_qer1w, o_qel1r,o_qer1r,
                        o_qel2t,o_qer2t, o_qel2w,o_qer2w, o_qel2r,o_qer2r};
    for (int i = 0; i < 12; ++i) {
        qt.woff[i] = qw[i]; qt.aoff[i] = qa[i]; qt.qoff[i] = qq[i];
        qt.K[i] = (i < 6) ? 128 : 256; qt.Hh[i] = (i < 6) ? 4 : 1;
    }
    make_q<<<12, 256, 0, stream>>>(qt, PAR);

    // ---- P1: tic GAT layer 1 -> Hac ----
    gemm1<<<N_AC / 8, 256, 0, stream>>>(x_ac, FLAG, PAR + o_W1t, Zb);
    elr<<<N_AC / 4, 256, 0, stream>>>(x_ac, FLAG, PAR + o_qel1t, PAR + o_qer1t, EL, ER, N_AC, 128, 4);
    hipMemsetAsync(S, 0, (size_t)N_AC * NH * 4, stream);
    epass<4><<<(E_TIC + 255) / 256, 256, 0, stream>>>(src_tic, dst_tic, EL, ER, S, E_TIC);
    hipMemsetAsync(ACC, 0, (size_t)20000 * HD * 4, stream);
    scat1<<<E_TIC / 4, 256, 0, stream>>>(src_tic, dst_tic, Zb, EL, ER, S, PAR + o_wtic, ACC, E_TIC, 0, 20000);
    post_relu_bf16<<<(20000 * HD) / 256, 256, 0, stream>>>(ACC, PAR + o_b1t, Hac, 0, 20000 * HD);
    hipMemsetAsync(ACC, 0, (size_t)20000 * HD * 4, stream);
    scat1<<<E_TIC / 4, 256, 0, stream>>>(src_tic, dst_tic, Zb, EL, ER, S, PAR + o_wtic, ACC, E_TIC, 20000, 40000);
    post_relu_bf16<<<(20000 * HD) / 256, 256, 0, stream>>>(ACC, PAR + o_b1t, Hac, 20000, 20000 * HD);

    // ---- P2: w GAT layer 1 -> Hw (elu) ----
    gemm1<<<N_W / 8, 256, 0, stream>>>(x_w, FLAG, PAR + o_W1w, Zb);
    elr<<<N_W / 4, 256, 0, stream>>>(x_w, FLAG, PAR + o_qel1w, PAR + o_qer1w, EL, ER, N_W, 128, 4);
    hipMemsetAsync(S, 0, (size_t)N_W * NH * 4, stream);
    epass<4><<<(E_W + 255) / 256, 256, 0, stream>>>(src_w, dst_w, EL, ER, S, E_W);
    hipMemsetAsync(ACC, 0, (size_t)N_W * HD * 4, stream);
    scat1<<<E_W / 4, 256, 0, stream>>>(src_w, dst_w, Zb, EL, ER, S, PAR + o_ww, ACC, E_W, 0, 20000);
    post_elu_bf16<<<(N_W * HD) / 256, 256, 0, stream>>>(ACC, PAR + o_b1w, Hw, N_W * HD);

    // ---- P3: rel GAT layer 1; combine -> Hw = h_word ----
    gemm1<<<N_AC / 8, 256, 0, stream>>>(x_ac, FLAG, PAR + o_W1r, Zb);
    elr<<<N_AC / 4, 256, 0, stream>>>(x_ac, FLAG, PAR + o_qel1r, nullptr, EL, nullptr, N_AC, 128, 4);
    elr<<<N_W / 4, 256, 0, stream>>>(x_w, FLAG, PAR + o_qer1r, nullptr, ER, nullptr, N_W, 128, 4);
    hipMemsetAsync(S, 0, (size_t)N_W * NH * 4, stream);
    epass<4><<<(E_REL + 255) / 256, 256, 0, stream>>>(src_rel, dst_rel, EL, ER, S, E_REL);
    hipMemsetAsync(ACC, 0, (size_t)N_W * HD * 4, stream);
    scat1<<<E_REL / 4, 256, 0, stream>>>(src_rel, dst_rel, Zb, EL, ER, S, PAR + o_wrel, ACC, E_REL, 0, 20000);
    combine_word<<<(N_W * HD) / 256, 256, 0, stream>>>(ACC, PAR + o_b1r, Hw, N_W * HD);

    // ---- P4: tic GAT layer 2 -> out[0 : 40000*64] ----
    gemm2<<<N_AC / 16, 256, 0, stream>>>(Hac, PAR + o_W2t, Zb);
    elr<<<N_AC / 4, 256, 0, stream>>>(Hac, nullptr, PAR + o_qel2t, PAR + o_qer2t, EL, ER, N_AC, 256, 1);
    hipMemsetAsync(S, 0, (size_t)N_AC * 4, stream);
    epass<1><<<(E_TIC + 255) / 256, 256, 0, stream>>>(src_tic, dst_tic, EL, ER, S, E_TIC);
    hipMemsetAsync(ACC, 0, (size_t)N_AC * DOUT * 4, stream);
    scat2<<<E_TIC / 4, 256, 0, stream>>>(src_tic, dst_tic, Zb, EL, ER, S, PAR + o_wtic, ACC, E_TIC);
    out_tic<<<(N_AC * DOUT) / 256, 256, 0, stream>>>(ACC, PAR + o_b2t, d_out, FLAG, N_AC * DOUT);

    // ---- P5: w GAT layer 2 -> ACC[0 : 1.28M] ----
    gemm2<<<N_W / 16, 256, 0, stream>>>(Hw, PAR + o_W2w, Zb);
    elr<<<N_W / 4, 256, 0, stream>>>(Hw, nullptr, PAR + o_qel2w, PAR + o_qer2w, EL, ER, N_W, 256, 1);
    hipMemsetAsync(S, 0, (size_t)N_W * 4, stream);
    epass<1><<<(E_W + 255) / 256, 256, 0, stream>>>(src_w, dst_w, EL, ER, S, E_W);
    hipMemsetAsync(ACC, 0, (size_t)N_W * DOUT * 4, stream);
    scat2<<<E_W / 4, 256, 0, stream>>>(src_w, dst_w, Zb, EL, ER, S, PAR + o_ww, ACC, E_W);

    // ---- P6: rel GAT layer 2 -> ACC[1.28M : 2.56M]; combine -> out word ----
    float* ACC2 = ACC + (size_t)N_W * DOUT;
    gemm2<<<N_AC / 16, 256, 0, stream>>>(Hac, PAR + o_W2r, Zb);
    elr<<<N_AC / 4, 256, 0, stream>>>(Hac, nullptr, PAR + o_qel2r, nullptr, EL, nullptr, N_AC, 256, 1);
    elr<<<N_W / 4, 256, 0, stream>>>(Hw, nullptr, PAR + o_qer2r, nullptr, ER, nullptr, N_W, 256, 1);
    hipMemsetAsync(S, 0, (size_t)N_W * 4, stream);
    epass<1><<<(E_REL + 255) / 256, 256, 0, stream>>>(src_rel, dst_rel, EL, ER, S, E_REL);
    hipMemsetAsync(ACC2, 0, (size_t)N_W * DOUT * 4, stream);
    scat2<<<E_REL / 4, 256, 0, stream>>>(src_rel, dst_rel, Zb, EL, ER, S, PAR + o_wrel, ACC2, E_REL);
    out_word<<<(N_W * DOUT) / 256, 256, 0, stream>>>(ACC, PAR + o_b2w, ACC2, PAR + o_b2r,
                                                     d_out, FLAG, N_W * DOUT);
}

// Round 3
// 1239.165 us; speedup vs baseline: 3.6084x; 3.6084x over previous
//
#include <hip/hip_runtime.h>
#include <hip/hip_bf16.h>

typedef unsigned short ushort_t;

// ---------------- constants ----------------
#define N_AC 40000
#define N_W  20000
#define D_IN 128
#define NH   4
#define HD   256   // NH*DH
#define DOUT 64
#define E_TIC 400000
#define E_W   200000
#define E_REL 400000
#define NEG 0.2f

__device__ __forceinline__ float bf2f(ushort_t u) {
    return __uint_as_float(((unsigned int)u) << 16);
}
__device__ __forceinline__ ushort_t f2bf(float v) {
    unsigned u = __float_as_uint(v);
    unsigned r = (u + 0x7fffu + ((u >> 16) & 1u)) >> 16;
    return (ushort_t)r;
}
__device__ __forceinline__ float ldf(const void* p, size_t i, int f) {
    return f ? ((const float*)p)[i] : bf2f(((const ushort_t*)p)[i]);
}

// ---------------- dtype autodetect ----------------
__global__ void detect_dtype(const ushort_t* __restrict__ x, int* __restrict__ flag) {
    __shared__ int hit;
    if (threadIdx.x == 0) hit = 0;
    __syncthreads();
    for (int i = threadIdx.x; i < 4096; i += 256) {
        float v = bf2f(x[i]);
        if (!(fabsf(v) <= 1e4f)) atomicOr(&hit, 1);
    }
    __syncthreads();
    if (threadIdx.x == 0) flag[0] = hit ? 1 : 0;
}

// ---------------- canonicalize 27 float inputs to f32 params region ----------------
struct CvtTab { const void* src[27]; int n[27]; int off[27]; };
__global__ __launch_bounds__(256) void cvt_inputs(CvtTab t, float* __restrict__ par,
                                                  const int* __restrict__ flagp) {
    int ent = blockIdx.x >> 3, sub = blockIdx.x & 7;
    int f = flagp[0];
    const void* s = t.src[ent];
    int n = t.n[ent];
    float* d = par + t.off[ent];
    for (int i = sub * 256 + threadIdx.x; i < n; i += 8 * 256)
        d[i] = f ? ((const float*)s)[i] : bf2f(((const ushort_t*)s)[i]);
}

// ---------------- q vectors: q[k][h] = sum_d W[k, h*64+d] * a[h*64+d] ----------------
struct QTab { int woff[12]; int aoff[12]; int qoff[12]; int K[12]; int Hh[12]; };
__global__ __launch_bounds__(256) void make_q(QTab t, float* __restrict__ par) {
    int b = blockIdx.x;
    int k = threadIdx.x;
    int K = t.K[b], Hh = t.Hh[b];
    if (k >= K) return;
    const float* W = par + t.woff[b];
    const float* a = par + t.aoff[b];
    float* q = par + t.qoff[b];
    int HDc = Hh * 64;
    for (int h = 0; h < Hh; ++h) {
        float s = 0.f;
        for (int d = 0; d < 64; ++d) s += W[(size_t)k * HDc + h * 64 + d] * a[h * 64 + d];
        q[k * Hh + h] = s;
    }
}

// ---------------- CSR build ----------------
__global__ __launch_bounds__(256) void count_deg(const int* __restrict__ dst,
                                                 int* __restrict__ cnt, int E) {
    int e = blockIdx.x * 256 + threadIdx.x;
    if (e < E) atomicAdd(&cnt[dst[e]], 1);
}

// single-block exclusive scan; cnt and cur may alias
__global__ __launch_bounds__(1024) void exscan(const int* __restrict__ cnt,
                                               int* __restrict__ rowptr,
                                               int* __restrict__ cur, int N) {
    __shared__ int sums[1024];
    const int T = 1024, t = threadIdx.x;
    int chunk = (N + T - 1) / T;
    int lo = t * chunk, hi = lo + chunk;
    if (lo > N) lo = N;
    if (hi > N) hi = N;
    int s = 0;
    for (int i = lo; i < hi; ++i) s += cnt[i];
    sums[t] = s;
    __syncthreads();
    for (int o = 1; o < T; o <<= 1) {
        int v = (t >= o) ? sums[t - o] : 0;
        __syncthreads();
        sums[t] += v;
        __syncthreads();
    }
    int run = (t == 0) ? 0 : sums[t - 1];
    for (int i = lo; i < hi; ++i) {
        int c = cnt[i];          // read before cur write (cnt may alias cur)
        rowptr[i] = run;
        cur[i] = run;
        run += c;
    }
    if (t == T - 1) rowptr[N] = run;
}

__global__ __launch_bounds__(256) void fill_adj(const int* __restrict__ src,
                                                const int* __restrict__ dst,
                                                const float* __restrict__ ew,
                                                int* __restrict__ cur,
                                                int2* __restrict__ adj, int E) {
    int e = blockIdx.x * 256 + threadIdx.x;
    if (e >= E) return;
    int pos = atomicAdd(&cur[dst[e]], 1);
    adj[pos] = make_int2(src[e], __float_as_int(ew[e]));
}

// ---------------- GEMM L1: X(N x 128) @ Wf32(128 x 256) -> Zb(bf16 N x 256)
__global__ __launch_bounds__(256) void gemm1(const void* __restrict__ X,
                                             const int* __restrict__ flagp,
                                             const float* __restrict__ Wf,
                                             ushort_t* __restrict__ Zb) {
    __shared__ alignas(16) float Wl[32 * 256];
    __shared__ alignas(16) float xs[128][8];
    const int row0 = blockIdx.x * 8;
    const int tid = threadIdx.x;
    const int f = flagp[0];

    for (int idx = tid; idx < 8 * 128; idx += 256) {
        int r = idx >> 7, k = idx & 127;
        xs[k][r] = ldf(X, (size_t)(row0 + r) * D_IN + k, f);
    }
    float acc[8] = {0.f,0.f,0.f,0.f,0.f,0.f,0.f,0.f};
    for (int kt = 0; kt < 128; kt += 32) {
        for (int idx = tid; idx < (32 * 256) / 4; idx += 256)
            ((float4*)Wl)[idx] = ((const float4*)(Wf + (size_t)kt * 256))[idx];
        __syncthreads();
        #pragma unroll
        for (int k = 0; k < 32; ++k) {
            float w = Wl[k * 256 + tid];
            float4 xa = *(const float4*)&xs[kt + k][0];
            float4 xb = *(const float4*)&xs[kt + k][4];
            acc[0] += xa.x * w; acc[1] += xa.y * w;
            acc[2] += xa.z * w; acc[3] += xa.w * w;
            acc[4] += xb.x * w; acc[5] += xb.y * w;
            acc[6] += xb.z * w; acc[7] += xb.w * w;
        }
        __syncthreads();
    }
    #pragma unroll
    for (int r = 0; r < 8; ++r)
        Zb[(size_t)(row0 + r) * HD + tid] = f2bf(acc[r]);
}

// ---------------- GEMM L2: Hb(bf16 N x 256) @ Wf32(256 x 64) -> Zb(bf16 N x 64)
__global__ __launch_bounds__(256) void gemm2(const ushort_t* __restrict__ Hb,
                                             const float* __restrict__ Wf,
                                             ushort_t* __restrict__ Zb) {
    __shared__ alignas(16) float Wl[128 * 64];
    __shared__ alignas(16) ushort_t As[16 * 256];
    const int row0 = blockIdx.x * 16;
    const int tid = threadIdx.x;

    for (int idx = tid; idx < (16 * 256) / 8; idx += 256)
        ((uint4*)As)[idx] = ((const uint4*)(Hb + (size_t)row0 * HD))[idx];

    const int col = tid & 63, rq = tid >> 6;
    float acc[4] = {0.f,0.f,0.f,0.f};
    for (int kt = 0; kt < 256; kt += 128) {
        for (int idx = tid; idx < (128 * 64) / 4; idx += 256)
            ((float4*)Wl)[idx] = ((const float4*)(Wf + (size_t)kt * 64))[idx];
        __syncthreads();
        #pragma unroll 8
        for (int k = 0; k < 128; ++k) {
            float w = Wl[k * 64 + col];
            #pragma unroll
            for (int i = 0; i < 4; ++i)
                acc[i] += bf2f(As[(rq * 4 + i) * HD + kt + k]) * w;
        }
        __syncthreads();
    }
    #pragma unroll
    for (int i = 0; i < 4; ++i)
        Zb[(size_t)(row0 + rq * 4 + i) * DOUT + col] = f2bf(acc[i]);
}

// ---------------- el/er: out[n][h] = x[n] . q[:,h]  (one wave per node)
__global__ __launch_bounds__(256) void elr(const void* __restrict__ X,
                                           const int* __restrict__ flagp,
                                           const float* __restrict__ qL,
                                           const float* __restrict__ qR,
                                           float* __restrict__ el,
                                           float* __restrict__ er,
                                           int N, int D, int Hh) {
    __shared__ float qsL[512], qsR[512];
    const int tid = threadIdx.x;
    const int f = flagp ? flagp[0] : 0;
    const int tot = D * Hh;
    for (int i = tid; i < tot; i += 256) {
        qsL[i] = qL[i];
        if (qR) qsR[i] = qR[i];
    }
    __syncthreads();
    const int wid = tid >> 6, lane = tid & 63;
    const int n = blockIdx.x * 4 + wid;
    if (n >= N) return;
    const int J = D >> 6;
    float x[4];
    for (int j = 0; j < J; ++j) x[j] = ldf(X, (size_t)n * D + j * 64 + lane, f);
    for (int h = 0; h < Hh; ++h) {
        float v = 0.f;
        for (int j = 0; j < J; ++j) v += x[j] * qsL[(j * 64 + lane) * Hh + h];
        #pragma unroll
        for (int o = 32; o > 0; o >>= 1) v += __shfl_down(v, o, 64);
        if (lane == 0) el[n * Hh + h] = v;
        if (qR) {
            float u = 0.f;
            for (int j = 0; j < J; ++j) u += x[j] * qsR[(j * 64 + lane) * Hh + h];
            #pragma unroll
            for (int o = 32; o > 0; o >>= 1) u += __shfl_down(u, o, 64);
            if (lane == 0) er[n * Hh + h] = u;
        }
    }
}

// ---------------- fused CSR gather, layer 1 (H=4, D=256) ----------------
// MODE 0: h = max(acc+b, 0)                       (tic -> Hac)
// MODE 1: h = elu(acc+b)                          (w   -> Hw)
// MODE 2: h = relu((Hw + elu(acc+b)) * 0.5)       (rel -> Hw, in place)
template <int MODE>
__global__ __launch_bounds__(256) void gat1(const int* __restrict__ rp,
                                            const int2* __restrict__ adj,
                                            const ushort_t* __restrict__ zb,
                                            const float* __restrict__ el,
                                            const float* __restrict__ er,
                                            const float* __restrict__ bias,
                                            ushort_t* __restrict__ H, int N) {
    const int wid = threadIdx.x >> 6, lane = threadIdx.x & 63;
    const int n = blockIdx.x * 4 + wid;
    if (n >= N) return;
    const int h = lane >> 4;
    const int beg = rp[n], end = rp[n + 1];
    const float erh = er[n * 4 + h];

    float s = 0.f;
    for (int i = beg; i < end; ++i) {
        int sn = adj[i].x;
        float v = el[sn * 4 + h] + erh;
        v = v > 0.f ? v : NEG * v;
        s += __expf(v);
    }
    const float inv = 1.f / (s + 1e-9f);

    float a0 = 0.f, a1 = 0.f, a2 = 0.f, a3 = 0.f;
    for (int i = beg; i < end; ++i) {
        int2 ae = adj[i];
        float v = el[ae.x * 4 + h] + erh;
        v = v > 0.f ? v : NEG * v;
        float at = __expf(v) * inv * __int_as_float(ae.y);
        ushort4 zv = *(const ushort4*)(zb + (size_t)ae.x * HD + lane * 4);
        a0 += bf2f(zv.x) * at; a1 += bf2f(zv.y) * at;
        a2 += bf2f(zv.z) * at; a3 += bf2f(zv.w) * at;
    }
    float4 b = *(const float4*)(bias + lane * 4);
    a0 += b.x; a1 += b.y; a2 += b.z; a3 += b.w;

    ushort_t* hp = H + (size_t)n * HD + lane * 4;
    ushort4 o;
    if (MODE == 0) {
        o.x = f2bf(a0 > 0.f ? a0 : 0.f); o.y = f2bf(a1 > 0.f ? a1 : 0.f);
        o.z = f2bf(a2 > 0.f ? a2 : 0.f); o.w = f2bf(a3 > 0.f ? a3 : 0.f);
    } else if (MODE == 1) {
        o.x = f2bf(a0 > 0.f ? a0 : expm1f(a0)); o.y = f2bf(a1 > 0.f ? a1 : expm1f(a1));
        o.z = f2bf(a2 > 0.f ? a2 : expm1f(a2)); o.w = f2bf(a3 > 0.f ? a3 : expm1f(a3));
    } else {
        ushort4 hw = *(const ushort4*)hp;
        float v0 = (bf2f(hw.x) + (a0 > 0.f ? a0 : expm1f(a0))) * 0.5f;
        float v1 = (bf2f(hw.y) + (a1 > 0.f ? a1 : expm1f(a1))) * 0.5f;
        float v2 = (bf2f(hw.z) + (a2 > 0.f ? a2 : expm1f(a2))) * 0.5f;
        float v3 = (bf2f(hw.w) + (a3 > 0.f ? a3 : expm1f(a3))) * 0.5f;
        o.x = f2bf(v0 > 0.f ? v0 : 0.f); o.y = f2bf(v1 > 0.f ? v1 : 0.f);
        o.z = f2bf(v2 > 0.f ? v2 : 0.f); o.w = f2bf(v3 > 0.f ? v3 : 0.f);
    }
    *(ushort4*)hp = o;
}

// ---------------- fused CSR gather, layer 2 (H=1, D=64) -> f32 acc ----------------
__global__ __launch_bounds__(256) void gat2(const int* __restrict__ rp,
                                            const int2* __restrict__ adj,
                                            const ushort_t* __restrict__ zb,
                                            const float* __restrict__ el,
                                            const float* __restrict__ er,
                                            float* __restrict__ acc, int N) {
    const int wid = threadIdx.x >> 6, lane = threadIdx.x & 63;
    const int n = blockIdx.x * 4 + wid;
    if (n >= N) return;
    const int beg = rp[n], end = rp[n + 1];
    const float ern = er[n];

    float s = 0.f;
    for (int i = beg; i < end; ++i) {
        float v = el[adj[i].x] + ern;
        v = v > 0.f ? v : NEG * v;
        s += __expf(v);
    }
    const float inv = 1.f / (s + 1e-9f);

    float a0 = 0.f;
    for (int i = beg; i < end; ++i) {
        int2 ae = adj[i];
        float v = el[ae.x] + ern;
        v = v > 0.f ? v : NEG * v;
        float at = __expf(v) * inv * __int_as_float(ae.y);
        a0 += bf2f(zb[(size_t)ae.x * DOUT + lane]) * at;
    }
    acc[(size_t)n * DOUT + lane] = a0;
}

// ---------------- output epilogues ----------------
__global__ __launch_bounds__(256) void out_tic(const float* __restrict__ acc,
                                               const float* __restrict__ b,
                                               void* __restrict__ out,
                                               const int* __restrict__ flagp, int total) {
    int i = blockIdx.x * 256 + threadIdx.x;
    if (i >= total) return;
    float v = acc[i] + b[i & 63];
    if (flagp[0]) ((float*)out)[i] = v;
    else ((ushort_t*)out)[i] = f2bf(v);
}

__global__ __launch_bounds__(256) void out_word(const float* __restrict__ aw,
                                                const float* __restrict__ bw,
                                                const float* __restrict__ ar_,
                                                const float* __restrict__ br,
                                                void* __restrict__ out,
                                                const int* __restrict__ flagp, int total) {
    int i = blockIdx.x * 256 + threadIdx.x;
    if (i >= total) return;
    int c = i & 63;
    float v = ((aw[i] + bw[c]) + (ar_[i] + br[c])) * 0.5f;
    size_t o = (size_t)N_AC * DOUT + i;
    if (flagp[0]) ((float*)out)[o] = v;
    else ((ushort_t*)out)[o] = f2bf(v);
}

// ---------------- host launch ----------------
extern "C" void kernel_launch(void* const* d_in, const int* in_sizes, int n_in,
                              void* d_out, int out_size, void* d_ws, size_t ws_size,
                              hipStream_t stream) {
    (void)in_sizes; (void)n_in; (void)out_size; (void)ws_size;

    const void* x_ac = d_in[0];
    const void* x_w  = d_in[1];
    const int* src_tic = (const int*)d_in[29];
    const int* dst_tic = (const int*)d_in[30];
    const int* src_w   = (const int*)d_in[31];
    const int* dst_w   = (const int*)d_in[32];
    const int* src_rel = (const int*)d_in[33];
    const int* dst_rel = (const int*)d_in[34];

    float* ws = (float*)d_ws;
    int* FLAG = (int*)ws;

    float* PAR = ws + 16;
    const int o_wtic = 0, o_ww = 400000, o_wrel = 600000;
    const int o_W1t = 1000000, o_W1w = 1032768, o_W1r = 1065536;
    const int o_W2t = 1098304, o_W2w = 1114688, o_W2r = 1131072;
    const int o_al1t = 1147456, o_ar1t = 1147712, o_al1w = 1147968, o_ar1w = 1148224,
              o_al1r = 1148480, o_ar1r = 1148736;
    const int o_b1t = 1148992, o_b1w = 1149248, o_b1r = 1149504;
    const int o_al2t = 1149760, o_ar2t = 1149824, o_al2w = 1149888, o_ar2w = 1149952,
              o_al2r = 1150016, o_ar2r = 1150080;
    const int o_b2t = 1150144, o_b2w = 1150208, o_b2r = 1150272;
    const int o_qel1t = 1150400, o_qer1t = 1150912, o_qel1w = 1151424, o_qer1w = 1151936,
              o_qel1r = 1152448, o_qer1r = 1152960;
    const int o_qel2t = 1153472, o_qer2t = 1153728, o_qel2w = 1153984, o_qer2w = 1154240,
              o_qel2r = 1154496, o_qer2r = 1154752;

    float* EL  = ws + 1160016;                   // 160,000
    float* ER  = ws + 1320016;                   // 160,000
    float* ACC = ws + 1480016;                   // 2,560,000
    ushort_t* Zb  = (ushort_t*)(ws + 4040016);   // 10.24M bf16
    ushort_t* Hac = (ushort_t*)(ws + 9160016);   // 40000x256 bf16
    ushort_t* Hw  = (ushort_t*)(ws + 14280016);  // 20000x256 bf16
    int* IB = (int*)(ws + 16840016);
    int* rp_tic = IB;                            // 40,016
    int* rp_w   = IB + 40016;                    // 20,016
    int* rp_rel = IB + 60032;                    // 20,016
    int* cur    = IB + 80048;                    // 40,016 (also degree counts)
    int2* adj_tic = (int2*)(IB + 120064);        // 400,000 int2
    int2* adj_w   = (int2*)(IB + 920064);        // 200,000 int2
    int2* adj_rel = (int2*)(IB + 1320064);       // 400,000 int2
    // end: ws + 18,960,080 floats = 75.9 MB

    // ---- P0: dtype, params, q vectors ----
    detect_dtype<<<1, 256, 0, stream>>>((const ushort_t*)x_ac, FLAG);

    CvtTab ct;
    const int srcIdx[27] = {2,3,4, 5,6,7,8, 9,10,11,12, 13,14,15,16,
                            17,18,19,20, 21,22,23,24, 25,26,27,28};
    const int sizes[27] = {E_TIC, E_W, E_REL,
                           32768,256,256,256, 32768,256,256,256, 32768,256,256,256,
                           16384,64,64,64, 16384,64,64,64, 16384,64,64,64};
    const int offs[27] = {o_wtic,o_ww,o_wrel,
                          o_W1t,o_al1t,o_ar1t,o_b1t, o_W1w,o_al1w,o_ar1w,o_b1w,
                          o_W1r,o_al1r,o_ar1r,o_b1r,
                          o_W2t,o_al2t,o_ar2t,o_b2t, o_W2w,o_al2w,o_ar2w,o_b2w,
                          o_W2r,o_al2r,o_ar2r,o_b2r};
    for (int i = 0; i < 27; ++i) { ct.src[i] = d_in[srcIdx[i]]; ct.n[i] = sizes[i]; ct.off[i] = offs[i]; }
    cvt_inputs<<<27 * 8, 256, 0, stream>>>(ct, PAR, FLAG);

    QTab qt;
    const int qw[12] = {o_W1t,o_W1t, o_W1w,o_W1w, o_W1r,o_W1r, o_W2t,o_W2t, o_W2w,o_W2w, o_W2r,o_W2r};
    const int qa[12] = {o_al1t,o_ar1t, o_al1w,o_ar1w, o_al1r,o_ar1r,
                        o_al2t,o_ar2t, o_al2w,o_ar2w, o_al2r,o_ar2r};
    const int qq[12] = {o_qel1t,o_qer1t, o_qel1w,o_qer1w, o_qel1r,o_qer1r,
                        o_qel2t,o_qer2t, o_qel2w,o_qer2w, o_qel2r,o_qer2r};
    for (int i = 0; i < 12; ++i) {
        qt.woff[i] = qw[i]; qt.aoff[i] = qa[i]; qt.qoff[i] = qq[i];
        qt.K[i] = (i < 6) ? 128 : 256; qt.Hh[i] = (i < 6) ? 4 : 1;
    }
    make_q<<<12, 256, 0, stream>>>(qt, PAR);

    // ---- P0b: CSR builds (reused by both layers) ----
    hipMemsetAsync(cur, 0, N_AC * 4, stream);
    count_deg<<<(E_TIC + 255) / 256, 256, 0, stream>>>(dst_tic, cur, E_TIC);
    exscan<<<1, 1024, 0, stream>>>(cur, rp_tic, cur, N_AC);
    fill_adj<<<(E_TIC + 255) / 256, 256, 0, stream>>>(src_tic, dst_tic, PAR + o_wtic, cur, adj_tic, E_TIC);

    hipMemsetAsync(cur, 0, N_W * 4, stream);
    count_deg<<<(E_W + 255) / 256, 256, 0, stream>>>(dst_w, cur, E_W);
    exscan<<<1, 1024, 0, stream>>>(cur, rp_w, cur, N_W);
    fill_adj<<<(E_W + 255) / 256, 256, 0, stream>>>(src_w, dst_w, PAR + o_ww, cur, adj_w, E_W);

    hipMemsetAsync(cur, 0, N_W * 4, stream);
    count_deg<<<(E_REL + 255) / 256, 256, 0, stream>>>(dst_rel, cur, E_REL);
    exscan<<<1, 1024, 0, stream>>>(cur, rp_rel, cur, N_W);
    fill_adj<<<(E_REL + 255) / 256, 256, 0, stream>>>(src_rel, dst_rel, PAR + o_wrel, cur, adj_rel, E_REL);

    // ---- P1: tic GAT layer 1 -> Hac ----
    gemm1<<<N_AC / 8, 256, 0, stream>>>(x_ac, FLAG, PAR + o_W1t, Zb);
    elr<<<N_AC / 4, 256, 0, stream>>>(x_ac, FLAG, PAR + o_qel1t, PAR + o_qer1t, EL, ER, N_AC, 128, 4);
    gat1<0><<<N_AC / 4, 256, 0, stream>>>(rp_tic, adj_tic, Zb, EL, ER, PAR + o_b1t, Hac, N_AC);

    // ---- P2: w GAT layer 1 -> Hw (elu) ----
    gemm1<<<N_W / 8, 256, 0, stream>>>(x_w, FLAG, PAR + o_W1w, Zb);
    elr<<<N_W / 4, 256, 0, stream>>>(x_w, FLAG, PAR + o_qel1w, PAR + o_qer1w, EL, ER, N_W, 128, 4);
    gat1<1><<<N_W / 4, 256, 0, stream>>>(rp_w, adj_w, Zb, EL, ER, PAR + o_b1w, Hw, N_W);

    // ---- P3: rel GAT layer 1; combine -> Hw = h_word ----
    gemm1<<<N_AC / 8, 256, 0, stream>>>(x_ac, FLAG, PAR + o_W1r, Zb);
    elr<<<N_AC / 4, 256, 0, stream>>>(x_ac, FLAG, PAR + o_qel1r, nullptr, EL, nullptr, N_AC, 128, 4);
    elr<<<N_W / 4, 256, 0, stream>>>(x_w, FLAG, PAR + o_qer1r, nullptr, ER, nullptr, N_W, 128, 4);
    gat1<2><<<N_W / 4, 256, 0, stream>>>(rp_rel, adj_rel, Zb, EL, ER, PAR + o_b1r, Hw, N_W);

    // ---- P4: tic GAT layer 2 -> out[0 : 40000*64] ----
    gemm2<<<N_AC / 16, 256, 0, stream>>>(Hac, PAR + o_W2t, Zb);
    elr<<<N_AC / 4, 256, 0, stream>>>(Hac, nullptr, PAR + o_qel2t, PAR + o_qer2t, EL, ER, N_AC, 256, 1);
    gat2<<<N_AC / 4, 256, 0, stream>>>(rp_tic, adj_tic, Zb, EL, ER, ACC, N_AC);
    out_tic<<<(N_AC * DOUT) / 256, 256, 0, stream>>>(ACC, PAR + o_b2t, d_out, FLAG, N_AC * DOUT);

    // ---- P5: w GAT layer 2 -> ACC[0 : 1.28M] ----
    gemm2<<<N_W / 16, 256, 0, stream>>>(Hw, PAR + o_W2w, Zb);
    elr<<<N_W / 4, 256, 0, stream>>>(Hw, nullptr, PAR + o_qel2w, PAR + o_qer2w, EL, ER, N_W, 256, 1);
    gat2<<<N_W / 4, 256, 0, stream>>>(rp_w, adj_w, Zb, EL, ER, ACC, N_W);

    // ---- P6: rel GAT layer 2 -> ACC[1.28M : 2.56M]; combine -> out word ----
    float* ACC2 = ACC + (size_t)N_W * DOUT;
    gemm2<<<N_AC / 16, 256, 0, stream>>>(Hac, PAR + o_W2r, Zb);
    elr<<<N_AC / 4, 256, 0, stream>>>(Hac, nullptr, PAR + o_qel2r, nullptr, EL, nullptr, N_AC, 256, 1);
    elr<<<N_W / 4, 256, 0, stream>>>(Hw, nullptr, PAR + o_qer2r, nullptr, ER, nullptr, N_W, 256, 1);
    gat2<<<N_W / 4, 256, 0, stream>>>(rp_rel, adj_rel, Zb, EL, ER, ACC2, N_W);
    out_word<<<(N_W * DOUT) / 256, 256, 0, stream>>>(ACC, PAR + o_b2w, ACC2, PAR + o_b2r,
                                                     d_out, FLAG, N_W * DOUT);
}

// Round 4
// 940.971 us; speedup vs baseline: 4.7519x; 1.3169x over previous
//
#include <hip/hip_runtime.h>
#include <hip/hip_bf16.h>

typedef unsigned short ushort_t;

// ---------------- constants ----------------
#define N_AC 40000
#define N_W  20000
#define D_IN 128
#define NH   4
#define HD   256   // NH*DH
#define DOUT 64
#define E_TIC 400000
#define E_W   200000
#define E_REL 400000
#define NEG 0.2f
#define CAP 256    // per-wave LDS edge capacity (max degree ~50 expected)

__device__ __forceinline__ float bf2f(ushort_t u) {
    return __uint_as_float(((unsigned int)u) << 16);
}
__device__ __forceinline__ ushort_t f2bf(float v) {
    unsigned u = __float_as_uint(v);
    unsigned r = (u + 0x7fffu + ((u >> 16) & 1u)) >> 16;
    return (ushort_t)r;
}
__device__ __forceinline__ float ldf(const void* p, size_t i, int f) {
    return f ? ((const float*)p)[i] : bf2f(((const ushort_t*)p)[i]);
}
__device__ __forceinline__ float lrelu_exp(float v) {
    v = v > 0.f ? v : NEG * v;
    return __expf(v);
}

// ---------------- dtype autodetect ----------------
__global__ void detect_dtype(const ushort_t* __restrict__ x, int* __restrict__ flag) {
    __shared__ int hit;
    if (threadIdx.x == 0) hit = 0;
    __syncthreads();
    for (int i = threadIdx.x; i < 4096; i += 256) {
        float v = bf2f(x[i]);
        if (!(fabsf(v) <= 1e4f)) atomicOr(&hit, 1);
    }
    __syncthreads();
    if (threadIdx.x == 0) flag[0] = hit ? 1 : 0;
}

// ---------------- canonicalize 27 float inputs to f32 params region ----------------
struct CvtTab { const void* src[27]; int n[27]; int off[27]; };
__global__ __launch_bounds__(256) void cvt_inputs(CvtTab t, float* __restrict__ par,
                                                  const int* __restrict__ flagp) {
    int ent = blockIdx.x >> 3, sub = blockIdx.x & 7;
    int f = flagp[0];
    const void* s = t.src[ent];
    int n = t.n[ent];
    float* d = par + t.off[ent];
    for (int i = sub * 256 + threadIdx.x; i < n; i += 8 * 256)
        d[i] = f ? ((const float*)s)[i] : bf2f(((const ushort_t*)s)[i]);
}

// ---------------- q vectors: q[k][h] = sum_d W[k, h*64+d] * a[h*64+d] ----------------
struct QTab { int woff[12]; int aoff[12]; int qoff[12]; int K[12]; int Hh[12]; };
__global__ __launch_bounds__(256) void make_q(QTab t, float* __restrict__ par) {
    int b = blockIdx.x;
    int k = threadIdx.x;
    int K = t.K[b], Hh = t.Hh[b];
    if (k >= K) return;
    const float* W = par + t.woff[b];
    const float* a = par + t.aoff[b];
    float* q = par + t.qoff[b];
    int HDc = Hh * 64;
    for (int h = 0; h < Hh; ++h) {
        float s = 0.f;
        for (int d = 0; d < 64; ++d) s += W[(size_t)k * HDc + h * 64 + d] * a[h * 64 + d];
        q[k * Hh + h] = s;
    }
}

// ---------------- CSR build ----------------
__global__ __launch_bounds__(256) void count_deg(const int* __restrict__ dst,
                                                 int* __restrict__ cnt, int E) {
    int e = blockIdx.x * 256 + threadIdx.x;
    if (e < E) atomicAdd(&cnt[dst[e]], 1);
}

__global__ __launch_bounds__(1024) void exscan(const int* __restrict__ cnt,
                                               int* __restrict__ rowptr,
                                               int* __restrict__ cur, int N) {
    __shared__ int sums[1024];
    const int T = 1024, t = threadIdx.x;
    int chunk = (N + T - 1) / T;
    int lo = t * chunk, hi = lo + chunk;
    if (lo > N) lo = N;
    if (hi > N) hi = N;
    int s = 0;
    for (int i = lo; i < hi; ++i) s += cnt[i];
    sums[t] = s;
    __syncthreads();
    for (int o = 1; o < T; o <<= 1) {
        int v = (t >= o) ? sums[t - o] : 0;
        __syncthreads();
        sums[t] += v;
        __syncthreads();
    }
    int run = (t == 0) ? 0 : sums[t - 1];
    for (int i = lo; i < hi; ++i) {
        int c = cnt[i];
        rowptr[i] = run;
        cur[i] = run;
        run += c;
    }
    if (t == T - 1) rowptr[N] = run;
}

__global__ __launch_bounds__(256) void fill_adj(const int* __restrict__ src,
                                                const int* __restrict__ dst,
                                                const float* __restrict__ ew,
                                                int* __restrict__ cur,
                                                int2* __restrict__ adj, int E) {
    int e = blockIdx.x * 256 + threadIdx.x;
    if (e >= E) return;
    int pos = atomicAdd(&cur[dst[e]], 1);
    adj[pos] = make_int2(src[e], __float_as_int(ew[e]));
}

// ---------------- GEMM L1: X(N x 128) @ Wf32(128 x 256) -> Zb(bf16 N x 256)
__global__ __launch_bounds__(256) void gemm1(const void* __restrict__ X,
                                             const int* __restrict__ flagp,
                                             const float* __restrict__ Wf,
                                             ushort_t* __restrict__ Zb) {
    __shared__ alignas(16) float Wl[32 * 256];
    __shared__ alignas(16) float xs[128][8];
    const int row0 = blockIdx.x * 8;
    const int tid = threadIdx.x;
    const int f = flagp[0];

    for (int idx = tid; idx < 8 * 128; idx += 256) {
        int r = idx >> 7, k = idx & 127;
        xs[k][r] = ldf(X, (size_t)(row0 + r) * D_IN + k, f);
    }
    float acc[8] = {0.f,0.f,0.f,0.f,0.f,0.f,0.f,0.f};
    for (int kt = 0; kt < 128; kt += 32) {
        for (int idx = tid; idx < (32 * 256) / 4; idx += 256)
            ((float4*)Wl)[idx] = ((const float4*)(Wf + (size_t)kt * 256))[idx];
        __syncthreads();
        #pragma unroll
        for (int k = 0; k < 32; ++k) {
            float w = Wl[k * 256 + tid];
            float4 xa = *(const float4*)&xs[kt + k][0];
            float4 xb = *(const float4*)&xs[kt + k][4];
            acc[0] += xa.x * w; acc[1] += xa.y * w;
            acc[2] += xa.z * w; acc[3] += xa.w * w;
            acc[4] += xb.x * w; acc[5] += xb.y * w;
            acc[6] += xb.z * w; acc[7] += xb.w * w;
        }
        __syncthreads();
    }
    #pragma unroll
    for (int r = 0; r < 8; ++r)
        Zb[(size_t)(row0 + r) * HD + tid] = f2bf(acc[r]);
}

// ---------------- GEMM L2: Hb(bf16 N x 256) @ Wf32(256 x 64) -> Zb(bf16 N x 64)
__global__ __launch_bounds__(256) void gemm2(const ushort_t* __restrict__ Hb,
                                             const float* __restrict__ Wf,
                                             ushort_t* __restrict__ Zb) {
    __shared__ alignas(16) float Wl[128 * 64];
    __shared__ alignas(16) ushort_t As[16 * 256];
    const int row0 = blockIdx.x * 16;
    const int tid = threadIdx.x;

    for (int idx = tid; idx < (16 * 256) / 8; idx += 256)
        ((uint4*)As)[idx] = ((const uint4*)(Hb + (size_t)row0 * HD))[idx];

    const int col = tid & 63, rq = tid >> 6;
    float acc[4] = {0.f,0.f,0.f,0.f};
    for (int kt = 0; kt < 256; kt += 128) {
        for (int idx = tid; idx < (128 * 64) / 4; idx += 256)
            ((float4*)Wl)[idx] = ((const float4*)(Wf + (size_t)kt * 64))[idx];
        __syncthreads();
        #pragma unroll 8
        for (int k = 0; k < 128; ++k) {
            float w = Wl[k * 64 + col];
            #pragma unroll
            for (int i = 0; i < 4; ++i)
                acc[i] += bf2f(As[(rq * 4 + i) * HD + kt + k]) * w;
        }
        __syncthreads();
    }
    #pragma unroll
    for (int i = 0; i < 4; ++i)
        Zb[(size_t)(row0 + rq * 4 + i) * DOUT + col] = f2bf(acc[i]);
}

// ---------------- el/er: out[n][h] = x[n] . q[:,h]  (one wave per node)
__global__ __launch_bounds__(256) void elr(const void* __restrict__ X,
                                           const int* __restrict__ flagp,
                                           const float* __restrict__ qL,
                                           const float* __restrict__ qR,
                                           float* __restrict__ el,
                                           float* __restrict__ er,
                                           int N, int D, int Hh) {
    __shared__ float qsL[512], qsR[512];
    const int tid = threadIdx.x;
    const int f = flagp ? flagp[0] : 0;
    const int tot = D * Hh;
    for (int i = tid; i < tot; i += 256) {
        qsL[i] = qL[i];
        if (qR) qsR[i] = qR[i];
    }
    __syncthreads();
    const int wid = tid >> 6, lane = tid & 63;
    const int n = blockIdx.x * 4 + wid;
    if (n >= N) return;
    const int J = D >> 6;
    float x[4];
    for (int j = 0; j < J; ++j) x[j] = ldf(X, (size_t)n * D + j * 64 + lane, f);
    for (int h = 0; h < Hh; ++h) {
        float v = 0.f;
        for (int j = 0; j < J; ++j) v += x[j] * qsL[(j * 64 + lane) * Hh + h];
        #pragma unroll
        for (int o = 32; o > 0; o >>= 1) v += __shfl_down(v, o, 64);
        if (lane == 0) el[n * Hh + h] = v;
        if (qR) {
            float u = 0.f;
            for (int j = 0; j < J; ++j) u += x[j] * qsR[(j * 64 + lane) * Hh + h];
            #pragma unroll
            for (int o = 32; o > 0; o >>= 1) u += __shfl_down(u, o, 64);
            if (lane == 0) er[n * Hh + h] = u;
        }
    }
}

// ---------------- fused CSR gather, layer 1 (H=4, D=256) ----------------
// Pass A (lane-parallel over edges): exp + stash (exp*ew, src) in LDS, sum s.
// Pass B (edge-serial, lane-parallel over D): gather z rows, accumulate
// unscaled; scale by 1/s once at the end.
// MODE 0: h = max(acc+b, 0)            MODE 1: h = elu(acc+b)
// MODE 2: h = relu((Hw + elu(acc+b)) * 0.5)
template <int MODE>
__global__ __launch_bounds__(256) void gat1(const int* __restrict__ rp,
                                            const int2* __restrict__ adj,
                                            const ushort_t* __restrict__ zb,
                                            const float* __restrict__ el,
                                            const float* __restrict__ er,
                                            const float* __restrict__ bias,
                                            ushort_t* __restrict__ H, int N) {
    __shared__ float atl[4][CAP * 4];   // exp*ew per (edge, head)
    __shared__ int   snl[4][CAP];       // src node per edge
    const int w = threadIdx.x >> 6, lane = threadIdx.x & 63;
    const int n = blockIdx.x * 4 + w;
    if (n >= N) return;
    const int h = lane >> 4;
    const int beg = rp[n], deg = rp[n + 1] - beg;
    const float4* el4 = (const float4*)el;
    const float4 ern = ((const float4*)er)[n];

    // ---- pass A ----
    float4 ss = make_float4(0.f, 0.f, 0.f, 0.f);
    for (int base = 0; base < deg; base += 64) {
        int i = base + lane;
        if (i < deg) {
            int2 ae = adj[beg + i];
            float4 e = el4[ae.x];
            float x0 = lrelu_exp(e.x + ern.x);
            float x1 = lrelu_exp(e.y + ern.y);
            float x2 = lrelu_exp(e.z + ern.z);
            float x3 = lrelu_exp(e.w + ern.w);
            ss.x += x0; ss.y += x1; ss.z += x2; ss.w += x3;
            if (i < CAP) {
                float ew = __int_as_float(ae.y);
                float4* dst4 = (float4*)&atl[w][i * 4];
                *dst4 = make_float4(x0 * ew, x1 * ew, x2 * ew, x3 * ew);
                snl[w][i] = ae.x;
            }
        }
    }
    #pragma unroll
    for (int o = 32; o > 0; o >>= 1) {
        ss.x += __shfl_xor(ss.x, o, 64);
        ss.y += __shfl_xor(ss.y, o, 64);
        ss.z += __shfl_xor(ss.z, o, 64);
        ss.w += __shfl_xor(ss.w, o, 64);
    }
    const float sh = (h == 0) ? ss.x : (h == 1) ? ss.y : (h == 2) ? ss.z : ss.w;
    const float inv = 1.f / (sh + 1e-9f);
    const float erh = (h == 0) ? ern.x : (h == 1) ? ern.y : (h == 2) ? ern.z : ern.w;

    // ---- pass B ----
    float a0 = 0.f, a1 = 0.f, a2 = 0.f, a3 = 0.f;
    #pragma unroll 2
    for (int i = 0; i < deg; ++i) {
        int sn; float atv;
        if (i < CAP) {
            sn = snl[w][i];
            atv = atl[w][i * 4 + h];
        } else {                         // rare overflow: recompute
            int2 ae = adj[beg + i];
            sn = ae.x;
            atv = lrelu_exp(el[sn * 4 + h] + erh) * __int_as_float(ae.y);
        }
        ushort4 zv = *(const ushort4*)(zb + (size_t)sn * HD + lane * 4);
        a0 += bf2f(zv.x) * atv; a1 += bf2f(zv.y) * atv;
        a2 += bf2f(zv.z) * atv; a3 += bf2f(zv.w) * atv;
    }
    float4 b = *(const float4*)(bias + lane * 4);
    a0 = a0 * inv + b.x; a1 = a1 * inv + b.y;
    a2 = a2 * inv + b.z; a3 = a3 * inv + b.w;

    ushort_t* hp = H + (size_t)n * HD + lane * 4;
    ushort4 o;
    if (MODE == 0) {
        o.x = f2bf(a0 > 0.f ? a0 : 0.f); o.y = f2bf(a1 > 0.f ? a1 : 0.f);
        o.z = f2bf(a2 > 0.f ? a2 : 0.f); o.w = f2bf(a3 > 0.f ? a3 : 0.f);
    } else if (MODE == 1) {
        o.x = f2bf(a0 > 0.f ? a0 : expm1f(a0)); o.y = f2bf(a1 > 0.f ? a1 : expm1f(a1));
        o.z = f2bf(a2 > 0.f ? a2 : expm1f(a2)); o.w = f2bf(a3 > 0.f ? a3 : expm1f(a3));
    } else {
        ushort4 hw = *(const ushort4*)hp;
        float v0 = (bf2f(hw.x) + (a0 > 0.f ? a0 : expm1f(a0))) * 0.5f;
        float v1 = (bf2f(hw.y) + (a1 > 0.f ? a1 : expm1f(a1))) * 0.5f;
        float v2 = (bf2f(hw.z) + (a2 > 0.f ? a2 : expm1f(a2))) * 0.5f;
        float v3 = (bf2f(hw.w) + (a3 > 0.f ? a3 : expm1f(a3))) * 0.5f;
        o.x = f2bf(v0 > 0.f ? v0 : 0.f); o.y = f2bf(v1 > 0.f ? v1 : 0.f);
        o.z = f2bf(v2 > 0.f ? v2 : 0.f); o.w = f2bf(v3 > 0.f ? v3 : 0.f);
    }
    *(ushort4*)hp = o;
}

// ---------------- fused CSR gather + epilogue, layer 2 (H=1, D=64) ----------------
// MODE 0: out[n*64+l] = acc + b                       (tic, offset 0)
// MODE 1: ACC[n*64+l] = acc                           (w)
// MODE 2: out[N_AC*64 + n*64+l] = ((ACC+bw)+(acc+br))*0.5   (rel)
template <int MODE>
__global__ __launch_bounds__(256) void gat2(const int* __restrict__ rp,
                                            const int2* __restrict__ adj,
                                            const ushort_t* __restrict__ zb,
                                            const float* __restrict__ el,
                                            const float* __restrict__ er,
                                            const float* __restrict__ b1,
                                            const float* __restrict__ b2,
                                            float* __restrict__ ACC,
                                            void* __restrict__ out,
                                            const int* __restrict__ flagp, int N) {
    __shared__ float atl[4][CAP];
    __shared__ int   snl[4][CAP];
    const int w = threadIdx.x >> 6, lane = threadIdx.x & 63;
    const int n = blockIdx.x * 4 + w;
    if (n >= N) return;
    const int beg = rp[n], deg = rp[n + 1] - beg;
    const float ern = er[n];

    float ssum = 0.f;
    for (int base = 0; base < deg; base += 64) {
        int i = base + lane;
        if (i < deg) {
            int2 ae = adj[beg + i];
            float x = lrelu_exp(el[ae.x] + ern);
            ssum += x;
            if (i < CAP) {
                atl[w][i] = x * __int_as_float(ae.y);
                snl[w][i] = ae.x;
            }
        }
    }
    #pragma unroll
    for (int o = 32; o > 0; o >>= 1) ssum += __shfl_xor(ssum, o, 64);
    const float inv = 1.f / (ssum + 1e-9f);

    float a = 0.f;
    #pragma unroll 2
    for (int i = 0; i < deg; ++i) {
        int sn; float atv;
        if (i < CAP) {
            sn = snl[w][i];
            atv = atl[w][i];
        } else {
            int2 ae = adj[beg + i];
            sn = ae.x;
            atv = lrelu_exp(el[sn] + ern) * __int_as_float(ae.y);
        }
        a += bf2f(zb[(size_t)sn * DOUT + lane]) * atv;
    }
    a *= inv;

    if (MODE == 0) {
        float v = a + b1[lane];
        size_t o = (size_t)n * DOUT + lane;
        if (flagp[0]) ((float*)out)[o] = v;
        else ((ushort_t*)out)[o] = f2bf(v);
    } else if (MODE == 1) {
        ACC[(size_t)n * DOUT + lane] = a;
    } else {
        float v = ((ACC[(size_t)n * DOUT + lane] + b1[lane]) + (a + b2[lane])) * 0.5f;
        size_t o = (size_t)N_AC * DOUT + (size_t)n * DOUT + lane;
        if (flagp[0]) ((float*)out)[o] = v;
        else ((ushort_t*)out)[o] = f2bf(v);
    }
}

// ---------------- host launch ----------------
extern "C" void kernel_launch(void* const* d_in, const int* in_sizes, int n_in,
                              void* d_out, int out_size, void* d_ws, size_t ws_size,
                              hipStream_t stream) {
    (void)in_sizes; (void)n_in; (void)out_size; (void)ws_size;

    const void* x_ac = d_in[0];
    const void* x_w  = d_in[1];
    const int* src_tic = (const int*)d_in[29];
    const int* dst_tic = (const int*)d_in[30];
    const int* src_w   = (const int*)d_in[31];
    const int* dst_w   = (const int*)d_in[32];
    const int* src_rel = (const int*)d_in[33];
    const int* dst_rel = (const int*)d_in[34];

    float* ws = (float*)d_ws;
    int* FLAG = (int*)ws;

    float* PAR = ws + 16;
    const int o_wtic = 0, o_ww = 400000, o_wrel = 600000;
    const int o_W1t = 1000000, o_W1w = 1032768, o_W1r = 1065536;
    const int o_W2t = 1098304, o_W2w = 1114688, o_W2r = 1131072;
    const int o_al1t = 1147456, o_ar1t = 1147712, o_al1w = 1147968, o_ar1w = 1148224,
              o_al1r = 1148480, o_ar1r = 1148736;
    const int o_b1t = 1148992, o_b1w = 1149248, o_b1r = 1149504;
    const int o_al2t = 1149760, o_ar2t = 1149824, o_al2w = 1149888, o_ar2w = 1149952,
              o_al2r = 1150016, o_ar2r = 1150080;
    const int o_b2t = 1150144, o_b2w = 1150208, o_b2r = 1150272;
    const int o_qel1t = 1150400, o_qer1t = 1150912, o_qel1w = 1151424, o_qer1w = 1151936,
              o_qel1r = 1152448, o_qer1r = 1152960;
    const int o_qel2t = 1153472, o_qer2t = 1153728, o_qel2w = 1153984, o_qer2w = 1154240,
              o_qel2r = 1154496, o_qer2r = 1154752;

    float* EL  = ws + 1160016;                   // 160,000
    float* ER  = ws + 1320016;                   // 160,000
    float* ACC = ws + 1480016;                   // 2,560,000
    ushort_t* Zb  = (ushort_t*)(ws + 4040016);   // 10.24M bf16
    ushort_t* Hac = (ushort_t*)(ws + 9160016);   // 40000x256 bf16
    ushort_t* Hw  = (ushort_t*)(ws + 14280016);  // 20000x256 bf16
    int* IB = (int*)(ws + 16840016);
    int* rp_tic = IB;
    int* rp_w   = IB + 40016;
    int* rp_rel = IB + 60032;
    int* cur    = IB + 80048;
    int2* adj_tic = (int2*)(IB + 120064);
    int2* adj_w   = (int2*)(IB + 920064);
    int2* adj_rel = (int2*)(IB + 1320064);

    // ---- P0: dtype, params, q vectors ----
    detect_dtype<<<1, 256, 0, stream>>>((const ushort_t*)x_ac, FLAG);

    CvtTab ct;
    const int srcIdx[27] = {2,3,4, 5,6,7,8, 9,10,11,12, 13,14,15,16,
                            17,18,19,20, 21,22,23,24, 25,26,27,28};
    const int sizes[27] = {E_TIC, E_W, E_REL,
                           32768,256,256,256, 32768,256,256,256, 32768,256,256,256,
                           16384,64,64,64, 16384,64,64,64, 16384,64,64,64};
    const int offs[27] = {o_wtic,o_ww,o_wrel,
                          o_W1t,o_al1t,o_ar1t,o_b1t, o_W1w,o_al1w,o_ar1w,o_b1w,
                          o_W1r,o_al1r,o_ar1r,o_b1r,
                          o_W2t,o_al2t,o_ar2t,o_b2t, o_W2w,o_al2w,o_ar2w,o_b2w,
                          o_W2r,o_al2r,o_ar2r,o_b2r};
    for (int i = 0; i < 27; ++i) { ct.src[i] = d_in[srcIdx[i]]; ct.n[i] = sizes[i]; ct.off[i] = offs[i]; }
    cvt_inputs<<<27 * 8, 256, 0, stream>>>(ct, PAR, FLAG);

    QTab qt;
    const int qw[12] = {o_W1t,o_W1t, o_W1w,o_W1w, o_W1r,o_W1r, o_W2t,o_W2t, o_W2w,o_W2w, o_W2r,o_W2r};
    const int qa[12] = {o_al1t,o_ar1t, o_al1w,o_ar1w, o_al1r,o_ar1r,
                        o_al2t,o_ar2t, o_al2w,o_ar2w, o_al2r,o_ar2r};
    const int qq[12] = {o_qel1t,o_qer1t, o_qel1w,o_qer1w, o_qel1r,o_qer1r,
                        o_qel2t,o_qer2t, o_qel2w,o_qer2w, o_qel2r,o_qer2r};
    for (int i = 0; i < 12; ++i) {
        qt.woff[i] = qw[i]; qt.aoff[i] = qa[i]; qt.qoff[i] = qq[i];
        qt.K[i] = (i < 6) ? 128 : 256; qt.Hh[i] = (i < 6) ? 4 : 1;
    }
    make_q<<<12, 256, 0, stream>>>(qt, PAR);

    // ---- P0b: CSR builds ----
    hipMemsetAsync(cur, 0, N_AC * 4, stream);
    count_deg<<<(E_TIC + 255) / 256, 256, 0, stream>>>(dst_tic, cur, E_TIC);
    exscan<<<1, 1024, 0, stream>>>(cur, rp_tic, cur, N_AC);
    fill_adj<<<(E_TIC + 255) / 256, 256, 0, stream>>>(src_tic, dst_tic, PAR + o_wtic, cur, adj_tic, E_TIC);

    hipMemsetAsync(cur, 0, N_W * 4, stream);
    count_deg<<<(E_W + 255) / 256, 256, 0, stream>>>(dst_w, cur, E_W);
    exscan<<<1, 1024, 0, stream>>>(cur, rp_w, cur, N_W);
    fill_adj<<<(E_W + 255) / 256, 256, 0, stream>>>(src_w, dst_w, PAR + o_ww, cur, adj_w, E_W);

    hipMemsetAsync(cur, 0, N_W * 4, stream);
    count_deg<<<(E_REL + 255) / 256, 256, 0, stream>>>(dst_rel, cur, E_REL);
    exscan<<<1, 1024, 0, stream>>>(cur, rp_rel, cur, N_W);
    fill_adj<<<(E_REL + 255) / 256, 256, 0, stream>>>(src_rel, dst_rel, PAR + o_wrel, cur, adj_rel, E_REL);

    // ---- P1: tic GAT layer 1 -> Hac ----
    gemm1<<<N_AC / 8, 256, 0, stream>>>(x_ac, FLAG, PAR + o_W1t, Zb);
    elr<<<N_AC / 4, 256, 0, stream>>>(x_ac, FLAG, PAR + o_qel1t, PAR + o_qer1t, EL, ER, N_AC, 128, 4);
    gat1<0><<<N_AC / 4, 256, 0, stream>>>(rp_tic, adj_tic, Zb, EL, ER, PAR + o_b1t, Hac, N_AC);

    // ---- P2: w GAT layer 1 -> Hw (elu) ----
    gemm1<<<N_W / 8, 256, 0, stream>>>(x_w, FLAG, PAR + o_W1w, Zb);
    elr<<<N_W / 4, 256, 0, stream>>>(x_w, FLAG, PAR + o_qel1w, PAR + o_qer1w, EL, ER, N_W, 128, 4);
    gat1<1><<<N_W / 4, 256, 0, stream>>>(rp_w, adj_w, Zb, EL, ER, PAR + o_b1w, Hw, N_W);

    // ---- P3: rel GAT layer 1; combine -> Hw = h_word ----
    gemm1<<<N_AC / 8, 256, 0, stream>>>(x_ac, FLAG, PAR + o_W1r, Zb);
    elr<<<N_AC / 4, 256, 0, stream>>>(x_ac, FLAG, PAR + o_qel1r, nullptr, EL, nullptr, N_AC, 128, 4);
    elr<<<N_W / 4, 256, 0, stream>>>(x_w, FLAG, PAR + o_qer1r, nullptr, ER, nullptr, N_W, 128, 4);
    gat1<2><<<N_W / 4, 256, 0, stream>>>(rp_rel, adj_rel, Zb, EL, ER, PAR + o_b1r, Hw, N_W);

    // ---- P4: tic GAT layer 2 -> out[0 : 40000*64] ----
    gemm2<<<N_AC / 16, 256, 0, stream>>>(Hac, PAR + o_W2t, Zb);
    elr<<<N_AC / 4, 256, 0, stream>>>(Hac, nullptr, PAR + o_qel2t, PAR + o_qer2t, EL, ER, N_AC, 256, 1);
    gat2<0><<<N_AC / 4, 256, 0, stream>>>(rp_tic, adj_tic, Zb, EL, ER,
                                          PAR + o_b2t, nullptr, ACC, d_out, FLAG, N_AC);

    // ---- P5: w GAT layer 2 -> ACC ----
    gemm2<<<N_W / 16, 256, 0, stream>>>(Hw, PAR + o_W2w, Zb);
    elr<<<N_W / 4, 256, 0, stream>>>(Hw, nullptr, PAR + o_qel2w, PAR + o_qer2w, EL, ER, N_W, 256, 1);
    gat2<1><<<N_W / 4, 256, 0, stream>>>(rp_w, adj_w, Zb, EL, ER,
                                         nullptr, nullptr, ACC, d_out, FLAG, N_W);

    // ---- P6: rel GAT layer 2; combine -> out word ----
    gemm2<<<N_AC / 16, 256, 0, stream>>>(Hac, PAR + o_W2r, Zb);
    elr<<<N_AC / 4, 256, 0, stream>>>(Hac, nullptr, PAR + o_qel2r, nullptr, EL, nullptr, N_AC, 256, 1);
    elr<<<N_W / 4, 256, 0, stream>>>(Hw, nullptr, PAR + o_qer2r, nullptr, ER, nullptr, N_W, 256, 1);
    gat2<2><<<N_W / 4, 256, 0, stream>>>(rp_rel, adj_rel, Zb, EL, ER,
                                         PAR + o_b2w, PAR + o_b2r, ACC, d_out, FLAG, N_W);
}

// Round 5
// 803.102 us; speedup vs baseline: 5.5676x; 1.1717x over previous
//
#include <hip/hip_runtime.h>
#include <hip/hip_bf16.h>

typedef unsigned short ushort_t;

// ---------------- constants ----------------
#define N_AC 40000
#define N_W  20000
#define D_IN 128
#define NH   4
#define HD   256   // NH*DH
#define DOUT 64
#define E_TIC 400000
#define E_W   200000
#define E_REL 400000
#define NEG 0.2f
#define CAP 256    // per-wave LDS edge capacity (max degree ~50 expected)

__device__ __forceinline__ float bf2f(ushort_t u) {
    return __uint_as_float(((unsigned int)u) << 16);
}
__device__ __forceinline__ ushort_t f2bf(float v) {
    unsigned u = __float_as_uint(v);
    unsigned r = (u + 0x7fffu + ((u >> 16) & 1u)) >> 16;
    return (ushort_t)r;
}
__device__ __forceinline__ float ldf(const void* p, size_t i, int f) {
    return f ? ((const float*)p)[i] : bf2f(((const ushort_t*)p)[i]);
}
__device__ __forceinline__ float lrelu_exp(float v) {
    v = v > 0.f ? v : NEG * v;
    return __expf(v);
}

// ---------------- dtype autodetect ----------------
__global__ void detect_dtype(const ushort_t* __restrict__ x, int* __restrict__ flag) {
    __shared__ int hit;
    if (threadIdx.x == 0) hit = 0;
    __syncthreads();
    for (int i = threadIdx.x; i < 4096; i += 256) {
        float v = bf2f(x[i]);
        if (!(fabsf(v) <= 1e4f)) atomicOr(&hit, 1);
    }
    __syncthreads();
    if (threadIdx.x == 0) flag[0] = hit ? 1 : 0;
}

// ---------------- canonicalize 27 float inputs to f32 params region ----------------
struct CvtTab { const void* src[27]; int n[27]; int off[27]; };
__global__ __launch_bounds__(256) void cvt_inputs(CvtTab t, float* __restrict__ par,
                                                  const int* __restrict__ flagp) {
    int ent = blockIdx.x >> 3, sub = blockIdx.x & 7;
    int f = flagp[0];
    const void* s = t.src[ent];
    int n = t.n[ent];
    float* d = par + t.off[ent];
    for (int i = sub * 256 + threadIdx.x; i < n; i += 8 * 256)
        d[i] = f ? ((const float*)s)[i] : bf2f(((const ushort_t*)s)[i]);
}

// ---------------- q vectors: q[k][h] = sum_d W[k, h*64+d] * a[h*64+d] ----------------
struct QTab { int woff[12]; int aoff[12]; int qoff[12]; int K[12]; int Hh[12]; };
__global__ __launch_bounds__(256) void make_q(QTab t, float* __restrict__ par) {
    int b = blockIdx.x;
    int k = threadIdx.x;
    int K = t.K[b], Hh = t.Hh[b];
    if (k >= K) return;
    const float* W = par + t.woff[b];
    const float* a = par + t.aoff[b];
    float* q = par + t.qoff[b];
    int HDc = Hh * 64;
    for (int h = 0; h < Hh; ++h) {
        float s = 0.f;
        for (int d = 0; d < 64; ++d) s += W[(size_t)k * HDc + h * 64 + d] * a[h * 64 + d];
        q[k * Hh + h] = s;
    }
}

// ---------------- CSR build ----------------
__global__ __launch_bounds__(256) void count_deg(const int* __restrict__ dst,
                                                 int* __restrict__ cnt, int E) {
    int e = blockIdx.x * 256 + threadIdx.x;
    if (e < E) atomicAdd(&cnt[dst[e]], 1);
}

// 3-phase parallel exclusive scan (N <= 256*256)
__global__ __launch_bounds__(256) void scan_bsum(const int* __restrict__ cnt,
                                                 int* __restrict__ bsum, int N) {
    __shared__ int red[256];
    int i = blockIdx.x * 256 + threadIdx.x;
    red[threadIdx.x] = (i < N) ? cnt[i] : 0;
    __syncthreads();
    #pragma unroll
    for (int o = 128; o > 0; o >>= 1) {
        if (threadIdx.x < o) red[threadIdx.x] += red[threadIdx.x + o];
        __syncthreads();
    }
    if (threadIdx.x == 0) bsum[blockIdx.x] = red[0];
}

__global__ __launch_bounds__(256) void scan_top(int* __restrict__ bsum, int B) {
    __shared__ int sc[256];
    const int t = threadIdx.x;
    int v = (t < B) ? bsum[t] : 0;
    sc[t] = v;
    __syncthreads();
    #pragma unroll
    for (int o = 1; o < 256; o <<= 1) {
        int u = (t >= o) ? sc[t - o] : 0;
        __syncthreads();
        sc[t] += u;
        __syncthreads();
    }
    if (t < B) bsum[t] = sc[t] - v;   // exclusive
}

__global__ __launch_bounds__(256) void scan_out(const int* __restrict__ cnt,
                                                const int* __restrict__ bsum,
                                                int* __restrict__ rowptr,
                                                int* __restrict__ cur, int N) {
    __shared__ int sc[256];
    const int t = threadIdx.x;
    int i = blockIdx.x * 256 + t;
    int v = (i < N) ? cnt[i] : 0;
    sc[t] = v;
    __syncthreads();
    #pragma unroll
    for (int o = 1; o < 256; o <<= 1) {
        int u = (t >= o) ? sc[t - o] : 0;
        __syncthreads();
        sc[t] += u;
        __syncthreads();
    }
    int ex = sc[t] - v + bsum[blockIdx.x];
    if (i < N) {
        rowptr[i] = ex;
        cur[i] = ex;
        if (i == N - 1) rowptr[N] = ex + v;
    }
}

__global__ __launch_bounds__(256) void fill_adj(const int* __restrict__ src,
                                                const int* __restrict__ dst,
                                                const float* __restrict__ ew,
                                                int* __restrict__ cur,
                                                int2* __restrict__ adj, int E) {
    int e = blockIdx.x * 256 + threadIdx.x;
    if (e >= E) return;
    int pos = atomicAdd(&cur[dst[e]], 1);
    adj[pos] = make_int2(src[e], __float_as_int(ew[e]));
}

// ---------------- GEMM L1: X(N x 128) @ Wf32(128 x 256) -> Zb(bf16 N x 256)
__global__ __launch_bounds__(256) void gemm1(const void* __restrict__ X,
                                             const int* __restrict__ flagp,
                                             const float* __restrict__ Wf,
                                             ushort_t* __restrict__ Zb) {
    __shared__ alignas(16) float Wl[32 * 256];
    __shared__ alignas(16) float xs[128][8];
    const int row0 = blockIdx.x * 8;
    const int tid = threadIdx.x;
    const int f = flagp[0];

    for (int idx = tid; idx < 8 * 128; idx += 256) {
        int r = idx >> 7, k = idx & 127;
        xs[k][r] = ldf(X, (size_t)(row0 + r) * D_IN + k, f);
    }
    float acc[8] = {0.f,0.f,0.f,0.f,0.f,0.f,0.f,0.f};
    for (int kt = 0; kt < 128; kt += 32) {
        for (int idx = tid; idx < (32 * 256) / 4; idx += 256)
            ((float4*)Wl)[idx] = ((const float4*)(Wf + (size_t)kt * 256))[idx];
        __syncthreads();
        #pragma unroll
        for (int k = 0; k < 32; ++k) {
            float w = Wl[k * 256 + tid];
            float4 xa = *(const float4*)&xs[kt + k][0];
            float4 xb = *(const float4*)&xs[kt + k][4];
            acc[0] += xa.x * w; acc[1] += xa.y * w;
            acc[2] += xa.z * w; acc[3] += xa.w * w;
            acc[4] += xb.x * w; acc[5] += xb.y * w;
            acc[6] += xb.z * w; acc[7] += xb.w * w;
        }
        __syncthreads();
    }
    #pragma unroll
    for (int r = 0; r < 8; ++r)
        Zb[(size_t)(row0 + r) * HD + tid] = f2bf(acc[r]);
}

// ---------------- GEMM L2: Hb(bf16 N x 256) @ Wf32(256 x 64) -> Zb(bf16 N x 64)
__global__ __launch_bounds__(256) void gemm2(const ushort_t* __restrict__ Hb,
                                             const float* __restrict__ Wf,
                                             ushort_t* __restrict__ Zb) {
    __shared__ alignas(16) float Wl[128 * 64];
    __shared__ alignas(16) ushort_t As[16 * 256];
    const int row0 = blockIdx.x * 16;
    const int tid = threadIdx.x;

    for (int idx = tid; idx < (16 * 256) / 8; idx += 256)
        ((uint4*)As)[idx] = ((const uint4*)(Hb + (size_t)row0 * HD))[idx];

    const int col = tid & 63, rq = tid >> 6;
    float acc[4] = {0.f,0.f,0.f,0.f};
    for (int kt = 0; kt < 256; kt += 128) {
        for (int idx = tid; idx < (128 * 64) / 4; idx += 256)
            ((float4*)Wl)[idx] = ((const float4*)(Wf + (size_t)kt * 64))[idx];
        __syncthreads();
        #pragma unroll 8
        for (int k = 0; k < 128; ++k) {
            float w = Wl[k * 64 + col];
            #pragma unroll
            for (int i = 0; i < 4; ++i)
                acc[i] += bf2f(As[(rq * 4 + i) * HD + kt + k]) * w;
        }
        __syncthreads();
    }
    #pragma unroll
    for (int i = 0; i < 4; ++i)
        Zb[(size_t)(row0 + rq * 4 + i) * DOUT + col] = f2bf(acc[i]);
}

// ---------------- el/er: out[n][h] = x[n] . q[:,h]  (one wave per node)
__global__ __launch_bounds__(256) void elr(const void* __restrict__ X,
                                           const int* __restrict__ flagp,
                                           const float* __restrict__ qL,
                                           const float* __restrict__ qR,
                                           float* __restrict__ el,
                                           float* __restrict__ er,
                                           int N, int D, int Hh) {
    __shared__ float qsL[512], qsR[512];
    const int tid = threadIdx.x;
    const int f = flagp ? flagp[0] : 0;
    const int tot = D * Hh;
    for (int i = tid; i < tot; i += 256) {
        qsL[i] = qL[i];
        if (qR) qsR[i] = qR[i];
    }
    __syncthreads();
    const int wid = tid >> 6, lane = tid & 63;
    const int n = blockIdx.x * 4 + wid;
    if (n >= N) return;
    const int J = D >> 6;
    float x[4];
    for (int j = 0; j < J; ++j) x[j] = ldf(X, (size_t)n * D + j * 64 + lane, f);
    for (int h = 0; h < Hh; ++h) {
        float v = 0.f;
        for (int j = 0; j < J; ++j) v += x[j] * qsL[(j * 64 + lane) * Hh + h];
        #pragma unroll
        for (int o = 32; o > 0; o >>= 1) v += __shfl_down(v, o, 64);
        if (lane == 0) el[n * Hh + h] = v;
        if (qR) {
            float u = 0.f;
            for (int j = 0; j < J; ++j) u += x[j] * qsR[(j * 64 + lane) * Hh + h];
            #pragma unroll
            for (int o = 32; o > 0; o >>= 1) u += __shfl_down(u, o, 64);
            if (lane == 0) er[n * Hh + h] = u;
        }
    }
}

// ---------------- fused CSR gather, layer 1 (H=4, D=256) ----------------
template <int MODE>
__global__ __launch_bounds__(256) void gat1(const int* __restrict__ rp,
                                            const int2* __restrict__ adj,
                                            const ushort_t* __restrict__ zb,
                                            const float* __restrict__ el,
                                            const float* __restrict__ er,
                                            const float* __restrict__ bias,
                                            ushort_t* __restrict__ H, int N) {
    __shared__ float atl[4][CAP * 4];   // exp*ew per (edge, head)
    __shared__ int   snl[4][CAP];       // src node per edge
    const int w = threadIdx.x >> 6, lane = threadIdx.x & 63;
    const int n = blockIdx.x * 4 + w;
    if (n >= N) return;
    const int h = lane >> 4;
    const int beg = rp[n], deg = rp[n + 1] - beg;
    const float4* el4 = (const float4*)el;
    const float4 ern = ((const float4*)er)[n];

    // ---- pass A ----
    float4 ss = make_float4(0.f, 0.f, 0.f, 0.f);
    for (int base = 0; base < deg; base += 64) {
        int i = base + lane;
        if (i < deg) {
            int2 ae = adj[beg + i];
            float4 e = el4[ae.x];
            float x0 = lrelu_exp(e.x + ern.x);
            float x1 = lrelu_exp(e.y + ern.y);
            float x2 = lrelu_exp(e.z + ern.z);
            float x3 = lrelu_exp(e.w + ern.w);
            ss.x += x0; ss.y += x1; ss.z += x2; ss.w += x3;
            if (i < CAP) {
                float ew = __int_as_float(ae.y);
                float4* dst4 = (float4*)&atl[w][i * 4];
                *dst4 = make_float4(x0 * ew, x1 * ew, x2 * ew, x3 * ew);
                snl[w][i] = ae.x;
            }
        }
    }
    #pragma unroll
    for (int o = 32; o > 0; o >>= 1) {
        ss.x += __shfl_xor(ss.x, o, 64);
        ss.y += __shfl_xor(ss.y, o, 64);
        ss.z += __shfl_xor(ss.z, o, 64);
        ss.w += __shfl_xor(ss.w, o, 64);
    }
    const float sh = (h == 0) ? ss.x : (h == 1) ? ss.y : (h == 2) ? ss.z : ss.w;
    const float inv = 1.f / (sh + 1e-9f);
    const float erh = (h == 0) ? ern.x : (h == 1) ? ern.y : (h == 2) ? ern.z : ern.w;

    // ---- pass B ----
    float a0 = 0.f, a1 = 0.f, a2 = 0.f, a3 = 0.f;
    #pragma unroll 2
    for (int i = 0; i < deg; ++i) {
        int sn; float atv;
        if (i < CAP) {
            sn = snl[w][i];
            atv = atl[w][i * 4 + h];
        } else {                         // rare overflow: recompute
            int2 ae = adj[beg + i];
            sn = ae.x;
            atv = lrelu_exp(el[sn * 4 + h] + erh) * __int_as_float(ae.y);
        }
        ushort4 zv = *(const ushort4*)(zb + (size_t)sn * HD + lane * 4);
        a0 += bf2f(zv.x) * atv; a1 += bf2f(zv.y) * atv;
        a2 += bf2f(zv.z) * atv; a3 += bf2f(zv.w) * atv;
    }
    float4 b = *(const float4*)(bias + lane * 4);
    a0 = a0 * inv + b.x; a1 = a1 * inv + b.y;
    a2 = a2 * inv + b.z; a3 = a3 * inv + b.w;

    ushort_t* hp = H + (size_t)n * HD + lane * 4;
    ushort4 o;
    if (MODE == 0) {
        o.x = f2bf(a0 > 0.f ? a0 : 0.f); o.y = f2bf(a1 > 0.f ? a1 : 0.f);
        o.z = f2bf(a2 > 0.f ? a2 : 0.f); o.w = f2bf(a3 > 0.f ? a3 : 0.f);
    } else if (MODE == 1) {
        o.x = f2bf(a0 > 0.f ? a0 : expm1f(a0)); o.y = f2bf(a1 > 0.f ? a1 : expm1f(a1));
        o.z = f2bf(a2 > 0.f ? a2 : expm1f(a2)); o.w = f2bf(a3 > 0.f ? a3 : expm1f(a3));
    } else {
        ushort4 hw = *(const ushort4*)hp;
        float v0 = (bf2f(hw.x) + (a0 > 0.f ? a0 : expm1f(a0))) * 0.5f;
        float v1 = (bf2f(hw.y) + (a1 > 0.f ? a1 : expm1f(a1))) * 0.5f;
        float v2 = (bf2f(hw.z) + (a2 > 0.f ? a2 : expm1f(a2))) * 0.5f;
        float v3 = (bf2f(hw.w) + (a3 > 0.f ? a3 : expm1f(a3))) * 0.5f;
        o.x = f2bf(v0 > 0.f ? v0 : 0.f); o.y = f2bf(v1 > 0.f ? v1 : 0.f);
        o.z = f2bf(v2 > 0.f ? v2 : 0.f); o.w = f2bf(v3 > 0.f ? v3 : 0.f);
    }
    *(ushort4*)hp = o;
}

// ---------------- fused CSR gather + epilogue, layer 2 (H=1, D=64) ----------------
template <int MODE>
__global__ __launch_bounds__(256) void gat2(const int* __restrict__ rp,
                                            const int2* __restrict__ adj,
                                            const ushort_t* __restrict__ zb,
                                            const float* __restrict__ el,
                                            const float* __restrict__ er,
                                            const float* __restrict__ b1,
                                            const float* __restrict__ b2,
                                            float* __restrict__ ACC,
                                            void* __restrict__ out,
                                            const int* __restrict__ flagp, int N) {
    __shared__ float atl[4][CAP];
    __shared__ int   snl[4][CAP];
    const int w = threadIdx.x >> 6, lane = threadIdx.x & 63;
    const int n = blockIdx.x * 4 + w;
    if (n >= N) return;
    const int beg = rp[n], deg = rp[n + 1] - beg;
    const float ern = er[n];

    float ssum = 0.f;
    for (int base = 0; base < deg; base += 64) {
        int i = base + lane;
        if (i < deg) {
            int2 ae = adj[beg + i];
            float x = lrelu_exp(el[ae.x] + ern);
            ssum += x;
            if (i < CAP) {
                atl[w][i] = x * __int_as_float(ae.y);
                snl[w][i] = ae.x;
            }
        }
    }
    #pragma unroll
    for (int o = 32; o > 0; o >>= 1) ssum += __shfl_xor(ssum, o, 64);
    const float inv = 1.f / (ssum + 1e-9f);

    float a = 0.f;
    #pragma unroll 2
    for (int i = 0; i < deg; ++i) {
        int sn; float atv;
        if (i < CAP) {
            sn = snl[w][i];
            atv = atl[w][i];
        } else {
            int2 ae = adj[beg + i];
            sn = ae.x;
            atv = lrelu_exp(el[sn] + ern) * __int_as_float(ae.y);
        }
        a += bf2f(zb[(size_t)sn * DOUT + lane]) * atv;
    }
    a *= inv;

    if (MODE == 0) {
        float v = a + b1[lane];
        size_t o = (size_t)n * DOUT + lane;
        if (flagp[0]) ((float*)out)[o] = v;
        else ((ushort_t*)out)[o] = f2bf(v);
    } else if (MODE == 1) {
        ACC[(size_t)n * DOUT + lane] = a;
    } else {
        float v = ((ACC[(size_t)n * DOUT + lane] + b1[lane]) + (a + b2[lane])) * 0.5f;
        size_t o = (size_t)N_AC * DOUT + (size_t)n * DOUT + lane;
        if (flagp[0]) ((float*)out)[o] = v;
        else ((ushort_t*)out)[o] = f2bf(v);
    }
}

// ---------------- host launch ----------------
extern "C" void kernel_launch(void* const* d_in, const int* in_sizes, int n_in,
                              void* d_out, int out_size, void* d_ws, size_t ws_size,
                              hipStream_t stream) {
    (void)in_sizes; (void)n_in; (void)out_size; (void)ws_size;

    const void* x_ac = d_in[0];
    const void* x_w  = d_in[1];
    const int* src_tic = (const int*)d_in[29];
    const int* dst_tic = (const int*)d_in[30];
    const int* src_w   = (const int*)d_in[31];
    const int* dst_w   = (const int*)d_in[32];
    const int* src_rel = (const int*)d_in[33];
    const int* dst_rel = (const int*)d_in[34];

    float* ws = (float*)d_ws;
    int* FLAG = (int*)ws;

    float* PAR = ws + 16;
    const int o_wtic = 0, o_ww = 400000, o_wrel = 600000;
    const int o_W1t = 1000000, o_W1w = 1032768, o_W1r = 1065536;
    const int o_W2t = 1098304, o_W2w = 1114688, o_W2r = 1131072;
    const int o_al1t = 1147456, o_ar1t = 1147712, o_al1w = 1147968, o_ar1w = 1148224,
              o_al1r = 1148480, o_ar1r = 1148736;
    const int o_b1t = 1148992, o_b1w = 1149248, o_b1r = 1149504;
    const int o_al2t = 1149760, o_ar2t = 1149824, o_al2w = 1149888, o_ar2w = 1149952,
              o_al2r = 1150016, o_ar2r = 1150080;
    const int o_b2t = 1150144, o_b2w = 1150208, o_b2r = 1150272;
    const int o_qel1t = 1150400, o_qer1t = 1150912, o_qel1w = 1151424, o_qer1w = 1151936,
              o_qel1r = 1152448, o_qer1r = 1152960;
    const int o_qel2t = 1153472, o_qer2t = 1153728, o_qel2w = 1153984, o_qer2w = 1154240,
              o_qel2r = 1154496, o_qer2r = 1154752;

    float* EL  = ws + 1160016;                   // 160,000
    float* ER  = ws + 1320016;                   // 160,000
    float* ACC = ws + 1480016;                   // 2,560,000
    ushort_t* Zb  = (ushort_t*)(ws + 4040016);   // 10.24M bf16
    ushort_t* Hac = (ushort_t*)(ws + 9160016);   // 40000x256 bf16
    ushort_t* Hw  = (ushort_t*)(ws + 14280016);  // 20000x256 bf16
    int* IB = (int*)(ws + 16840016);
    int* rp_tic = IB;
    int* rp_w   = IB + 40016;
    int* rp_rel = IB + 60032;
    int* cur    = IB + 80048;
    int2* adj_tic = (int2*)(IB + 120064);
    int2* adj_w   = (int2*)(IB + 920064);
    int2* adj_rel = (int2*)(IB + 1320064);
    int* bsum   = IB + 2120064;                  // 256 ints

    // ---- P0: dtype, params, q vectors ----
    detect_dtype<<<1, 256, 0, stream>>>((const ushort_t*)x_ac, FLAG);

    CvtTab ct;
    const int srcIdx[27] = {2,3,4, 5,6,7,8, 9,10,11,12, 13,14,15,16,
                            17,18,19,20, 21,22,23,24, 25,26,27,28};
    const int sizes[27] = {E_TIC, E_W, E_REL,
                           32768,256,256,256, 32768,256,256,256, 32768,256,256,256,
                           16384,64,64,64, 16384,64,64,64, 16384,64,64,64};
    const int offs[27] = {o_wtic,o_ww,o_wrel,
                          o_W1t,o_al1t,o_ar1t,o_b1t, o_W1w,o_al1w,o_ar1w,o_b1w,
                          o_W1r,o_al1r,o_ar1r,o_b1r,
                          o_W2t,o_al2t,o_ar2t,o_b2t, o_W2w,o_al2w,o_ar2w,o_b2w,
                          o_W2r,o_al2r,o_ar2r,o_b2r};
    for (int i = 0; i < 27; ++i) { ct.src[i] = d_in[srcIdx[i]]; ct.n[i] = sizes[i]; ct.off[i] = offs[i]; }
    cvt_inputs<<<27 * 8, 256, 0, stream>>>(ct, PAR, FLAG);

    QTab qt;
    const int qw[12] = {o_W1t,o_W1t, o_W1w,o_W1w, o_W1r,o_W1r, o_W2t,o_W2t, o_W2w,o_W2w, o_W2r,o_W2r};
    const int qa[12] = {o_al1t,o_ar1t, o_al1w,o_ar1w, o_al1r,o_ar1r,
                        o_al2t,o_ar2t, o_al2w,o_ar2w, o_al2r,o_ar2r};
    const int qq[12] = {o_qel1t,o_qer1t, o_qel1w,o_qer1w, o_qel1r,o_qer1r,
                        o_qel2t,o_qer2t, o_qel2w,o_qer2w, o_qel2r,o_qer2r};
    for (int i = 0; i < 12; ++i) {
        qt.woff[i] = qw[i]; qt.aoff[i] = qa[i]; qt.qoff[i] = qq[i];
        qt.K[i] = (i < 6) ? 128 : 256; qt.Hh[i] = (i < 6) ? 4 : 1;
    }
    make_q<<<12, 256, 0, stream>>>(qt, PAR);

    // ---- P0b: CSR builds (parallel 3-phase scan) ----
    {
        const int B = (N_AC + 255) / 256;
        hipMemsetAsync(cur, 0, N_AC * 4, stream);
        count_deg<<<(E_TIC + 255) / 256, 256, 0, stream>>>(dst_tic, cur, E_TIC);
        scan_bsum<<<B, 256, 0, stream>>>(cur, bsum, N_AC);
        scan_top<<<1, 256, 0, stream>>>(bsum, B);
        scan_out<<<B, 256, 0, stream>>>(cur, bsum, rp_tic, cur, N_AC);
        fill_adj<<<(E_TIC + 255) / 256, 256, 0, stream>>>(src_tic, dst_tic, PAR + o_wtic, cur, adj_tic, E_TIC);
    }
    {
        const int B = (N_W + 255) / 256;
        hipMemsetAsync(cur, 0, N_W * 4, stream);
        count_deg<<<(E_W + 255) / 256, 256, 0, stream>>>(dst_w, cur, E_W);
        scan_bsum<<<B, 256, 0, stream>>>(cur, bsum, N_W);
        scan_top<<<1, 256, 0, stream>>>(bsum, B);
        scan_out<<<B, 256, 0, stream>>>(cur, bsum, rp_w, cur, N_W);
        fill_adj<<<(E_W + 255) / 256, 256, 0, stream>>>(src_w, dst_w, PAR + o_ww, cur, adj_w, E_W);
    }
    {
        const int B = (N_W + 255) / 256;
        hipMemsetAsync(cur, 0, N_W * 4, stream);
        count_deg<<<(E_REL + 255) / 256, 256, 0, stream>>>(dst_rel, cur, E_REL);
        scan_bsum<<<B, 256, 0, stream>>>(cur, bsum, N_W);
        scan_top<<<1, 256, 0, stream>>>(bsum, B);
        scan_out<<<B, 256, 0, stream>>>(cur, bsum, rp_rel, cur, N_W);
        fill_adj<<<(E_REL + 255) / 256, 256, 0, stream>>>(src_rel, dst_rel, PAR + o_wrel, cur, adj_rel, E_REL);
    }

    // ---- P1: tic GAT layer 1 -> Hac ----
    gemm1<<<N_AC / 8, 256, 0, stream>>>(x_ac, FLAG, PAR + o_W1t, Zb);
    elr<<<N_AC / 4, 256, 0, stream>>>(x_ac, FLAG, PAR + o_qel1t, PAR + o_qer1t, EL, ER, N_AC, 128, 4);
    gat1<0><<<N_AC / 4, 256, 0, stream>>>(rp_tic, adj_tic, Zb, EL, ER, PAR + o_b1t, Hac, N_AC);

    // ---- P2: w GAT layer 1 -> Hw (elu) ----
    gemm1<<<N_W / 8, 256, 0, stream>>>(x_w, FLAG, PAR + o_W1w, Zb);
    elr<<<N_W / 4, 256, 0, stream>>>(x_w, FLAG, PAR + o_qel1w, PAR + o_qer1w, EL, ER, N_W, 128, 4);
    gat1<1><<<N_W / 4, 256, 0, stream>>>(rp_w, adj_w, Zb, EL, ER, PAR + o_b1w, Hw, N_W);

    // ---- P3: rel GAT layer 1; combine -> Hw = h_word ----
    gemm1<<<N_AC / 8, 256, 0, stream>>>(x_ac, FLAG, PAR + o_W1r, Zb);
    elr<<<N_AC / 4, 256, 0, stream>>>(x_ac, FLAG, PAR + o_qel1r, nullptr, EL, nullptr, N_AC, 128, 4);
    elr<<<N_W / 4, 256, 0, stream>>>(x_w, FLAG, PAR + o_qer1r, nullptr, ER, nullptr, N_W, 128, 4);
    gat1<2><<<N_W / 4, 256, 0, stream>>>(rp_rel, adj_rel, Zb, EL, ER, PAR + o_b1r, Hw, N_W);

    // ---- P4: tic GAT layer 2 -> out[0 : 40000*64] ----
    gemm2<<<N_AC / 16, 256, 0, stream>>>(Hac, PAR + o_W2t, Zb);
    elr<<<N_AC / 4, 256, 0, stream>>>(Hac, nullptr, PAR + o_qel2t, PAR + o_qer2t, EL, ER, N_AC, 256, 1);
    gat2<0><<<N_AC / 4, 256, 0, stream>>>(rp_tic, adj_tic, Zb, EL, ER,
                                          PAR + o_b2t, nullptr, ACC, d_out, FLAG, N_AC);

    // ---- P5: w GAT layer 2 -> ACC ----
    gemm2<<<N_W / 16, 256, 0, stream>>>(Hw, PAR + o_W2w, Zb);
    elr<<<N_W / 4, 256, 0, stream>>>(Hw, nullptr, PAR + o_qel2w, PAR + o_qer2w, EL, ER, N_W, 256, 1);
    gat2<1><<<N_W / 4, 256, 0, stream>>>(rp_w, adj_w, Zb, EL, ER,
                                         nullptr, nullptr, ACC, d_out, FLAG, N_W);

    // ---- P6: rel GAT layer 2; combine -> out word ----
    gemm2<<<N_AC / 16, 256, 0, stream>>>(Hac, PAR + o_W2r, Zb);
    elr<<<N_AC / 4, 256, 0, stream>>>(Hac, nullptr, PAR + o_qel2r, nullptr, EL, nullptr, N_AC, 256, 1);
    elr<<<N_W / 4, 256, 0, stream>>>(Hw, nullptr, PAR + o_qer2r, nullptr, ER, nullptr, N_W, 256, 1);
    gat2<2><<<N_W / 4, 256, 0, stream>>>(rp_rel, adj_rel, Zb, EL, ER,
                                         PAR + o_b2w, PAR + o_b2r, ACC, d_out, FLAG, N_W);
}

// Round 6
// 611.990 us; speedup vs baseline: 7.3063x; 1.3123x over previous
//
#include <hip/hip_runtime.h>
#include <hip/hip_bf16.h>

typedef unsigned short ushort_t;
typedef __attribute__((ext_vector_type(8))) short bf16x8;
typedef __attribute__((ext_vector_type(4))) float f32x4;

// ---------------- constants ----------------
#define N_AC 40000
#define N_W  20000
#define D_IN 128
#define NH   4
#define HD   256   // NH*DH
#define DOUT 64
#define E_TIC 400000
#define E_W   200000
#define E_REL 400000
#define NEG 0.2f
#define CAP 256

__device__ __forceinline__ float bf2f(ushort_t u) {
    return __uint_as_float(((unsigned int)u) << 16);
}
__device__ __forceinline__ ushort_t f2bf(float v) {
    unsigned u = __float_as_uint(v);
    unsigned r = (u + 0x7fffu + ((u >> 16) & 1u)) >> 16;
    return (ushort_t)r;
}
__device__ __forceinline__ float ldf(const void* p, size_t i, int f) {
    return f ? ((const float*)p)[i] : bf2f(((const ushort_t*)p)[i]);
}
__device__ __forceinline__ float lrelu_exp(float v) {
    v = v > 0.f ? v : NEG * v;
    return __expf(v);
}

// ---------------- dtype autodetect ----------------
__global__ void detect_dtype(const ushort_t* __restrict__ x, int* __restrict__ flag) {
    __shared__ int hit;
    if (threadIdx.x == 0) hit = 0;
    __syncthreads();
    for (int i = threadIdx.x; i < 4096; i += 256) {
        float v = bf2f(x[i]);
        if (!(fabsf(v) <= 1e4f)) atomicOr(&hit, 1);
    }
    __syncthreads();
    if (threadIdx.x == 0) flag[0] = hit ? 1 : 0;
}

// ---------------- canonicalize 27 float inputs to f32 params region ----------------
struct CvtTab { const void* src[27]; int n[27]; int off[27]; };
__global__ __launch_bounds__(256) void cvt_inputs(CvtTab t, float* __restrict__ par,
                                                  const int* __restrict__ flagp) {
    int ent = blockIdx.x >> 3, sub = blockIdx.x & 7;
    int f = flagp[0];
    const void* s = t.src[ent];
    int n = t.n[ent];
    float* d = par + t.off[ent];
    for (int i = sub * 256 + threadIdx.x; i < n; i += 8 * 256)
        d[i] = f ? ((const float*)s)[i] : bf2f(((const ushort_t*)s)[i]);
}

// ---------------- q vectors ----------------
struct QTab { int woff[12]; int aoff[12]; int qoff[12]; int K[12]; int Hh[12]; };
__global__ __launch_bounds__(256) void make_q(QTab t, float* __restrict__ par) {
    int b = blockIdx.x;
    int k = threadIdx.x;
    int K = t.K[b], Hh = t.Hh[b];
    if (k >= K) return;
    const float* W = par + t.woff[b];
    const float* a = par + t.aoff[b];
    float* q = par + t.qoff[b];
    int HDc = Hh * 64;
    for (int h = 0; h < Hh; ++h) {
        float s = 0.f;
        for (int d = 0; d < 64; ++d) s += W[(size_t)k * HDc + h * 64 + d] * a[h * 64 + d];
        q[k * Hh + h] = s;
    }
}

// ---------------- pack W^T to bf16 (N x K row-major) ----------------
struct PTab { int woff[6]; int toff[6]; int Klog[6]; int N[6]; };
__global__ __launch_bounds__(256) void pack_wt(PTab t, const float* __restrict__ par,
                                               ushort_t* __restrict__ wt) {
    int m = blockIdx.x >> 4, sub = blockIdx.x & 15;
    int Klog = t.Klog[m], K = 1 << Klog, Nn = t.N[m];
    int tot = K * Nn;
    const float* Wp = par + t.woff[m];
    ushort_t* d = wt + t.toff[m];
    for (int i = sub * 256 + threadIdx.x; i < tot; i += 16 * 256) {
        int n = i >> Klog, k = i & (K - 1);
        d[i] = f2bf(Wp[(size_t)k * Nn + n]);
    }
}

// ---------------- CSR build ----------------
__global__ __launch_bounds__(256) void count_deg(const int* __restrict__ dst,
                                                 int* __restrict__ cnt, int E) {
    int e = blockIdx.x * 256 + threadIdx.x;
    if (e < E) atomicAdd(&cnt[dst[e]], 1);
}

__global__ __launch_bounds__(256) void scan_bsum(const int* __restrict__ cnt,
                                                 int* __restrict__ bsum, int N) {
    __shared__ int red[256];
    int i = blockIdx.x * 256 + threadIdx.x;
    red[threadIdx.x] = (i < N) ? cnt[i] : 0;
    __syncthreads();
    #pragma unroll
    for (int o = 128; o > 0; o >>= 1) {
        if (threadIdx.x < o) red[threadIdx.x] += red[threadIdx.x + o];
        __syncthreads();
    }
    if (threadIdx.x == 0) bsum[blockIdx.x] = red[0];
}

__global__ __launch_bounds__(256) void scan_top(int* __restrict__ bsum, int B) {
    __shared__ int sc[256];
    const int t = threadIdx.x;
    int v = (t < B) ? bsum[t] : 0;
    sc[t] = v;
    __syncthreads();
    #pragma unroll
    for (int o = 1; o < 256; o <<= 1) {
        int u = (t >= o) ? sc[t - o] : 0;
        __syncthreads();
        sc[t] += u;
        __syncthreads();
    }
    if (t < B) bsum[t] = sc[t] - v;
}

__global__ __launch_bounds__(256) void scan_out(const int* __restrict__ cnt,
                                                const int* __restrict__ bsum,
                                                int* __restrict__ rowptr,
                                                int* __restrict__ cur, int N) {
    __shared__ int sc[256];
    const int t = threadIdx.x;
    int i = blockIdx.x * 256 + t;
    int v = (i < N) ? cnt[i] : 0;
    sc[t] = v;
    __syncthreads();
    #pragma unroll
    for (int o = 1; o < 256; o <<= 1) {
        int u = (t >= o) ? sc[t - o] : 0;
        __syncthreads();
        sc[t] += u;
        __syncthreads();
    }
    int ex = sc[t] - v + bsum[blockIdx.x];
    if (i < N) {
        rowptr[i] = ex;
        cur[i] = ex;
        if (i == N - 1) rowptr[N] = ex + v;
    }
}

__global__ __launch_bounds__(256) void fill_adj(const int* __restrict__ src,
                                                const int* __restrict__ dst,
                                                const float* __restrict__ ew,
                                                int* __restrict__ cur,
                                                int2* __restrict__ adj, int E) {
    int e = blockIdx.x * 256 + threadIdx.x;
    if (e >= E) return;
    int pos = atomicAdd(&cur[dst[e]], 1);
    adj[pos] = make_int2(src[e], __float_as_int(ew[e]));
}

// ---------------- MFMA GEMM L1: X(N x 128) @ W(128 x 256) -> Zb(bf16 N x 256)
// A-frag: lane l holds A[l&15][(l>>4)*8 + j]  (8 contiguous k, 16B load)
// B-frag from WT (N x K row-major): lane l holds W^T[col0+(l&15)][(l>>4)*8 + j]
// D: lane l, reg r -> row (l>>4)*4 + r, col l&15
__global__ __launch_bounds__(256) void mgemm1(const void* __restrict__ X,
                                              const int* __restrict__ flagp,
                                              const ushort_t* __restrict__ WT,
                                              ushort_t* __restrict__ Zb, int N) {
    const int w = threadIdx.x >> 6, l = threadIdx.x & 63;
    const int row0 = blockIdx.x * 16;
    const int lr = l & 15, lk = l >> 4;
    const int f = flagp[0];

    bf16x8 a[4];
    if (!f) {
        const ushort_t* xp = (const ushort_t*)X + (size_t)(row0 + lr) * 128 + lk * 8;
        #pragma unroll
        for (int ks = 0; ks < 4; ++ks) a[ks] = *(const bf16x8*)(xp + ks * 32);
    } else {
        const float* xp = (const float*)X + (size_t)(row0 + lr) * 128 + lk * 8;
        #pragma unroll
        for (int ks = 0; ks < 4; ++ks)
            #pragma unroll
            for (int j = 0; j < 8; ++j) a[ks][j] = (short)f2bf(xp[ks * 32 + j]);
    }

    f32x4 acc[4] = {{0.f,0.f,0.f,0.f},{0.f,0.f,0.f,0.f},{0.f,0.f,0.f,0.f},{0.f,0.f,0.f,0.f}};
    const int col0 = w * 64;
    #pragma unroll
    for (int ks = 0; ks < 4; ++ks) {
        #pragma unroll
        for (int nt = 0; nt < 4; ++nt) {
            bf16x8 b = *(const bf16x8*)(WT + (size_t)(col0 + nt * 16 + lr) * 128 + ks * 32 + lk * 8);
            acc[nt] = __builtin_amdgcn_mfma_f32_16x16x32_bf16(a[ks], b, acc[nt], 0, 0, 0);
        }
    }
    #pragma unroll
    for (int nt = 0; nt < 4; ++nt)
        #pragma unroll
        for (int r = 0; r < 4; ++r)
            Zb[(size_t)(row0 + lk * 4 + r) * HD + col0 + nt * 16 + lr] = f2bf(acc[nt][r]);
}

// ---------------- MFMA GEMM L2: Hb(bf16 N x 256) @ W(256 x 64) -> Zb(bf16 N x 64)
__global__ __launch_bounds__(256) void mgemm2(const ushort_t* __restrict__ Hb,
                                              const ushort_t* __restrict__ WT,
                                              ushort_t* __restrict__ Zb, int N) {
    const int w = threadIdx.x >> 6, l = threadIdx.x & 63;
    const int row0 = blockIdx.x * 64 + w * 16;
    if (row0 >= N) return;
    const int lr = l & 15, lk = l >> 4;
    const ushort_t* ap = Hb + (size_t)(row0 + lr) * 256 + lk * 8;

    f32x4 acc[4] = {{0.f,0.f,0.f,0.f},{0.f,0.f,0.f,0.f},{0.f,0.f,0.f,0.f},{0.f,0.f,0.f,0.f}};
    #pragma unroll
    for (int ks = 0; ks < 8; ++ks) {
        bf16x8 a = *(const bf16x8*)(ap + ks * 32);
        #pragma unroll
        for (int nt = 0; nt < 4; ++nt) {
            bf16x8 b = *(const bf16x8*)(WT + (size_t)(nt * 16 + lr) * 256 + ks * 32 + lk * 8);
            acc[nt] = __builtin_amdgcn_mfma_f32_16x16x32_bf16(a, b, acc[nt], 0, 0, 0);
        }
    }
    #pragma unroll
    for (int nt = 0; nt < 4; ++nt)
        #pragma unroll
        for (int r = 0; r < 4; ++r)
            Zb[(size_t)(row0 + lk * 4 + r) * DOUT + nt * 16 + lr] = f2bf(acc[nt][r]);
}

// ---------------- elr3: three q-dots per node from one X read ----------------
__global__ __launch_bounds__(256) void elr3(const void* __restrict__ X,
                                            const int* __restrict__ flagp,
                                            const float* __restrict__ q0,
                                            const float* __restrict__ q1,
                                            const float* __restrict__ q2,
                                            float* __restrict__ o0,
                                            float* __restrict__ o1,
                                            float* __restrict__ o2,
                                            int N, int D, int Hh) {
    __shared__ float qs[3][512];   // transposed [h*D + k] layout (conflict-free)
    const int tid = threadIdx.x;
    const int f = flagp ? flagp[0] : 0;
    const int tot = D * Hh;
    for (int i = tid; i < tot; i += 256) {
        int k, h;
        if (Hh == 4) { k = i >> 2; h = i & 3; } else { k = i; h = 0; }
        qs[0][h * D + k] = q0[i];
        qs[1][h * D + k] = q1[i];
        qs[2][h * D + k] = q2[i];
    }
    __syncthreads();
    const int wid = tid >> 6, lane = tid & 63;
    const int n = blockIdx.x * 4 + wid;
    if (n >= N) return;
    const int J = D >> 6;
    float x[4];
    for (int j = 0; j < J; ++j) x[j] = ldf(X, (size_t)n * D + j * 64 + lane, f);
    #pragma unroll
    for (int s = 0; s < 3; ++s) {
        float* op = (s == 0) ? o0 : (s == 1) ? o1 : o2;
        for (int h = 0; h < Hh; ++h) {
            float v = 0.f;
            for (int j = 0; j < J; ++j) v += x[j] * qs[s][h * D + j * 64 + lane];
            #pragma unroll
            for (int o = 32; o > 0; o >>= 1) v += __shfl_down(v, o, 64);
            if (lane == 0) op[n * Hh + h] = v;
        }
    }
}

// ---------------- fused CSR gather, layer 1 (H=4, D=256) ----------------
template <int MODE>
__global__ __launch_bounds__(256) void gat1(const int* __restrict__ rp,
                                            const int2* __restrict__ adj,
                                            const ushort_t* __restrict__ zb,
                                            const float* __restrict__ el,
                                            const float* __restrict__ er,
                                            const float* __restrict__ bias,
                                            ushort_t* __restrict__ H, int N) {
    __shared__ float atl[4][CAP * 4];
    __shared__ int   snl[4][CAP];
    const int w = threadIdx.x >> 6, lane = threadIdx.x & 63;
    const int n = blockIdx.x * 4 + w;
    if (n >= N) return;
    const int h = lane >> 4;
    const int beg = rp[n], deg = rp[n + 1] - beg;
    const float4* el4 = (const float4*)el;
    const float4 ern = ((const float4*)er)[n];

    float4 ss = make_float4(0.f, 0.f, 0.f, 0.f);
    for (int base = 0; base < deg; base += 64) {
        int i = base + lane;
        if (i < deg) {
            int2 ae = adj[beg + i];
            float4 e = el4[ae.x];
            float x0 = lrelu_exp(e.x + ern.x);
            float x1 = lrelu_exp(e.y + ern.y);
            float x2 = lrelu_exp(e.z + ern.z);
            float x3 = lrelu_exp(e.w + ern.w);
            ss.x += x0; ss.y += x1; ss.z += x2; ss.w += x3;
            if (i < CAP) {
                float ew = __int_as_float(ae.y);
                float4* dst4 = (float4*)&atl[w][i * 4];
                *dst4 = make_float4(x0 * ew, x1 * ew, x2 * ew, x3 * ew);
                snl[w][i] = ae.x;
            }
        }
    }
    #pragma unroll
    for (int o = 32; o > 0; o >>= 1) {
        ss.x += __shfl_xor(ss.x, o, 64);
        ss.y += __shfl_xor(ss.y, o, 64);
        ss.z += __shfl_xor(ss.z, o, 64);
        ss.w += __shfl_xor(ss.w, o, 64);
    }
    const float sh = (h == 0) ? ss.x : (h == 1) ? ss.y : (h == 2) ? ss.z : ss.w;
    const float inv = 1.f / (sh + 1e-9f);
    const float erh = (h == 0) ? ern.x : (h == 1) ? ern.y : (h == 2) ? ern.z : ern.w;

    float a0 = 0.f, a1 = 0.f, a2 = 0.f, a3 = 0.f;
    #pragma unroll 2
    for (int i = 0; i < deg; ++i) {
        int sn; float atv;
        if (i < CAP) {
            sn = snl[w][i];
            atv = atl[w][i * 4 + h];
        } else {
            int2 ae = adj[beg + i];
            sn = ae.x;
            atv = lrelu_exp(el[sn * 4 + h] + erh) * __int_as_float(ae.y);
        }
        ushort4 zv = *(const ushort4*)(zb + (size_t)sn * HD + lane * 4);
        a0 += bf2f(zv.x) * atv; a1 += bf2f(zv.y) * atv;
        a2 += bf2f(zv.z) * atv; a3 += bf2f(zv.w) * atv;
    }
    float4 b = *(const float4*)(bias + lane * 4);
    a0 = a0 * inv + b.x; a1 = a1 * inv + b.y;
    a2 = a2 * inv + b.z; a3 = a3 * inv + b.w;

    ushort_t* hp = H + (size_t)n * HD + lane * 4;
    ushort4 o;
    if (MODE == 0) {
        o.x = f2bf(a0 > 0.f ? a0 : 0.f); o.y = f2bf(a1 > 0.f ? a1 : 0.f);
        o.z = f2bf(a2 > 0.f ? a2 : 0.f); o.w = f2bf(a3 > 0.f ? a3 : 0.f);
    } else if (MODE == 1) {
        o.x = f2bf(a0 > 0.f ? a0 : expm1f(a0)); o.y = f2bf(a1 > 0.f ? a1 : expm1f(a1));
        o.z = f2bf(a2 > 0.f ? a2 : expm1f(a2)); o.w = f2bf(a3 > 0.f ? a3 : expm1f(a3));
    } else {
        ushort4 hw = *(const ushort4*)hp;
        float v0 = (bf2f(hw.x) + (a0 > 0.f ? a0 : expm1f(a0))) * 0.5f;
        float v1 = (bf2f(hw.y) + (a1 > 0.f ? a1 : expm1f(a1))) * 0.5f;
        float v2 = (bf2f(hw.z) + (a2 > 0.f ? a2 : expm1f(a2))) * 0.5f;
        float v3 = (bf2f(hw.w) + (a3 > 0.f ? a3 : expm1f(a3))) * 0.5f;
        o.x = f2bf(v0 > 0.f ? v0 : 0.f); o.y = f2bf(v1 > 0.f ? v1 : 0.f);
        o.z = f2bf(v2 > 0.f ? v2 : 0.f); o.w = f2bf(v3 > 0.f ? v3 : 0.f);
    }
    *(ushort4*)hp = o;
}

// ---------------- fused CSR gather + epilogue, layer 2 (H=1, D=64) ----------------
template <int MODE>
__global__ __launch_bounds__(256) void gat2(const int* __restrict__ rp,
                                            const int2* __restrict__ adj,
                                            const ushort_t* __restrict__ zb,
                                            const float* __restrict__ el,
                                            const float* __restrict__ er,
                                            const float* __restrict__ b1,
                                            const float* __restrict__ b2,
                                            float* __restrict__ ACC,
                                            void* __restrict__ out,
                                            const int* __restrict__ flagp, int N) {
    __shared__ float atl[4][CAP];
    __shared__ int   snl[4][CAP];
    const int w = threadIdx.x >> 6, lane = threadIdx.x & 63;
    const int n = blockIdx.x * 4 + w;
    if (n >= N) return;
    const int beg = rp[n], deg = rp[n + 1] - beg;
    const float ern = er[n];

    float ssum = 0.f;
    for (int base = 0; base < deg; base += 64) {
        int i = base + lane;
        if (i < deg) {
            int2 ae = adj[beg + i];
            float x = lrelu_exp(el[ae.x] + ern);
            ssum += x;
            if (i < CAP) {
                atl[w][i] = x * __int_as_float(ae.y);
                snl[w][i] = ae.x;
            }
        }
    }
    #pragma unroll
    for (int o = 32; o > 0; o >>= 1) ssum += __shfl_xor(ssum, o, 64);
    const float inv = 1.f / (ssum + 1e-9f);

    float a = 0.f;
    #pragma unroll 2
    for (int i = 0; i < deg; ++i) {
        int sn; float atv;
        if (i < CAP) {
            sn = snl[w][i];
            atv = atl[w][i];
        } else {
            int2 ae = adj[beg + i];
            sn = ae.x;
            atv = lrelu_exp(el[sn] + ern) * __int_as_float(ae.y);
        }
        a += bf2f(zb[(size_t)sn * DOUT + lane]) * atv;
    }
    a *= inv;

    if (MODE == 0) {
        float v = a + b1[lane];
        size_t o = (size_t)n * DOUT + lane;
        if (flagp[0]) ((float*)out)[o] = v;
        else ((ushort_t*)out)[o] = f2bf(v);
    } else if (MODE == 1) {
        ACC[(size_t)n * DOUT + lane] = a;
    } else {
        float v = ((ACC[(size_t)n * DOUT + lane] + b1[lane]) + (a + b2[lane])) * 0.5f;
        size_t o = (size_t)N_AC * DOUT + (size_t)n * DOUT + lane;
        if (flagp[0]) ((float*)out)[o] = v;
        else ((ushort_t*)out)[o] = f2bf(v);
    }
}

// ---------------- host launch ----------------
extern "C" void kernel_launch(void* const* d_in, const int* in_sizes, int n_in,
                              void* d_out, int out_size, void* d_ws, size_t ws_size,
                              hipStream_t stream) {
    (void)in_sizes; (void)n_in; (void)out_size; (void)ws_size;

    const void* x_ac = d_in[0];
    const void* x_w  = d_in[1];
    const int* src_tic = (const int*)d_in[29];
    const int* dst_tic = (const int*)d_in[30];
    const int* src_w   = (const int*)d_in[31];
    const int* dst_w   = (const int*)d_in[32];
    const int* src_rel = (const int*)d_in[33];
    const int* dst_rel = (const int*)d_in[34];

    float* ws = (float*)d_ws;
    int* FLAG = (int*)ws;

    float* PAR = ws + 16;
    const int o_wtic = 0, o_ww = 400000, o_wrel = 600000;
    const int o_W1t = 1000000, o_W1w = 1032768, o_W1r = 1065536;
    const int o_W2t = 1098304, o_W2w = 1114688, o_W2r = 1131072;
    const int o_al1t = 1147456, o_ar1t = 1147712, o_al1w = 1147968, o_ar1w = 1148224,
              o_al1r = 1148480, o_ar1r = 1148736;
    const int o_b1t = 1148992, o_b1w = 1149248, o_b1r = 1149504;
    const int o_al2t = 1149760, o_ar2t = 1149824, o_al2w = 1149888, o_ar2w = 1149952,
              o_al2r = 1150016, o_ar2r = 1150080;
    const int o_b2t = 1150144, o_b2w = 1150208, o_b2r = 1150272;
    const int o_qel1t = 1150400, o_qer1t = 1150912, o_qel1w = 1151424, o_qer1w = 1151936,
              o_qel1r = 1152448, o_qer1r = 1152960;
    const int o_qel2t = 1153472, o_qer2t = 1153728, o_qel2w = 1153984, o_qer2w = 1154240,
              o_qel2r = 1154496, o_qer2r = 1154752;

    // per-etype attention coefficient buffers
    float* EB   = ws + 1160016;
    float* ELt  = EB;                // N_AC*4
    float* ERt  = EB + 160000;       // N_AC*4
    float* ELw  = EB + 320000;       // N_W*4
    float* ERw  = EB + 400000;       // N_W*4
    float* ELr  = EB + 480000;       // N_AC*4
    float* ERr  = EB + 640000;       // N_W*4
    float* E2tl = EB + 720000;       // N_AC
    float* E2tr = EB + 760000;       // N_AC
    float* E2wl = EB + 800000;       // N_W
    float* E2wr = EB + 820000;       // N_W
    float* E2rl = EB + 840000;       // N_AC
    float* E2rr = EB + 880000;       // N_W
    float* ACC = ws + 2060016;                   // 1,280,000
    ushort_t* Zb  = (ushort_t*)(ws + 3340016);   // 10.24M bf16
    ushort_t* Hac = (ushort_t*)(ws + 8460016);   // 40000x256 bf16
    ushort_t* Hw  = (ushort_t*)(ws + 13580016);  // 20000x256 bf16
    ushort_t* WT  = (ushort_t*)(ws + 16140016);  // 147456 bf16 (packed W^T)
    const int t_W1t = 0, t_W1w = 32768, t_W1r = 65536,
              t_W2t = 98304, t_W2w = 114688, t_W2r = 131072;
    int* IB = (int*)(ws + 16213760);
    int* rp_tic = IB;
    int* rp_w   = IB + 40016;
    int* rp_rel = IB + 60032;
    int* cur    = IB + 80048;
    int* bsum   = IB + 120064;
    int2* adj_tic = (int2*)(IB + 120320);
    int2* adj_w   = (int2*)(IB + 920320);
    int2* adj_rel = (int2*)(IB + 1320320);
    // end: ws + 18,334,080 floats = 73.3 MB

    // ---- P0: dtype, params, q vectors, packed W^T ----
    detect_dtype<<<1, 256, 0, stream>>>((const ushort_t*)x_ac, FLAG);

    CvtTab ct;
    const int srcIdx[27] = {2,3,4, 5,6,7,8, 9,10,11,12, 13,14,15,16,
                            17,18,19,20, 21,22,23,24, 25,26,27,28};
    const int sizes[27] = {E_TIC, E_W, E_REL,
                           32768,256,256,256, 32768,256,256,256, 32768,256,256,256,
                           16384,64,64,64, 16384,64,64,64, 16384,64,64,64};
    const int offs[27] = {o_wtic,o_ww,o_wrel,
                          o_W1t,o_al1t,o_ar1t,o_b1t, o_W1w,o_al1w,o_ar1w,o_b1w,
                          o_W1r,o_al1r,o_ar1r,o_b1r,
                          o_W2t,o_al2t,o_ar2t,o_b2t, o_W2w,o_al2w,o_ar2w,o_b2w,
                          o_W2r,o_al2r,o_ar2r,o_b2r};
    for (int i = 0; i < 27; ++i) { ct.src[i] = d_in[srcIdx[i]]; ct.n[i] = sizes[i]; ct.off[i] = offs[i]; }
    cvt_inputs<<<27 * 8, 256, 0, stream>>>(ct, PAR, FLAG);

    QTab qt;
    const int qw[12] = {o_W1t,o_W1t, o_W1w,o_W1w, o_W1r,o_W1r, o_W2t,o_W2t, o_W2w,o_W2w, o_W2r,o_W2r};
    const int qa[12] = {o_al1t,o_ar1t, o_al1w,o_ar1w, o_al1r,o_ar1r,
                        o_al2t,o_ar2t, o_al2w,o_ar2w, o_al2r,o_ar2r};
    const int qq[12] = {o_qel1t,o_qer1t, o_qel1w,o_qer1w, o_qel1r,o_qer1r,
                        o_qel2t,o_qer2t, o_qel2w,o_qer2w, o_qel2r,o_qer2r};
    for (int i = 0; i < 12; ++i) {
        qt.woff[i] = qw[i]; qt.aoff[i] = qa[i]; qt.qoff[i] = qq[i];
        qt.K[i] = (i < 6) ? 128 : 256; qt.Hh[i] = (i < 6) ? 4 : 1;
    }
    make_q<<<12, 256, 0, stream>>>(qt, PAR);

    PTab pt;
    const int pw[6] = {o_W1t, o_W1w, o_W1r, o_W2t, o_W2w, o_W2r};
    const int ptf[6] = {t_W1t, t_W1w, t_W1r, t_W2t, t_W2w, t_W2r};
    for (int i = 0; i < 6; ++i) {
        pt.woff[i] = pw[i]; pt.toff[i] = ptf[i];
        pt.Klog[i] = (i < 3) ? 7 : 8; pt.N[i] = (i < 3) ? 256 : 64;
    }
    pack_wt<<<6 * 16, 256, 0, stream>>>(pt, PAR, WT);

    // ---- P0b: CSR builds ----
    {
        const int B = (N_AC + 255) / 256;
        hipMemsetAsync(cur, 0, N_AC * 4, stream);
        count_deg<<<(E_TIC + 255) / 256, 256, 0, stream>>>(dst_tic, cur, E_TIC);
        scan_bsum<<<B, 256, 0, stream>>>(cur, bsum, N_AC);
        scan_top<<<1, 256, 0, stream>>>(bsum, B);
        scan_out<<<B, 256, 0, stream>>>(cur, bsum, rp_tic, cur, N_AC);
        fill_adj<<<(E_TIC + 255) / 256, 256, 0, stream>>>(src_tic, dst_tic, PAR + o_wtic, cur, adj_tic, E_TIC);
    }
    {
        const int B = (N_W + 255) / 256;
        hipMemsetAsync(cur, 0, N_W * 4, stream);
        count_deg<<<(E_W + 255) / 256, 256, 0, stream>>>(dst_w, cur, E_W);
        scan_bsum<<<B, 256, 0, stream>>>(cur, bsum, N_W);
        scan_top<<<1, 256, 0, stream>>>(bsum, B);
        scan_out<<<B, 256, 0, stream>>>(cur, bsum, rp_w, cur, N_W);
        fill_adj<<<(E_W + 255) / 256, 256, 0, stream>>>(src_w, dst_w, PAR + o_ww, cur, adj_w, E_W);
    }
    {
        const int B = (N_W + 255) / 256;
        hipMemsetAsync(cur, 0, N_W * 4, stream);
        count_deg<<<(E_REL + 255) / 256, 256, 0, stream>>>(dst_rel, cur, E_REL);
        scan_bsum<<<B, 256, 0, stream>>>(cur, bsum, N_W);
        scan_top<<<1, 256, 0, stream>>>(bsum, B);
        scan_out<<<B, 256, 0, stream>>>(cur, bsum, rp_rel, cur, N_W);
        fill_adj<<<(E_REL + 255) / 256, 256, 0, stream>>>(src_rel, dst_rel, PAR + o_wrel, cur, adj_rel, E_REL);
    }

    // ---- P0c: layer-1 attention coefficients (one X read for 3 q's each) ----
    elr3<<<N_AC / 4, 256, 0, stream>>>(x_ac, FLAG, PAR + o_qel1t, PAR + o_qer1t, PAR + o_qel1r,
                                       ELt, ERt, ELr, N_AC, 128, 4);
    elr3<<<N_W / 4, 256, 0, stream>>>(x_w, FLAG, PAR + o_qel1w, PAR + o_qer1w, PAR + o_qer1r,
                                      ELw, ERw, ERr, N_W, 128, 4);

    // ---- P1: tic GAT layer 1 -> Hac ----
    mgemm1<<<N_AC / 16, 256, 0, stream>>>(x_ac, FLAG, WT + t_W1t, Zb, N_AC);
    gat1<0><<<N_AC / 4, 256, 0, stream>>>(rp_tic, adj_tic, Zb, ELt, ERt, PAR + o_b1t, Hac, N_AC);

    // ---- P2: w GAT layer 1 -> Hw (elu) ----
    mgemm1<<<N_W / 16, 256, 0, stream>>>(x_w, FLAG, WT + t_W1w, Zb, N_W);
    gat1<1><<<N_W / 4, 256, 0, stream>>>(rp_w, adj_w, Zb, ELw, ERw, PAR + o_b1w, Hw, N_W);

    // ---- P3: rel GAT layer 1; combine -> Hw = h_word ----
    mgemm1<<<N_AC / 16, 256, 0, stream>>>(x_ac, FLAG, WT + t_W1r, Zb, N_AC);
    gat1<2><<<N_W / 4, 256, 0, stream>>>(rp_rel, adj_rel, Zb, ELr, ERr, PAR + o_b1r, Hw, N_W);

    // ---- P3b: layer-2 attention coefficients ----
    elr3<<<N_AC / 4, 256, 0, stream>>>(Hac, nullptr, PAR + o_qel2t, PAR + o_qer2t, PAR + o_qel2r,
                                       E2tl, E2tr, E2rl, N_AC, 256, 1);
    elr3<<<N_W / 4, 256, 0, stream>>>(Hw, nullptr, PAR + o_qel2w, PAR + o_qer2w, PAR + o_qer2r,
                                      E2wl, E2wr, E2rr, N_W, 256, 1);

    // ---- P4: tic GAT layer 2 -> out[0 : 40000*64] ----
    mgemm2<<<(N_AC + 63) / 64, 256, 0, stream>>>(Hac, WT + t_W2t, Zb, N_AC);
    gat2<0><<<N_AC / 4, 256, 0, stream>>>(rp_tic, adj_tic, Zb, E2tl, E2tr,
                                          PAR + o_b2t, nullptr, ACC, d_out, FLAG, N_AC);

    // ---- P5: w GAT layer 2 -> ACC ----
    mgemm2<<<(N_W + 63) / 64, 256, 0, stream>>>(Hw, WT + t_W2w, Zb, N_W);
    gat2<1><<<N_W / 4, 256, 0, stream>>>(rp_w, adj_w, Zb, E2wl, E2wr,
                                         nullptr, nullptr, ACC, d_out, FLAG, N_W);

    // ---- P6: rel GAT layer 2; combine -> out word ----
    mgemm2<<<(N_AC + 63) / 64, 256, 0, stream>>>(Hac, WT + t_W2r, Zb, N_AC);
    gat2<2><<<N_W / 4, 256, 0, stream>>>(rp_rel, adj_rel, Zb, E2rl, E2rr,
                                         PAR + o_b2w, PAR + o_b2r, ACC, d_out, FLAG, N_W);
}

// Round 7
// 544.514 us; speedup vs baseline: 8.2116x; 1.1239x over previous
//
#include <hip/hip_runtime.h>
#include <hip/hip_bf16.h>

typedef unsigned short ushort_t;
typedef __attribute__((ext_vector_type(8))) short bf16x8;
typedef __attribute__((ext_vector_type(4))) float f32x4;

// ---------------- constants ----------------
#define N_AC 40000
#define N_W  20000
#define D_IN 128
#define NH   4
#define HD   256   // NH*DH
#define DOUT 64
#define E_TIC 400000
#define E_W   200000
#define E_REL 400000
#define E_ALL 1000000
#define N_ALL 80000
#define NEG 0.2f
#define CAP 256

__device__ __forceinline__ float bf2f(ushort_t u) {
    return __uint_as_float(((unsigned int)u) << 16);
}
__device__ __forceinline__ ushort_t f2bf(float v) {
    unsigned u = __float_as_uint(v);
    unsigned r = (u + 0x7fffu + ((u >> 16) & 1u)) >> 16;
    return (ushort_t)r;
}
__device__ __forceinline__ float ldf(const void* p, size_t i, int f) {
    return f ? ((const float*)p)[i] : bf2f(((const ushort_t*)p)[i]);
}
__device__ __forceinline__ float lrelu_exp(float v) {
    v = v > 0.f ? v : NEG * v;
    return __expf(v);
}

// ---------------- dtype autodetect ----------------
__global__ void detect_dtype(const ushort_t* __restrict__ x, int* __restrict__ flag) {
    __shared__ int hit;
    if (threadIdx.x == 0) hit = 0;
    __syncthreads();
    for (int i = threadIdx.x; i < 4096; i += 256) {
        float v = bf2f(x[i]);
        if (!(fabsf(v) <= 1e4f)) atomicOr(&hit, 1);
    }
    __syncthreads();
    if (threadIdx.x == 0) flag[0] = hit ? 1 : 0;
}

// ---------------- canonicalize 24 small param tensors to f32 ----------------
struct CvtTab { const void* src[24]; int n[24]; int off[24]; };
__global__ __launch_bounds__(256) void cvt_inputs(CvtTab t, float* __restrict__ par,
                                                  const int* __restrict__ flagp) {
    int ent = blockIdx.x >> 3, sub = blockIdx.x & 7;
    int f = flagp[0];
    const void* s = t.src[ent];
    int n = t.n[ent];
    float* d = par + t.off[ent];
    for (int i = sub * 256 + threadIdx.x; i < n; i += 8 * 256)
        d[i] = f ? ((const float*)s)[i] : bf2f(((const ushort_t*)s)[i]);
}

// ---------------- q vectors ----------------
struct QTab { int woff[12]; int aoff[12]; int qoff[12]; int K[12]; int Hh[12]; };
__global__ __launch_bounds__(256) void make_q(QTab t, float* __restrict__ par) {
    int b = blockIdx.x;
    int k = threadIdx.x;
    int K = t.K[b], Hh = t.Hh[b];
    if (k >= K) return;
    const float* W = par + t.woff[b];
    const float* a = par + t.aoff[b];
    float* q = par + t.qoff[b];
    int HDc = Hh * 64;
    for (int h = 0; h < Hh; ++h) {
        float s = 0.f;
        for (int d = 0; d < 64; ++d) s += W[(size_t)k * HDc + h * 64 + d] * a[h * 64 + d];
        q[k * Hh + h] = s;
    }
}

// ---------------- pack W^T to bf16 (N x K row-major) ----------------
struct PTab { int woff[6]; int toff[6]; int Klog[6]; int N[6]; };
__global__ __launch_bounds__(256) void pack_wt(PTab t, const float* __restrict__ par,
                                               ushort_t* __restrict__ wt) {
    int m = blockIdx.x >> 4, sub = blockIdx.x & 15;
    int Klog = t.Klog[m], K = 1 << Klog, Nn = t.N[m];
    int tot = K * Nn;
    const float* Wp = par + t.woff[m];
    ushort_t* d = wt + t.toff[m];
    for (int i = sub * 256 + threadIdx.x; i < tot; i += 16 * 256) {
        int n = i >> Klog, k = i & (K - 1);
        d[i] = f2bf(Wp[(size_t)k * Nn + n]);
    }
}

// ---------------- merged CSR build over concatenated node space ----------------
__global__ __launch_bounds__(256) void count3(const int* __restrict__ d0,
                                              const int* __restrict__ d1,
                                              const int* __restrict__ d2,
                                              int* __restrict__ cnt) {
    int e = blockIdx.x * 256 + threadIdx.x;
    if (e >= E_ALL) return;
    int g;
    if (e < E_TIC) g = d0[e];
    else if (e < E_TIC + E_W) g = N_AC + d1[e - E_TIC];
    else g = N_AC + N_W + d2[e - E_TIC - E_W];
    atomicAdd(&cnt[g], 1);
}

__global__ __launch_bounds__(256) void scan_bsum(const int* __restrict__ cnt,
                                                 int* __restrict__ bsum, int N) {
    __shared__ int red[256];
    int i = blockIdx.x * 256 + threadIdx.x;
    red[threadIdx.x] = (i < N) ? cnt[i] : 0;
    __syncthreads();
    #pragma unroll
    for (int o = 128; o > 0; o >>= 1) {
        if (threadIdx.x < o) red[threadIdx.x] += red[threadIdx.x + o];
        __syncthreads();
    }
    if (threadIdx.x == 0) bsum[blockIdx.x] = red[0];
}

__global__ __launch_bounds__(512) void scan_top(int* __restrict__ bsum, int B) {
    __shared__ int sc[512];
    const int t = threadIdx.x;
    int v = (t < B) ? bsum[t] : 0;
    sc[t] = v;
    __syncthreads();
    #pragma unroll
    for (int o = 1; o < 512; o <<= 1) {
        int u = (t >= o) ? sc[t - o] : 0;
        __syncthreads();
        sc[t] += u;
        __syncthreads();
    }
    if (t < B) bsum[t] = sc[t] - v;
}

__global__ __launch_bounds__(256) void scan_out(const int* __restrict__ cnt,
                                                const int* __restrict__ bsum,
                                                int* __restrict__ rowptr,
                                                int* __restrict__ cur, int N) {
    __shared__ int sc[256];
    const int t = threadIdx.x;
    int i = blockIdx.x * 256 + t;
    int v = (i < N) ? cnt[i] : 0;
    sc[t] = v;
    __syncthreads();
    #pragma unroll
    for (int o = 1; o < 256; o <<= 1) {
        int u = (t >= o) ? sc[t - o] : 0;
        __syncthreads();
        sc[t] += u;
        __syncthreads();
    }
    int ex = sc[t] - v + bsum[blockIdx.x];
    if (i < N) {
        rowptr[i] = ex;
        cur[i] = ex;
        if (i == N - 1) rowptr[N] = ex + v;
    }
}

__global__ __launch_bounds__(256) void fill3(const int* __restrict__ s0, const int* __restrict__ d0, const void* __restrict__ w0,
                                             const int* __restrict__ s1, const int* __restrict__ d1, const void* __restrict__ w1,
                                             const int* __restrict__ s2, const int* __restrict__ d2, const void* __restrict__ w2,
                                             const int* __restrict__ flagp,
                                             int* __restrict__ cur, int2* __restrict__ adj) {
    int e = blockIdx.x * 256 + threadIdx.x;
    if (e >= E_ALL) return;
    int f = flagp[0];
    int g, sn; float ew;
    if (e < E_TIC) {
        g = d0[e]; sn = s0[e]; ew = ldf(w0, e, f);
    } else if (e < E_TIC + E_W) {
        int le = e - E_TIC;
        g = N_AC + d1[le]; sn = s1[le]; ew = ldf(w1, le, f);
    } else {
        int le = e - E_TIC - E_W;
        g = N_AC + N_W + d2[le]; sn = s2[le]; ew = ldf(w2, le, f);
    }
    int pos = atomicAdd(&cur[g], 1);
    adj[pos] = make_int2(sn, __float_as_int(ew));
}

// ---------------- MFMA GEMM L1: X(N x 128) @ W(128 x 256) -> Zb(bf16 N x 256)
__global__ __launch_bounds__(256) void mgemm1(const void* __restrict__ X,
                                              const int* __restrict__ flagp,
                                              const ushort_t* __restrict__ WT,
                                              ushort_t* __restrict__ Zb, int N) {
    const int w = threadIdx.x >> 6, l = threadIdx.x & 63;
    const int row0 = blockIdx.x * 16;
    const int lr = l & 15, lk = l >> 4;
    const int f = flagp[0];

    bf16x8 a[4];
    if (!f) {
        const ushort_t* xp = (const ushort_t*)X + (size_t)(row0 + lr) * 128 + lk * 8;
        #pragma unroll
        for (int ks = 0; ks < 4; ++ks) a[ks] = *(const bf16x8*)(xp + ks * 32);
    } else {
        const float* xp = (const float*)X + (size_t)(row0 + lr) * 128 + lk * 8;
        #pragma unroll
        for (int ks = 0; ks < 4; ++ks)
            #pragma unroll
            for (int j = 0; j < 8; ++j) a[ks][j] = (short)f2bf(xp[ks * 32 + j]);
    }

    f32x4 acc[4] = {{0.f,0.f,0.f,0.f},{0.f,0.f,0.f,0.f},{0.f,0.f,0.f,0.f},{0.f,0.f,0.f,0.f}};
    const int col0 = w * 64;
    #pragma unroll
    for (int ks = 0; ks < 4; ++ks) {
        #pragma unroll
        for (int nt = 0; nt < 4; ++nt) {
            bf16x8 b = *(const bf16x8*)(WT + (size_t)(col0 + nt * 16 + lr) * 128 + ks * 32 + lk * 8);
            acc[nt] = __builtin_amdgcn_mfma_f32_16x16x32_bf16(a[ks], b, acc[nt], 0, 0, 0);
        }
    }
    #pragma unroll
    for (int nt = 0; nt < 4; ++nt)
        #pragma unroll
        for (int r = 0; r < 4; ++r)
            Zb[(size_t)(row0 + lk * 4 + r) * HD + col0 + nt * 16 + lr] = f2bf(acc[nt][r]);
}

// ---------------- MFMA GEMM L2: Hb(bf16 N x 256) @ W(256 x 64) -> Zb(bf16 N x 64)
__global__ __launch_bounds__(256) void mgemm2(const ushort_t* __restrict__ Hb,
                                              const ushort_t* __restrict__ WT,
                                              ushort_t* __restrict__ Zb, int N) {
    const int w = threadIdx.x >> 6, l = threadIdx.x & 63;
    const int row0 = blockIdx.x * 64 + w * 16;
    if (row0 >= N) return;
    const int lr = l & 15, lk = l >> 4;
    const ushort_t* ap = Hb + (size_t)(row0 + lr) * 256 + lk * 8;

    f32x4 acc[4] = {{0.f,0.f,0.f,0.f},{0.f,0.f,0.f,0.f},{0.f,0.f,0.f,0.f},{0.f,0.f,0.f,0.f}};
    #pragma unroll
    for (int ks = 0; ks < 8; ++ks) {
        bf16x8 a = *(const bf16x8*)(ap + ks * 32);
        #pragma unroll
        for (int nt = 0; nt < 4; ++nt) {
            bf16x8 b = *(const bf16x8*)(WT + (size_t)(nt * 16 + lr) * 256 + ks * 32 + lk * 8);
            acc[nt] = __builtin_amdgcn_mfma_f32_16x16x32_bf16(a, b, acc[nt], 0, 0, 0);
        }
    }
    #pragma unroll
    for (int nt = 0; nt < 4; ++nt)
        #pragma unroll
        for (int r = 0; r < 4; ++r)
            Zb[(size_t)(row0 + lk * 4 + r) * DOUT + nt * 16 + lr] = f2bf(acc[nt][r]);
}

// ---------------- elr3: three q-dots per node from one X read ----------------
__global__ __launch_bounds__(256) void elr3(const void* __restrict__ X,
                                            const int* __restrict__ flagp,
                                            const float* __restrict__ q0,
                                            const float* __restrict__ q1,
                                            const float* __restrict__ q2,
                                            float* __restrict__ o0,
                                            float* __restrict__ o1,
                                            float* __restrict__ o2,
                                            int N, int D, int Hh) {
    __shared__ float qs[3][512];
    const int tid = threadIdx.x;
    const int f = flagp ? flagp[0] : 0;
    const int tot = D * Hh;
    for (int i = tid; i < tot; i += 256) {
        int k, h;
        if (Hh == 4) { k = i >> 2; h = i & 3; } else { k = i; h = 0; }
        qs[0][h * D + k] = q0[i];
        qs[1][h * D + k] = q1[i];
        qs[2][h * D + k] = q2[i];
    }
    __syncthreads();
    const int wid = tid >> 6, lane = tid & 63;
    const int n = blockIdx.x * 4 + wid;
    if (n >= N) return;
    const int J = D >> 6;
    float x[4];
    for (int j = 0; j < J; ++j) x[j] = ldf(X, (size_t)n * D + j * 64 + lane, f);
    #pragma unroll
    for (int s = 0; s < 3; ++s) {
        float* op = (s == 0) ? o0 : (s == 1) ? o1 : o2;
        for (int h = 0; h < Hh; ++h) {
            float v = 0.f;
            for (int j = 0; j < J; ++j) v += x[j] * qs[s][h * D + j * 64 + lane];
            #pragma unroll
            for (int o = 32; o > 0; o >>= 1) v += __shfl_down(v, o, 64);
            if (lane == 0) op[n * Hh + h] = v;
        }
    }
}

// ---------------- fused CSR gather, layer 1 (H=4, D=256) ----------------
template <int MODE>
__global__ __launch_bounds__(256) void gat1(const int* __restrict__ rp,
                                            const int2* __restrict__ adj,
                                            const ushort_t* __restrict__ zb,
                                            const float* __restrict__ el,
                                            const float* __restrict__ er,
                                            const float* __restrict__ bias,
                                            ushort_t* __restrict__ H, int N) {
    __shared__ float atl[4][CAP * 4];
    __shared__ int   snl[4][CAP];
    const int w = threadIdx.x >> 6, lane = threadIdx.x & 63;
    const int n = blockIdx.x * 4 + w;
    if (n >= N) return;
    const int h = lane >> 4;
    const int beg = rp[n], deg = rp[n + 1] - beg;
    const float4* el4 = (const float4*)el;
    const float4 ern = ((const float4*)er)[n];

    float4 ss = make_float4(0.f, 0.f, 0.f, 0.f);
    for (int base = 0; base < deg; base += 64) {
        int i = base + lane;
        if (i < deg) {
            int2 ae = adj[beg + i];
            float4 e = el4[ae.x];
            float x0 = lrelu_exp(e.x + ern.x);
            float x1 = lrelu_exp(e.y + ern.y);
            float x2 = lrelu_exp(e.z + ern.z);
            float x3 = lrelu_exp(e.w + ern.w);
            ss.x += x0; ss.y += x1; ss.z += x2; ss.w += x3;
            if (i < CAP) {
                float ew = __int_as_float(ae.y);
                float4* dst4 = (float4*)&atl[w][i * 4];
                *dst4 = make_float4(x0 * ew, x1 * ew, x2 * ew, x3 * ew);
                snl[w][i] = ae.x;
            }
        }
    }
    #pragma unroll
    for (int o = 32; o > 0; o >>= 1) {
        ss.x += __shfl_xor(ss.x, o, 64);
        ss.y += __shfl_xor(ss.y, o, 64);
        ss.z += __shfl_xor(ss.z, o, 64);
        ss.w += __shfl_xor(ss.w, o, 64);
    }
    const float sh = (h == 0) ? ss.x : (h == 1) ? ss.y : (h == 2) ? ss.z : ss.w;
    const float inv = 1.f / (sh + 1e-9f);
    const float erh = (h == 0) ? ern.x : (h == 1) ? ern.y : (h == 2) ? ern.z : ern.w;

    float a0 = 0.f, a1 = 0.f, a2 = 0.f, a3 = 0.f;
    #pragma unroll 2
    for (int i = 0; i < deg; ++i) {
        int sn; float atv;
        if (i < CAP) {
            sn = snl[w][i];
            atv = atl[w][i * 4 + h];
        } else {
            int2 ae = adj[beg + i];
            sn = ae.x;
            atv = lrelu_exp(el[sn * 4 + h] + erh) * __int_as_float(ae.y);
        }
        ushort4 zv = *(const ushort4*)(zb + (size_t)sn * HD + lane * 4);
        a0 += bf2f(zv.x) * atv; a1 += bf2f(zv.y) * atv;
        a2 += bf2f(zv.z) * atv; a3 += bf2f(zv.w) * atv;
    }
    float4 b = *(const float4*)(bias + lane * 4);
    a0 = a0 * inv + b.x; a1 = a1 * inv + b.y;
    a2 = a2 * inv + b.z; a3 = a3 * inv + b.w;

    ushort_t* hp = H + (size_t)n * HD + lane * 4;
    ushort4 o;
    if (MODE == 0) {
        o.x = f2bf(a0 > 0.f ? a0 : 0.f); o.y = f2bf(a1 > 0.f ? a1 : 0.f);
        o.z = f2bf(a2 > 0.f ? a2 : 0.f); o.w = f2bf(a3 > 0.f ? a3 : 0.f);
    } else if (MODE == 1) {
        o.x = f2bf(a0 > 0.f ? a0 : expm1f(a0)); o.y = f2bf(a1 > 0.f ? a1 : expm1f(a1));
        o.z = f2bf(a2 > 0.f ? a2 : expm1f(a2)); o.w = f2bf(a3 > 0.f ? a3 : expm1f(a3));
    } else {
        ushort4 hw = *(const ushort4*)hp;
        float v0 = (bf2f(hw.x) + (a0 > 0.f ? a0 : expm1f(a0))) * 0.5f;
        float v1 = (bf2f(hw.y) + (a1 > 0.f ? a1 : expm1f(a1))) * 0.5f;
        float v2 = (bf2f(hw.z) + (a2 > 0.f ? a2 : expm1f(a2))) * 0.5f;
        float v3 = (bf2f(hw.w) + (a3 > 0.f ? a3 : expm1f(a3))) * 0.5f;
        o.x = f2bf(v0 > 0.f ? v0 : 0.f); o.y = f2bf(v1 > 0.f ? v1 : 0.f);
        o.z = f2bf(v2 > 0.f ? v2 : 0.f); o.w = f2bf(v3 > 0.f ? v3 : 0.f);
    }
    *(ushort4*)hp = o;
}

// ---------------- fused CSR gather + epilogue, layer 2 (H=1, D=64) ----------------
template <int MODE>
__global__ __launch_bounds__(256) void gat2(const int* __restrict__ rp,
                                            const int2* __restrict__ adj,
                                            const ushort_t* __restrict__ zb,
                                            const float* __restrict__ el,
                                            const float* __restrict__ er,
                                            const float* __restrict__ b1,
                                            const float* __restrict__ b2,
                                            float* __restrict__ ACC,
                                            void* __restrict__ out,
                                            const int* __restrict__ flagp, int N) {
    __shared__ float atl[4][CAP];
    __shared__ int   snl[4][CAP];
    const int w = threadIdx.x >> 6, lane = threadIdx.x & 63;
    const int n = blockIdx.x * 4 + w;
    if (n >= N) return;
    const int beg = rp[n], deg = rp[n + 1] - beg;
    const float ern = er[n];

    float ssum = 0.f;
    for (int base = 0; base < deg; base += 64) {
        int i = base + lane;
        if (i < deg) {
            int2 ae = adj[beg + i];
            float x = lrelu_exp(el[ae.x] + ern);
            ssum += x;
            if (i < CAP) {
                atl[w][i] = x * __int_as_float(ae.y);
                snl[w][i] = ae.x;
            }
        }
    }
    #pragma unroll
    for (int o = 32; o > 0; o >>= 1) ssum += __shfl_xor(ssum, o, 64);
    const float inv = 1.f / (ssum + 1e-9f);

    float a = 0.f;
    #pragma unroll 2
    for (int i = 0; i < deg; ++i) {
        int sn; float atv;
        if (i < CAP) {
            sn = snl[w][i];
            atv = atl[w][i];
        } else {
            int2 ae = adj[beg + i];
            sn = ae.x;
            atv = lrelu_exp(el[sn] + ern) * __int_as_float(ae.y);
        }
        a += bf2f(zb[(size_t)sn * DOUT + lane]) * atv;
    }
    a *= inv;

    if (MODE == 0) {
        float v = a + b1[lane];
        size_t o = (size_t)n * DOUT + lane;
        if (flagp[0]) ((float*)out)[o] = v;
        else ((ushort_t*)out)[o] = f2bf(v);
    } else if (MODE == 1) {
        ACC[(size_t)n * DOUT + lane] = a;
    } else {
        float v = ((ACC[(size_t)n * DOUT + lane] + b1[lane]) + (a + b2[lane])) * 0.5f;
        size_t o = (size_t)N_AC * DOUT + (size_t)n * DOUT + lane;
        if (flagp[0]) ((float*)out)[o] = v;
        else ((ushort_t*)out)[o] = f2bf(v);
    }
}

// ---------------- host launch ----------------
extern "C" void kernel_launch(void* const* d_in, const int* in_sizes, int n_in,
                              void* d_out, int out_size, void* d_ws, size_t ws_size,
                              hipStream_t stream) {
    (void)in_sizes; (void)n_in; (void)out_size; (void)ws_size;

    const void* x_ac = d_in[0];
    const void* x_w  = d_in[1];
    const void* ew_tic = d_in[2];
    const void* ew_w   = d_in[3];
    const void* ew_rel = d_in[4];
    const int* src_tic = (const int*)d_in[29];
    const int* dst_tic = (const int*)d_in[30];
    const int* src_w   = (const int*)d_in[31];
    const int* dst_w   = (const int*)d_in[32];
    const int* src_rel = (const int*)d_in[33];
    const int* dst_rel = (const int*)d_in[34];

    float* ws = (float*)d_ws;
    int* FLAG = (int*)ws;

    float* PAR = ws + 16;
    const int o_W1t = 1000000, o_W1w = 1032768, o_W1r = 1065536;
    const int o_W2t = 1098304, o_W2w = 1114688, o_W2r = 1131072;
    const int o_al1t = 1147456, o_ar1t = 1147712, o_al1w = 1147968, o_ar1w = 1148224,
              o_al1r = 1148480, o_ar1r = 1148736;
    const int o_b1t = 1148992, o_b1w = 1149248, o_b1r = 1149504;
    const int o_al2t = 1149760, o_ar2t = 1149824, o_al2w = 1149888, o_ar2w = 1149952,
              o_al2r = 1150016, o_ar2r = 1150080;
    const int o_b2t = 1150144, o_b2w = 1150208, o_b2r = 1150272;
    const int o_qel1t = 1150400, o_qer1t = 1150912, o_qel1w = 1151424, o_qer1w = 1151936,
              o_qel1r = 1152448, o_qer1r = 1152960;
    const int o_qel2t = 1153472, o_qer2t = 1153728, o_qel2w = 1153984, o_qer2w = 1154240,
              o_qel2r = 1154496, o_qer2r = 1154752;

    float* EB   = ws + 1160016;
    float* ELt  = EB;
    float* ERt  = EB + 160000;
    float* ELw  = EB + 320000;
    float* ERw  = EB + 400000;
    float* ELr  = EB + 480000;
    float* ERr  = EB + 640000;
    float* E2tl = EB + 720000;
    float* E2tr = EB + 760000;
    float* E2wl = EB + 800000;
    float* E2wr = EB + 820000;
    float* E2rl = EB + 840000;
    float* E2rr = EB + 880000;
    float* ACC = ws + 2060016;                   // 1,280,000
    ushort_t* Zb  = (ushort_t*)(ws + 3340016);   // 10.24M bf16
    ushort_t* Hac = (ushort_t*)(ws + 8460016);   // 40000x256 bf16
    ushort_t* Hw  = (ushort_t*)(ws + 13580016);  // 20000x256 bf16
    ushort_t* WT  = (ushort_t*)(ws + 16140016);  // 147456 bf16
    const int t_W1t = 0, t_W1w = 32768, t_W1r = 65536,
              t_W2t = 98304, t_W2w = 114688, t_W2r = 131072;
    int* IB = (int*)(ws + 16213760);
    int* rp   = IB;                              // N_ALL + 1
    int* cur  = IB + 80064;                      // N_ALL
    int* bsum = IB + 160128;                     // 512
    int2* adj = (int2*)(IB + 160704);            // E_ALL int2

    // ---- P0: dtype, params, q vectors, packed W^T ----
    detect_dtype<<<1, 256, 0, stream>>>((const ushort_t*)x_ac, FLAG);

    CvtTab ct;
    const int srcIdx[24] = {5,6,7,8, 9,10,11,12, 13,14,15,16,
                            17,18,19,20, 21,22,23,24, 25,26,27,28};
    const int sizes[24] = {32768,256,256,256, 32768,256,256,256, 32768,256,256,256,
                           16384,64,64,64, 16384,64,64,64, 16384,64,64,64};
    const int offs[24] = {o_W1t,o_al1t,o_ar1t,o_b1t, o_W1w,o_al1w,o_ar1w,o_b1w,
                          o_W1r,o_al1r,o_ar1r,o_b1r,
                          o_W2t,o_al2t,o_ar2t,o_b2t, o_W2w,o_al2w,o_ar2w,o_b2w,
                          o_W2r,o_al2r,o_ar2r,o_b2r};
    for (int i = 0; i < 24; ++i) { ct.src[i] = d_in[srcIdx[i]]; ct.n[i] = sizes[i]; ct.off[i] = offs[i]; }
    cvt_inputs<<<24 * 8, 256, 0, stream>>>(ct, PAR, FLAG);

    QTab qt;
    const int qw[12] = {o_W1t,o_W1t, o_W1w,o_W1w, o_W1r,o_W1r, o_W2t,o_W2t, o_W2w,o_W2w, o_W2r,o_W2r};
    const int qa[12] = {o_al1t,o_ar1t, o_al1w,o_ar1w, o_al1r,o_ar1r,
                        o_al2t,o_ar2t, o_al2w,o_ar2w, o_al2r,o_ar2r};
    const int qq[12] = {o_qel1t,o_qer1t, o_qel1w,o_qer1w, o_qel1r,o_qer1r,
                        o_qel2t,o_qer2t, o_qel2w,o_qer2w, o_qel2r,o_qer2r};
    for (int i = 0; i < 12; ++i) {
        qt.woff[i] = qw[i]; qt.aoff[i] = qa[i]; qt.qoff[i] = qq[i];
        qt.K[i] = (i < 6) ? 128 : 256; qt.Hh[i] = (i < 6) ? 4 : 1;
    }
    make_q<<<12, 256, 0, stream>>>(qt, PAR);

    PTab pt;
    const int pw[6] = {o_W1t, o_W1w, o_W1r, o_W2t, o_W2w, o_W2r};
    const int ptf[6] = {t_W1t, t_W1w, t_W1r, t_W2t, t_W2w, t_W2r};
    for (int i = 0; i < 6; ++i) {
        pt.woff[i] = pw[i]; pt.toff[i] = ptf[i];
        pt.Klog[i] = (i < 3) ? 7 : 8; pt.N[i] = (i < 3) ? 256 : 64;
    }
    pack_wt<<<6 * 16, 256, 0, stream>>>(pt, PAR, WT);

    // ---- P0b: merged CSR build (one scan over 80000 nodes) ----
    {
        const int B = (N_ALL + 255) / 256;   // 313
        hipMemsetAsync(cur, 0, N_ALL * 4, stream);
        count3<<<(E_ALL + 255) / 256, 256, 0, stream>>>(dst_tic, dst_w, dst_rel, cur);
        scan_bsum<<<B, 256, 0, stream>>>(cur, bsum, N_ALL);
        scan_top<<<1, 512, 0, stream>>>(bsum, B);
        scan_out<<<B, 256, 0, stream>>>(cur, bsum, rp, cur, N_ALL);
        fill3<<<(E_ALL + 255) / 256, 256, 0, stream>>>(src_tic, dst_tic, ew_tic,
                                                       src_w, dst_w, ew_w,
                                                       src_rel, dst_rel, ew_rel,
                                                       FLAG, cur, adj);
    }
    const int* rp_tic = rp;
    const int* rp_w   = rp + N_AC;
    const int* rp_rel = rp + N_AC + N_W;

    // ---- P0c: layer-1 attention coefficients ----
    elr3<<<N_AC / 4, 256, 0, stream>>>(x_ac, FLAG, PAR + o_qel1t, PAR + o_qer1t, PAR + o_qel1r,
                                       ELt, ERt, ELr, N_AC, 128, 4);
    elr3<<<N_W / 4, 256, 0, stream>>>(x_w, FLAG, PAR + o_qel1w, PAR + o_qer1w, PAR + o_qer1r,
                                      ELw, ERw, ERr, N_W, 128, 4);

    // ---- P1: tic GAT layer 1 -> Hac ----
    mgemm1<<<N_AC / 16, 256, 0, stream>>>(x_ac, FLAG, WT + t_W1t, Zb, N_AC);
    gat1<0><<<N_AC / 4, 256, 0, stream>>>(rp_tic, adj, Zb, ELt, ERt, PAR + o_b1t, Hac, N_AC);

    // ---- P2: w GAT layer 1 -> Hw (elu) ----
    mgemm1<<<N_W / 16, 256, 0, stream>>>(x_w, FLAG, WT + t_W1w, Zb, N_W);
    gat1<1><<<N_W / 4, 256, 0, stream>>>(rp_w, adj, Zb, ELw, ERw, PAR + o_b1w, Hw, N_W);

    // ---- P3: rel GAT layer 1; combine -> Hw = h_word ----
    mgemm1<<<N_AC / 16, 256, 0, stream>>>(x_ac, FLAG, WT + t_W1r, Zb, N_AC);
    gat1<2><<<N_W / 4, 256, 0, stream>>>(rp_rel, adj, Zb, ELr, ERr, PAR + o_b1r, Hw, N_W);

    // ---- P3b: layer-2 attention coefficients ----
    elr3<<<N_AC / 4, 256, 0, stream>>>(Hac, nullptr, PAR + o_qel2t, PAR + o_qer2t, PAR + o_qel2r,
                                       E2tl, E2tr, E2rl, N_AC, 256, 1);
    elr3<<<N_W / 4, 256, 0, stream>>>(Hw, nullptr, PAR + o_qel2w, PAR + o_qer2w, PAR + o_qer2r,
                                      E2wl, E2wr, E2rr, N_W, 256, 1);

    // ---- P4: tic GAT layer 2 -> out[0 : 40000*64] ----
    mgemm2<<<(N_AC + 63) / 64, 256, 0, stream>>>(Hac, WT + t_W2t, Zb, N_AC);
    gat2<0><<<N_AC / 4, 256, 0, stream>>>(rp_tic, adj, Zb, E2tl, E2tr,
                                          PAR + o_b2t, nullptr, ACC, d_out, FLAG, N_AC);

    // ---- P5: w GAT layer 2 -> ACC ----
    mgemm2<<<(N_W + 63) / 64, 256, 0, stream>>>(Hw, WT + t_W2w, Zb, N_W);
    gat2<1><<<N_W / 4, 256, 0, stream>>>(rp_w, adj, Zb, E2wl, E2wr,
                                         nullptr, nullptr, ACC, d_out, FLAG, N_W);

    // ---- P6: rel GAT layer 2; combine -> out word ----
    mgemm2<<<(N_AC + 63) / 64, 256, 0, stream>>>(Hac, WT + t_W2r, Zb, N_AC);
    gat2<2><<<N_W / 4, 256, 0, stream>>>(rp_rel, adj, Zb, E2rl, E2rr,
                                         PAR + o_b2w, PAR + o_b2r, ACC, d_out, FLAG, N_W);
}

// Round 8
// 456.577 us; speedup vs baseline: 9.7932x; 1.1926x over previous
//
#include <hip/hip_runtime.h>
#include <hip/hip_bf16.h>

typedef unsigned short ushort_t;
typedef __attribute__((ext_vector_type(8))) short bf16x8;
typedef __attribute__((ext_vector_type(4))) float f32x4;

// ---------------- constants ----------------
#define N_AC 40000
#define N_W  20000
#define D_IN 128
#define NH   4
#define HD   256   // NH*DH
#define DOUT 64
#define E_TIC 400000
#define E_W   200000
#define E_REL 400000
#define E_ALL 1000000
#define N_ALL 80000
#define NEG 0.2f
#define CAP 256

__device__ __forceinline__ float bf2f(ushort_t u) {
    return __uint_as_float(((unsigned int)u) << 16);
}
__device__ __forceinline__ ushort_t f2bf(float v) {
    unsigned u = __float_as_uint(v);
    unsigned r = (u + 0x7fffu + ((u >> 16) & 1u)) >> 16;
    return (ushort_t)r;
}
__device__ __forceinline__ float ldf(const void* p, size_t i, int f) {
    return f ? ((const float*)p)[i] : bf2f(((const ushort_t*)p)[i]);
}
__device__ __forceinline__ float lrelu_exp(float v) {
    v = v > 0.f ? v : NEG * v;
    return __expf(v);
}

// ---------------- dtype autodetect ----------------
__global__ void detect_dtype(const ushort_t* __restrict__ x, int* __restrict__ flag) {
    __shared__ int hit;
    if (threadIdx.x == 0) hit = 0;
    __syncthreads();
    for (int i = threadIdx.x; i < 4096; i += 256) {
        float v = bf2f(x[i]);
        if (!(fabsf(v) <= 1e4f)) atomicOr(&hit, 1);
    }
    __syncthreads();
    if (threadIdx.x == 0) flag[0] = hit ? 1 : 0;
}

// ---------------- canonicalize 24 small param tensors to f32 ----------------
struct CvtTab { const void* src[24]; int n[24]; int off[24]; };
__global__ __launch_bounds__(256) void cvt_inputs(CvtTab t, float* __restrict__ par,
                                                  const int* __restrict__ flagp) {
    int ent = blockIdx.x >> 3, sub = blockIdx.x & 7;
    int f = flagp[0];
    const void* s = t.src[ent];
    int n = t.n[ent];
    float* d = par + t.off[ent];
    for (int i = sub * 256 + threadIdx.x; i < n; i += 8 * 256)
        d[i] = f ? ((const float*)s)[i] : bf2f(((const ushort_t*)s)[i]);
}

// ---------------- q vectors (only the 2 rel-dst cases need them now) ----------------
struct QTab { int woff[2]; int aoff[2]; int qoff[2]; int K[2]; int Hh[2]; };
__global__ __launch_bounds__(256) void make_q(QTab t, float* __restrict__ par) {
    int b = blockIdx.x;
    int k = threadIdx.x;
    int K = t.K[b], Hh = t.Hh[b];
    if (k >= K) return;
    const float* W = par + t.woff[b];
    const float* a = par + t.aoff[b];
    float* q = par + t.qoff[b];
    int HDc = Hh * 64;
    for (int h = 0; h < Hh; ++h) {
        float s = 0.f;
        for (int d = 0; d < 64; ++d) s += W[(size_t)k * HDc + h * 64 + d] * a[h * 64 + d];
        q[k * Hh + h] = s;
    }
}

// ---------------- pack W^T to bf16 (N x K row-major) ----------------
struct PTab { int woff[6]; int toff[6]; int Klog[6]; int N[6]; };
__global__ __launch_bounds__(256) void pack_wt(PTab t, const float* __restrict__ par,
                                               ushort_t* __restrict__ wt) {
    int m = blockIdx.x >> 4, sub = blockIdx.x & 15;
    int Klog = t.Klog[m], K = 1 << Klog, Nn = t.N[m];
    int tot = K * Nn;
    const float* Wp = par + t.woff[m];
    ushort_t* d = wt + t.toff[m];
    for (int i = sub * 256 + threadIdx.x; i < tot; i += 16 * 256) {
        int n = i >> Klog, k = i & (K - 1);
        d[i] = f2bf(Wp[(size_t)k * Nn + n]);
    }
}

// ---------------- merged CSR build over concatenated node space ----------------
__global__ __launch_bounds__(256) void count3(const int* __restrict__ d0,
                                              const int* __restrict__ d1,
                                              const int* __restrict__ d2,
                                              int* __restrict__ cnt) {
    int e = blockIdx.x * 256 + threadIdx.x;
    if (e >= E_ALL) return;
    int g;
    if (e < E_TIC) g = d0[e];
    else if (e < E_TIC + E_W) g = N_AC + d1[e - E_TIC];
    else g = N_AC + N_W + d2[e - E_TIC - E_W];
    atomicAdd(&cnt[g], 1);
}

__global__ __launch_bounds__(256) void scan_bsum(const int* __restrict__ cnt,
                                                 int* __restrict__ bsum, int N) {
    __shared__ int red[256];
    int i = blockIdx.x * 256 + threadIdx.x;
    red[threadIdx.x] = (i < N) ? cnt[i] : 0;
    __syncthreads();
    #pragma unroll
    for (int o = 128; o > 0; o >>= 1) {
        if (threadIdx.x < o) red[threadIdx.x] += red[threadIdx.x + o];
        __syncthreads();
    }
    if (threadIdx.x == 0) bsum[blockIdx.x] = red[0];
}

__global__ __launch_bounds__(512) void scan_top(int* __restrict__ bsum, int B) {
    __shared__ int sc[512];
    const int t = threadIdx.x;
    int v = (t < B) ? bsum[t] : 0;
    sc[t] = v;
    __syncthreads();
    #pragma unroll
    for (int o = 1; o < 512; o <<= 1) {
        int u = (t >= o) ? sc[t - o] : 0;
        __syncthreads();
        sc[t] += u;
        __syncthreads();
    }
    if (t < B) bsum[t] = sc[t] - v;
}

__global__ __launch_bounds__(256) void scan_out(const int* __restrict__ cnt,
                                                const int* __restrict__ bsum,
                                                int* __restrict__ rowptr,
                                                int* __restrict__ cur, int N) {
    __shared__ int sc[256];
    const int t = threadIdx.x;
    int i = blockIdx.x * 256 + t;
    int v = (i < N) ? cnt[i] : 0;
    sc[t] = v;
    __syncthreads();
    #pragma unroll
    for (int o = 1; o < 256; o <<= 1) {
        int u = (t >= o) ? sc[t - o] : 0;
        __syncthreads();
        sc[t] += u;
        __syncthreads();
    }
    int ex = sc[t] - v + bsum[blockIdx.x];
    if (i < N) {
        rowptr[i] = ex;
        cur[i] = ex;
        if (i == N - 1) rowptr[N] = ex + v;
    }
}

// adj entry: (src:16) | (ew_bf16:16)  -- 4 bytes
__global__ __launch_bounds__(256) void fill3(const int* __restrict__ s0, const int* __restrict__ d0, const void* __restrict__ w0,
                                             const int* __restrict__ s1, const int* __restrict__ d1, const void* __restrict__ w1,
                                             const int* __restrict__ s2, const int* __restrict__ d2, const void* __restrict__ w2,
                                             const int* __restrict__ flagp,
                                             int* __restrict__ cur, unsigned* __restrict__ adj) {
    int e = blockIdx.x * 256 + threadIdx.x;
    if (e >= E_ALL) return;
    int f = flagp[0];
    int g, sn; float ew;
    if (e < E_TIC) {
        g = d0[e]; sn = s0[e]; ew = ldf(w0, e, f);
    } else if (e < E_TIC + E_W) {
        int le = e - E_TIC;
        g = N_AC + d1[le]; sn = s1[le]; ew = ldf(w1, le, f);
    } else {
        int le = e - E_TIC - E_W;
        g = N_AC + N_W + d2[le]; sn = s2[le]; ew = ldf(w2, le, f);
    }
    int pos = atomicAdd(&cur[g], 1);
    adj[pos] = (unsigned)(sn & 0xFFFF) | ((unsigned)f2bf(ew) << 16);
}

// ---------------- MFMA GEMM L1 + fused el/er epilogue ----------------
// wave w = head w (cols w*64..+63); 16 rows/block.
__global__ __launch_bounds__(256) void mgemm1(const void* __restrict__ X,
                                              const int* __restrict__ flagp,
                                              const ushort_t* __restrict__ WT,
                                              ushort_t* __restrict__ Zb,
                                              const float* __restrict__ alp,
                                              const float* __restrict__ arp,
                                              float* __restrict__ elo,
                                              float* __restrict__ ero, int N) {
    const int w = threadIdx.x >> 6, l = threadIdx.x & 63;
    const int row0 = blockIdx.x * 16;
    const int lr = l & 15, lk = l >> 4;
    const int f = flagp[0];

    bf16x8 a[4];
    if (!f) {
        const ushort_t* xp = (const ushort_t*)X + (size_t)(row0 + lr) * 128 + lk * 8;
        #pragma unroll
        for (int ks = 0; ks < 4; ++ks) a[ks] = *(const bf16x8*)(xp + ks * 32);
    } else {
        const float* xp = (const float*)X + (size_t)(row0 + lr) * 128 + lk * 8;
        #pragma unroll
        for (int ks = 0; ks < 4; ++ks)
            #pragma unroll
            for (int j = 0; j < 8; ++j) a[ks][j] = (short)f2bf(xp[ks * 32 + j]);
    }

    f32x4 acc[4] = {{0.f,0.f,0.f,0.f},{0.f,0.f,0.f,0.f},{0.f,0.f,0.f,0.f},{0.f,0.f,0.f,0.f}};
    const int col0 = w * 64;
    #pragma unroll
    for (int ks = 0; ks < 4; ++ks) {
        #pragma unroll
        for (int nt = 0; nt < 4; ++nt) {
            bf16x8 b = *(const bf16x8*)(WT + (size_t)(col0 + nt * 16 + lr) * 128 + ks * 32 + lk * 8);
            acc[nt] = __builtin_amdgcn_mfma_f32_16x16x32_bf16(a[ks], b, acc[nt], 0, 0, 0);
        }
    }
    #pragma unroll
    for (int nt = 0; nt < 4; ++nt)
        #pragma unroll
        for (int r = 0; r < 4; ++r)
            Zb[(size_t)(row0 + lk * 4 + r) * HD + col0 + nt * 16 + lr] = f2bf(acc[nt][r]);

    if (alp) {   // el epilogue: el[n][w] = sum_d z[n][w*64+d]*al[w][d]
        float a0 = alp[col0 + lr], a1 = alp[col0 + 16 + lr],
              a2 = alp[col0 + 32 + lr], a3 = alp[col0 + 48 + lr];
        #pragma unroll
        for (int r = 0; r < 4; ++r) {
            float v = acc[0][r] * a0 + acc[1][r] * a1 + acc[2][r] * a2 + acc[3][r] * a3;
            v += __shfl_xor(v, 1, 64); v += __shfl_xor(v, 2, 64);
            v += __shfl_xor(v, 4, 64); v += __shfl_xor(v, 8, 64);
            if (lr == r) elo[(size_t)(row0 + lk * 4 + r) * 4 + w] = v;
        }
    }
    if (arp) {
        float a0 = arp[col0 + lr], a1 = arp[col0 + 16 + lr],
              a2 = arp[col0 + 32 + lr], a3 = arp[col0 + 48 + lr];
        #pragma unroll
        for (int r = 0; r < 4; ++r) {
            float v = acc[0][r] * a0 + acc[1][r] * a1 + acc[2][r] * a2 + acc[3][r] * a3;
            v += __shfl_xor(v, 1, 64); v += __shfl_xor(v, 2, 64);
            v += __shfl_xor(v, 4, 64); v += __shfl_xor(v, 8, 64);
            if (lr == r) ero[(size_t)(row0 + lk * 4 + r) * 4 + w] = v;
        }
    }
}

// ---------------- MFMA GEMM L2 + fused el/er epilogue (H=1) ----------------
__global__ __launch_bounds__(256) void mgemm2(const ushort_t* __restrict__ Hb,
                                              const ushort_t* __restrict__ WT,
                                              ushort_t* __restrict__ Zb,
                                              const float* __restrict__ alp,
                                              const float* __restrict__ arp,
                                              float* __restrict__ elo,
                                              float* __restrict__ ero, int N) {
    const int w = threadIdx.x >> 6, l = threadIdx.x & 63;
    const int row0 = blockIdx.x * 64 + w * 16;
    if (row0 >= N) return;
    const int lr = l & 15, lk = l >> 4;
    const ushort_t* ap = Hb + (size_t)(row0 + lr) * 256 + lk * 8;

    f32x4 acc[4] = {{0.f,0.f,0.f,0.f},{0.f,0.f,0.f,0.f},{0.f,0.f,0.f,0.f},{0.f,0.f,0.f,0.f}};
    #pragma unroll
    for (int ks = 0; ks < 8; ++ks) {
        bf16x8 a = *(const bf16x8*)(ap + ks * 32);
        #pragma unroll
        for (int nt = 0; nt < 4; ++nt) {
            bf16x8 b = *(const bf16x8*)(WT + (size_t)(nt * 16 + lr) * 256 + ks * 32 + lk * 8);
            acc[nt] = __builtin_amdgcn_mfma_f32_16x16x32_bf16(a, b, acc[nt], 0, 0, 0);
        }
    }
    #pragma unroll
    for (int nt = 0; nt < 4; ++nt)
        #pragma unroll
        for (int r = 0; r < 4; ++r)
            Zb[(size_t)(row0 + lk * 4 + r) * DOUT + nt * 16 + lr] = f2bf(acc[nt][r]);

    if (alp) {
        float a0 = alp[lr], a1 = alp[16 + lr], a2 = alp[32 + lr], a3 = alp[48 + lr];
        #pragma unroll
        for (int r = 0; r < 4; ++r) {
            float v = acc[0][r] * a0 + acc[1][r] * a1 + acc[2][r] * a2 + acc[3][r] * a3;
            v += __shfl_xor(v, 1, 64); v += __shfl_xor(v, 2, 64);
            v += __shfl_xor(v, 4, 64); v += __shfl_xor(v, 8, 64);
            if (lr == r) elo[row0 + lk * 4 + r] = v;
        }
    }
    if (arp) {
        float a0 = arp[lr], a1 = arp[16 + lr], a2 = arp[32 + lr], a3 = arp[48 + lr];
        #pragma unroll
        for (int r = 0; r < 4; ++r) {
            float v = acc[0][r] * a0 + acc[1][r] * a1 + acc[2][r] * a2 + acc[3][r] * a3;
            v += __shfl_xor(v, 1, 64); v += __shfl_xor(v, 2, 64);
            v += __shfl_xor(v, 4, 64); v += __shfl_xor(v, 8, 64);
            if (lr == r) ero[row0 + lk * 4 + r] = v;
        }
    }
}

// ---------------- elr1: single q-dot per node (rel-dst projections only) ----------------
__global__ __launch_bounds__(256) void elr1(const void* __restrict__ X,
                                            const int* __restrict__ flagp,
                                            const float* __restrict__ q0,
                                            float* __restrict__ o0,
                                            int N, int D, int Hh) {
    __shared__ float qs[512];
    const int tid = threadIdx.x;
    const int f = flagp ? flagp[0] : 0;
    const int tot = D * Hh;
    for (int i = tid; i < tot; i += 256) {
        int k, h;
        if (Hh == 4) { k = i >> 2; h = i & 3; } else { k = i; h = 0; }
        qs[h * D + k] = q0[i];
    }
    __syncthreads();
    const int wid = tid >> 6, lane = tid & 63;
    const int n = blockIdx.x * 4 + wid;
    if (n >= N) return;
    const int J = D >> 6;
    float x[4];
    for (int j = 0; j < J; ++j) x[j] = ldf(X, (size_t)n * D + j * 64 + lane, f);
    for (int h = 0; h < Hh; ++h) {
        float v = 0.f;
        for (int j = 0; j < J; ++j) v += x[j] * qs[h * D + j * 64 + lane];
        #pragma unroll
        for (int o = 32; o > 0; o >>= 1) v += __shfl_down(v, o, 64);
        if (lane == 0) o0[n * Hh + h] = v;
    }
}

// ---------------- fused CSR gather, layer 1 (H=4, D=256) ----------------
template <int MODE>
__global__ __launch_bounds__(256) void gat1(const int* __restrict__ rp,
                                            const unsigned* __restrict__ adj,
                                            const ushort_t* __restrict__ zb,
                                            const float* __restrict__ el,
                                            const float* __restrict__ er,
                                            const float* __restrict__ bias,
                                            ushort_t* __restrict__ H, int N) {
    __shared__ float atl[4][CAP * 4];
    __shared__ int   snl[4][CAP];
    const int w = threadIdx.x >> 6, lane = threadIdx.x & 63;
    const int n = blockIdx.x * 4 + w;
    if (n >= N) return;
    const int h = lane >> 4;
    const int beg = rp[n], deg = rp[n + 1] - beg;
    const float4* el4 = (const float4*)el;
    const float4 ern = ((const float4*)er)[n];

    float4 ss = make_float4(0.f, 0.f, 0.f, 0.f);
    for (int base = 0; base < deg; base += 64) {
        int i = base + lane;
        if (i < deg) {
            unsigned ae = adj[beg + i];
            int sn = ae & 0xFFFF;
            float4 e = el4[sn];
            float x0 = lrelu_exp(e.x + ern.x);
            float x1 = lrelu_exp(e.y + ern.y);
            float x2 = lrelu_exp(e.z + ern.z);
            float x3 = lrelu_exp(e.w + ern.w);
            ss.x += x0; ss.y += x1; ss.z += x2; ss.w += x3;
            if (i < CAP) {
                float ew = bf2f((ushort_t)(ae >> 16));
                float4* dst4 = (float4*)&atl[w][i * 4];
                *dst4 = make_float4(x0 * ew, x1 * ew, x2 * ew, x3 * ew);
                snl[w][i] = sn;
            }
        }
    }
    #pragma unroll
    for (int o = 32; o > 0; o >>= 1) {
        ss.x += __shfl_xor(ss.x, o, 64);
        ss.y += __shfl_xor(ss.y, o, 64);
        ss.z += __shfl_xor(ss.z, o, 64);
        ss.w += __shfl_xor(ss.w, o, 64);
    }
    const float sh = (h == 0) ? ss.x : (h == 1) ? ss.y : (h == 2) ? ss.z : ss.w;
    const float inv = 1.f / (sh + 1e-9f);
    const float erh = (h == 0) ? ern.x : (h == 1) ? ern.y : (h == 2) ? ern.z : ern.w;

    float a0 = 0.f, a1 = 0.f, a2 = 0.f, a3 = 0.f;
    #pragma unroll 2
    for (int i = 0; i < deg; ++i) {
        int sn; float atv;
        if (i < CAP) {
            sn = snl[w][i];
            atv = atl[w][i * 4 + h];
        } else {
            unsigned ae = adj[beg + i];
            sn = ae & 0xFFFF;
            atv = lrelu_exp(el[sn * 4 + h] + erh) * bf2f((ushort_t)(ae >> 16));
        }
        ushort4 zv = *(const ushort4*)(zb + (size_t)sn * HD + lane * 4);
        a0 += bf2f(zv.x) * atv; a1 += bf2f(zv.y) * atv;
        a2 += bf2f(zv.z) * atv; a3 += bf2f(zv.w) * atv;
    }
    float4 b = *(const float4*)(bias + lane * 4);
    a0 = a0 * inv + b.x; a1 = a1 * inv + b.y;
    a2 = a2 * inv + b.z; a3 = a3 * inv + b.w;

    ushort_t* hp = H + (size_t)n * HD + lane * 4;
    ushort4 o;
    if (MODE == 0) {
        o.x = f2bf(a0 > 0.f ? a0 : 0.f); o.y = f2bf(a1 > 0.f ? a1 : 0.f);
        o.z = f2bf(a2 > 0.f ? a2 : 0.f); o.w = f2bf(a3 > 0.f ? a3 : 0.f);
    } else if (MODE == 1) {
        o.x = f2bf(a0 > 0.f ? a0 : expm1f(a0)); o.y = f2bf(a1 > 0.f ? a1 : expm1f(a1));
        o.z = f2bf(a2 > 0.f ? a2 : expm1f(a2)); o.w = f2bf(a3 > 0.f ? a3 : expm1f(a3));
    } else {
        ushort4 hw = *(const ushort4*)hp;
        float v0 = (bf2f(hw.x) + (a0 > 0.f ? a0 : expm1f(a0))) * 0.5f;
        float v1 = (bf2f(hw.y) + (a1 > 0.f ? a1 : expm1f(a1))) * 0.5f;
        float v2 = (bf2f(hw.z) + (a2 > 0.f ? a2 : expm1f(a2))) * 0.5f;
        float v3 = (bf2f(hw.w) + (a3 > 0.f ? a3 : expm1f(a3))) * 0.5f;
        o.x = f2bf(v0 > 0.f ? v0 : 0.f); o.y = f2bf(v1 > 0.f ? v1 : 0.f);
        o.z = f2bf(v2 > 0.f ? v2 : 0.f); o.w = f2bf(v3 > 0.f ? v3 : 0.f);
    }
    *(ushort4*)hp = o;
}

// ---------------- fused CSR gather + epilogue, layer 2 (H=1, D=64) ----------------
template <int MODE>
__global__ __launch_bounds__(256) void gat2(const int* __restrict__ rp,
                                            const unsigned* __restrict__ adj,
                                            const ushort_t* __restrict__ zb,
                                            const float* __restrict__ el,
                                            const float* __restrict__ er,
                                            const float* __restrict__ b1,
                                            const float* __restrict__ b2,
                                            float* __restrict__ ACC,
                                            void* __restrict__ out,
                                            const int* __restrict__ flagp, int N) {
    __shared__ float atl[4][CAP];
    __shared__ int   snl[4][CAP];
    const int w = threadIdx.x >> 6, lane = threadIdx.x & 63;
    const int n = blockIdx.x * 4 + w;
    if (n >= N) return;
    const int beg = rp[n], deg = rp[n + 1] - beg;
    const float ern = er[n];

    float ssum = 0.f;
    for (int base = 0; base < deg; base += 64) {
        int i = base + lane;
        if (i < deg) {
            unsigned ae = adj[beg + i];
            int sn = ae & 0xFFFF;
            float x = lrelu_exp(el[sn] + ern);
            ssum += x;
            if (i < CAP) {
                atl[w][i] = x * bf2f((ushort_t)(ae >> 16));
                snl[w][i] = sn;
            }
        }
    }
    #pragma unroll
    for (int o = 32; o > 0; o >>= 1) ssum += __shfl_xor(ssum, o, 64);
    const float inv = 1.f / (ssum + 1e-9f);

    float a = 0.f;
    #pragma unroll 2
    for (int i = 0; i < deg; ++i) {
        int sn; float atv;
        if (i < CAP) {
            sn = snl[w][i];
            atv = atl[w][i];
        } else {
            unsigned ae = adj[beg + i];
            sn = ae & 0xFFFF;
            atv = lrelu_exp(el[sn] + ern) * bf2f((ushort_t)(ae >> 16));
        }
        a += bf2f(zb[(size_t)sn * DOUT + lane]) * atv;
    }
    a *= inv;

    if (MODE == 0) {
        float v = a + b1[lane];
        size_t o = (size_t)n * DOUT + lane;
        if (flagp[0]) ((float*)out)[o] = v;
        else ((ushort_t*)out)[o] = f2bf(v);
    } else if (MODE == 1) {
        ACC[(size_t)n * DOUT + lane] = a;
    } else {
        float v = ((ACC[(size_t)n * DOUT + lane] + b1[lane]) + (a + b2[lane])) * 0.5f;
        size_t o = (size_t)N_AC * DOUT + (size_t)n * DOUT + lane;
        if (flagp[0]) ((float*)out)[o] = v;
        else ((ushort_t*)out)[o] = f2bf(v);
    }
}

// ---------------- host launch ----------------
extern "C" void kernel_launch(void* const* d_in, const int* in_sizes, int n_in,
                              void* d_out, int out_size, void* d_ws, size_t ws_size,
                              hipStream_t stream) {
    (void)in_sizes; (void)n_in; (void)out_size; (void)ws_size;

    const void* x_ac = d_in[0];
    const void* x_w  = d_in[1];
    const void* ew_tic = d_in[2];
    const void* ew_w   = d_in[3];
    const void* ew_rel = d_in[4];
    const int* src_tic = (const int*)d_in[29];
    const int* dst_tic = (const int*)d_in[30];
    const int* src_w   = (const int*)d_in[31];
    const int* dst_w   = (const int*)d_in[32];
    const int* src_rel = (const int*)d_in[33];
    const int* dst_rel = (const int*)d_in[34];

    float* ws = (float*)d_ws;
    int* FLAG = (int*)ws;

    float* PAR = ws + 16;
    const int o_W1t = 1000000, o_W1w = 1032768, o_W1r = 1065536;
    const int o_W2t = 1098304, o_W2w = 1114688, o_W2r = 1131072;
    const int o_al1t = 1147456, o_ar1t = 1147712, o_al1w = 1147968, o_ar1w = 1148224,
              o_al1r = 1148480, o_ar1r = 1148736;
    const int o_b1t = 1148992, o_b1w = 1149248, o_b1r = 1149504;
    const int o_al2t = 1149760, o_ar2t = 1149824, o_al2w = 1149888, o_ar2w = 1149952,
              o_al2r = 1150016, o_ar2r = 1150080;
    const int o_b2t = 1150144, o_b2w = 1150208, o_b2r = 1150272;
    const int o_qer1r = 1150400, o_qer2r = 1150912;   // only 2 q vectors needed

    float* EB   = ws + 1160016;
    float* ELt  = EB;
    float* ERt  = EB + 160000;
    float* ELw  = EB + 320000;
    float* ERw  = EB + 400000;
    float* ELr  = EB + 480000;
    float* ERr  = EB + 640000;
    float* E2tl = EB + 720000;
    float* E2tr = EB + 760000;
    float* E2wl = EB + 800000;
    float* E2wr = EB + 820000;
    float* E2rl = EB + 840000;
    float* E2rr = EB + 880000;
    float* ACC = ws + 2060016;                   // 1,280,000
    ushort_t* Zb  = (ushort_t*)(ws + 3340016);   // 10.24M bf16
    ushort_t* Hac = (ushort_t*)(ws + 8460016);   // 40000x256 bf16
    ushort_t* Hw  = (ushort_t*)(ws + 13580016);  // 20000x256 bf16
    ushort_t* WT  = (ushort_t*)(ws + 16140016);  // 147456 bf16
    const int t_W1t = 0, t_W1w = 32768, t_W1r = 65536,
              t_W2t = 98304, t_W2w = 114688, t_W2r = 131072;
    int* IB = (int*)(ws + 16213760);
    int* rp   = IB;                              // N_ALL + 1
    int* cur  = IB + 80064;                      // N_ALL
    int* bsum = IB + 160128;                     // 512
    unsigned* adj = (unsigned*)(IB + 160704);    // E_ALL x 4B

    // ---- P0: dtype, params, q vectors, packed W^T ----
    detect_dtype<<<1, 256, 0, stream>>>((const ushort_t*)x_ac, FLAG);

    CvtTab ct;
    const int srcIdx[24] = {5,6,7,8, 9,10,11,12, 13,14,15,16,
                            17,18,19,20, 21,22,23,24, 25,26,27,28};
    const int sizes[24] = {32768,256,256,256, 32768,256,256,256, 32768,256,256,256,
                           16384,64,64,64, 16384,64,64,64, 16384,64,64,64};
    const int offs[24] = {o_W1t,o_al1t,o_ar1t,o_b1t, o_W1w,o_al1w,o_ar1w,o_b1w,
                          o_W1r,o_al1r,o_ar1r,o_b1r,
                          o_W2t,o_al2t,o_ar2t,o_b2t, o_W2w,o_al2w,o_ar2w,o_b2w,
                          o_W2r,o_al2r,o_ar2r,o_b2r};
    for (int i = 0; i < 24; ++i) { ct.src[i] = d_in[srcIdx[i]]; ct.n[i] = sizes[i]; ct.off[i] = offs[i]; }
    cvt_inputs<<<24 * 8, 256, 0, stream>>>(ct, PAR, FLAG);

    QTab qt;
    qt.woff[0] = o_W1r; qt.aoff[0] = o_ar1r; qt.qoff[0] = o_qer1r; qt.K[0] = 128; qt.Hh[0] = 4;
    qt.woff[1] = o_W2r; qt.aoff[1] = o_ar2r; qt.qoff[1] = o_qer2r; qt.K[1] = 256; qt.Hh[1] = 1;
    make_q<<<2, 256, 0, stream>>>(qt, PAR);

    PTab pt;
    const int pw[6] = {o_W1t, o_W1w, o_W1r, o_W2t, o_W2w, o_W2r};
    const int ptf[6] = {t_W1t, t_W1w, t_W1r, t_W2t, t_W2w, t_W2r};
    for (int i = 0; i < 6; ++i) {
        pt.woff[i] = pw[i]; pt.toff[i] = ptf[i];
        pt.Klog[i] = (i < 3) ? 7 : 8; pt.N[i] = (i < 3) ? 256 : 64;
    }
    pack_wt<<<6 * 16, 256, 0, stream>>>(pt, PAR, WT);

    // ---- P0b: merged CSR build ----
    {
        const int B = (N_ALL + 255) / 256;   // 313
        hipMemsetAsync(cur, 0, N_ALL * 4, stream);
        count3<<<(E_ALL + 255) / 256, 256, 0, stream>>>(dst_tic, dst_w, dst_rel, cur);
        scan_bsum<<<B, 256, 0, stream>>>(cur, bsum, N_ALL);
        scan_top<<<1, 512, 0, stream>>>(bsum, B);
        scan_out<<<B, 256, 0, stream>>>(cur, bsum, rp, cur, N_ALL);
        fill3<<<(E_ALL + 255) / 256, 256, 0, stream>>>(src_tic, dst_tic, ew_tic,
                                                       src_w, dst_w, ew_w,
                                                       src_rel, dst_rel, ew_rel,
                                                       FLAG, cur, adj);
    }
    const int* rp_tic = rp;
    const int* rp_w   = rp + N_AC;
    const int* rp_rel = rp + N_AC + N_W;

    // rel-dst er for layer 1 (x_w with q = W1r·ar1r)
    elr1<<<N_W / 4, 256, 0, stream>>>(x_w, FLAG, PAR + o_qer1r, ERr, N_W, 128, 4);

    // ---- P1: tic GAT layer 1 -> Hac ----
    mgemm1<<<N_AC / 16, 256, 0, stream>>>(x_ac, FLAG, WT + t_W1t, Zb,
                                          PAR + o_al1t, PAR + o_ar1t, ELt, ERt, N_AC);
    gat1<0><<<N_AC / 4, 256, 0, stream>>>(rp_tic, adj, Zb, ELt, ERt, PAR + o_b1t, Hac, N_AC);

    // ---- P2: w GAT layer 1 -> Hw (elu) ----
    mgemm1<<<N_W / 16, 256, 0, stream>>>(x_w, FLAG, WT + t_W1w, Zb,
                                         PAR + o_al1w, PAR + o_ar1w, ELw, ERw, N_W);
    gat1<1><<<N_W / 4, 256, 0, stream>>>(rp_w, adj, Zb, ELw, ERw, PAR + o_b1w, Hw, N_W);

    // ---- P3: rel GAT layer 1; combine -> Hw = h_word ----
    mgemm1<<<N_AC / 16, 256, 0, stream>>>(x_ac, FLAG, WT + t_W1r, Zb,
                                          PAR + o_al1r, nullptr, ELr, nullptr, N_AC);
    gat1<2><<<N_W / 4, 256, 0, stream>>>(rp_rel, adj, Zb, ELr, ERr, PAR + o_b1r, Hw, N_W);

    // rel-dst er for layer 2 (Hw with q = W2r·ar2r) — Hw final after P3
    elr1<<<N_W / 4, 256, 0, stream>>>(Hw, nullptr, PAR + o_qer2r, E2rr, N_W, 256, 1);

    // ---- P4: tic GAT layer 2 -> out[0 : 40000*64] ----
    mgemm2<<<(N_AC + 63) / 64, 256, 0, stream>>>(Hac, WT + t_W2t, Zb,
                                                 PAR + o_al2t, PAR + o_ar2t, E2tl, E2tr, N_AC);
    gat2<0><<<N_AC / 4, 256, 0, stream>>>(rp_tic, adj, Zb, E2tl, E2tr,
                                          PAR + o_b2t, nullptr, ACC, d_out, FLAG, N_AC);

    // ---- P5: w GAT layer 2 -> ACC ----
    mgemm2<<<(N_W + 63) / 64, 256, 0, stream>>>(Hw, WT + t_W2w, Zb,
                                                PAR + o_al2w, PAR + o_ar2w, E2wl, E2wr, N_W);
    gat2<1><<<N_W / 4, 256, 0, stream>>>(rp_w, adj, Zb, E2wl, E2wr,
                                         nullptr, nullptr, ACC, d_out, FLAG, N_W);

    // ---- P6: rel GAT layer 2; combine -> out word ----
    mgemm2<<<(N_AC + 63) / 64, 256, 0, stream>>>(Hac, WT + t_W2r, Zb,
                                                 PAR + o_al2r, nullptr, E2rl, nullptr, N_AC);
    gat2<2><<<N_W / 4, 256, 0, stream>>>(rp_rel, adj, Zb, E2rl, E2rr,
                                         PAR + o_b2w, PAR + o_b2r, ACC, d_out, FLAG, N_W);
}

// Round 9
// 432.256 us; speedup vs baseline: 10.3442x; 1.0563x over previous
//
#include <hip/hip_runtime.h>
#include <hip/hip_bf16.h>

typedef unsigned short ushort_t;
typedef __attribute__((ext_vector_type(8))) short bf16x8;
typedef __attribute__((ext_vector_type(4))) float f32x4;

// ---------------- constants ----------------
#define N_AC 40000
#define N_W  20000
#define D_IN 128
#define NH   4
#define HD   256   // NH*DH
#define DOUT 64
#define E_TIC 400000
#define E_W   200000
#define E_REL 400000
#define E_ALL 1000000
#define N_ALL 80000
#define NEG 0.2f
#define CAP 256
#define FCH 4096   // edges per fill3 chunk

__device__ __forceinline__ float bf2f(ushort_t u) {
    return __uint_as_float(((unsigned int)u) << 16);
}
__device__ __forceinline__ ushort_t f2bf(float v) {
    unsigned u = __float_as_uint(v);
    unsigned r = (u + 0x7fffu + ((u >> 16) & 1u)) >> 16;
    return (ushort_t)r;
}
__device__ __forceinline__ float ldf(const void* p, size_t i, int f) {
    return f ? ((const float*)p)[i] : bf2f(((const ushort_t*)p)[i]);
}
__device__ __forceinline__ float lrelu_exp(float v) {
    v = v > 0.f ? v : NEG * v;
    return __expf(v);
}

// ---------------- dtype autodetect ----------------
__global__ void detect_dtype(const ushort_t* __restrict__ x, int* __restrict__ flag) {
    __shared__ int hit;
    if (threadIdx.x == 0) hit = 0;
    __syncthreads();
    for (int i = threadIdx.x; i < 4096; i += 256) {
        float v = bf2f(x[i]);
        if (!(fabsf(v) <= 1e4f)) atomicOr(&hit, 1);
    }
    __syncthreads();
    if (threadIdx.x == 0) flag[0] = hit ? 1 : 0;
}

// ---------------- canonicalize 24 small param tensors to f32 ----------------
struct CvtTab { const void* src[24]; int n[24]; int off[24]; };
__global__ __launch_bounds__(256) void cvt_inputs(CvtTab t, float* __restrict__ par,
                                                  const int* __restrict__ flagp) {
    int ent = blockIdx.x >> 3, sub = blockIdx.x & 7;
    int f = flagp[0];
    const void* s = t.src[ent];
    int n = t.n[ent];
    float* d = par + t.off[ent];
    for (int i = sub * 256 + threadIdx.x; i < n; i += 8 * 256)
        d[i] = f ? ((const float*)s)[i] : bf2f(((const ushort_t*)s)[i]);
}

// ---------------- q vectors (only the 2 rel-dst cases) ----------------
struct QTab { int woff[2]; int aoff[2]; int qoff[2]; int K[2]; int Hh[2]; };
__global__ __launch_bounds__(256) void make_q(QTab t, float* __restrict__ par) {
    int b = blockIdx.x;
    int k = threadIdx.x;
    int K = t.K[b], Hh = t.Hh[b];
    if (k >= K) return;
    const float* W = par + t.woff[b];
    const float* a = par + t.aoff[b];
    float* q = par + t.qoff[b];
    int HDc = Hh * 64;
    for (int h = 0; h < Hh; ++h) {
        float s = 0.f;
        for (int d = 0; d < 64; ++d) s += W[(size_t)k * HDc + h * 64 + d] * a[h * 64 + d];
        q[k * Hh + h] = s;
    }
}

// ---------------- pack W^T to bf16 (N x K row-major) ----------------
struct PTab { int woff[6]; int toff[6]; int Klog[6]; int N[6]; };
__global__ __launch_bounds__(256) void pack_wt(PTab t, const float* __restrict__ par,
                                               ushort_t* __restrict__ wt) {
    int m = blockIdx.x >> 4, sub = blockIdx.x & 15;
    int Klog = t.Klog[m], K = 1 << Klog, Nn = t.N[m];
    int tot = K * Nn;
    const float* Wp = par + t.woff[m];
    ushort_t* d = wt + t.toff[m];
    for (int i = sub * 256 + threadIdx.x; i < tot; i += 16 * 256) {
        int n = i >> Klog, k = i & (K - 1);
        d[i] = f2bf(Wp[(size_t)k * Nn + n]);
    }
}

// ---------------- merged CSR build over concatenated node space ----------------
// count + per-edge rank (rank store is coalesced in e)
__global__ __launch_bounds__(256) void count3(const int* __restrict__ d0,
                                              const int* __restrict__ d1,
                                              const int* __restrict__ d2,
                                              int* __restrict__ cnt,
                                              int* __restrict__ rank) {
    int e = blockIdx.x * 256 + threadIdx.x;
    if (e >= E_ALL) return;
    int g;
    if (e < E_TIC) g = d0[e];
    else if (e < E_TIC + E_W) g = N_AC + d1[e - E_TIC];
    else g = N_AC + N_W + d2[e - E_TIC - E_W];
    rank[e] = atomicAdd(&cnt[g], 1);
}

__global__ __launch_bounds__(256) void scan_bsum(const int* __restrict__ cnt,
                                                 int* __restrict__ bsum, int N) {
    __shared__ int red[256];
    int i = blockIdx.x * 256 + threadIdx.x;
    red[threadIdx.x] = (i < N) ? cnt[i] : 0;
    __syncthreads();
    #pragma unroll
    for (int o = 128; o > 0; o >>= 1) {
        if (threadIdx.x < o) red[threadIdx.x] += red[threadIdx.x + o];
        __syncthreads();
    }
    if (threadIdx.x == 0) bsum[blockIdx.x] = red[0];
}

__global__ __launch_bounds__(512) void scan_top(int* __restrict__ bsum, int B) {
    __shared__ int sc[512];
    const int t = threadIdx.x;
    int v = (t < B) ? bsum[t] : 0;
    sc[t] = v;
    __syncthreads();
    #pragma unroll
    for (int o = 1; o < 512; o <<= 1) {
        int u = (t >= o) ? sc[t - o] : 0;
        __syncthreads();
        sc[t] += u;
        __syncthreads();
    }
    if (t < B) bsum[t] = sc[t] - v;
}

__global__ __launch_bounds__(256) void scan_out(const int* __restrict__ cnt,
                                                const int* __restrict__ bsum,
                                                int* __restrict__ rowptr, int N) {
    __shared__ int sc[256];
    const int t = threadIdx.x;
    int i = blockIdx.x * 256 + t;
    int v = (i < N) ? cnt[i] : 0;
    sc[t] = v;
    __syncthreads();
    #pragma unroll
    for (int o = 1; o < 256; o <<= 1) {
        int u = (t >= o) ? sc[t - o] : 0;
        __syncthreads();
        sc[t] += u;
        __syncthreads();
    }
    int ex = sc[t] - v + bsum[blockIdx.x];
    if (i < N) {
        rowptr[i] = ex;
        if (i == N - 1) rowptr[N] = ex + v;
    }
}

// atomic-free, dst-range-partitioned fill. adj entry: (src:16)|(ew_bf16:16).
// Class boundaries edge-balanced (~125K edges each); blockIdx&7 likely maps
// to a fixed XCD (round-robin dispatch), keeping each class's 500 KB adj
// write region resident in ONE L2 -> lines fill before eviction.
__global__ __launch_bounds__(256) void fill3(const int* __restrict__ s0, const int* __restrict__ d0, const void* __restrict__ w0,
                                             const int* __restrict__ s1, const int* __restrict__ d1, const void* __restrict__ w1,
                                             const int* __restrict__ s2, const int* __restrict__ d2, const void* __restrict__ w2,
                                             const int* __restrict__ flagp,
                                             const int* __restrict__ rp,
                                             const int* __restrict__ rank,
                                             unsigned* __restrict__ adj) {
    const int CB[9] = {0, 12500, 25000, 37500, 50000, 61250, 67500, 73750, 80000};
    const int cls = blockIdx.x & 7;
    const int lo = CB[cls], hi = CB[cls + 1];
    const int f = flagp[0];
    const int e0 = (blockIdx.x >> 3) * FCH;
    for (int i = threadIdx.x; i < FCH; i += 256) {
        int e = e0 + i;
        if (e >= E_ALL) return;
        int g;
        if (e < E_TIC) g = d0[e];
        else if (e < E_TIC + E_W) g = N_AC + d1[e - E_TIC];
        else g = N_AC + N_W + d2[e - E_TIC - E_W];
        if (g < lo || g >= hi) continue;
        int sn; float ew;
        if (e < E_TIC) { sn = s0[e]; ew = ldf(w0, e, f); }
        else if (e < E_TIC + E_W) { int le = e - E_TIC; sn = s1[le]; ew = ldf(w1, le, f); }
        else { int le = e - E_TIC - E_W; sn = s2[le]; ew = ldf(w2, le, f); }
        int pos = rp[g] + rank[e];
        adj[pos] = (unsigned)(sn & 0xFFFF) | ((unsigned)f2bf(ew) << 16);
    }
}

// ---------------- MFMA GEMM L1 + fused el/er epilogue ----------------
__global__ __launch_bounds__(256) void mgemm1(const void* __restrict__ X,
                                              const int* __restrict__ flagp,
                                              const ushort_t* __restrict__ WT,
                                              ushort_t* __restrict__ Zb,
                                              const float* __restrict__ alp,
                                              const float* __restrict__ arp,
                                              float* __restrict__ elo,
                                              float* __restrict__ ero, int N) {
    const int w = threadIdx.x >> 6, l = threadIdx.x & 63;
    const int row0 = blockIdx.x * 16;
    const int lr = l & 15, lk = l >> 4;
    const int f = flagp[0];

    bf16x8 a[4];
    if (!f) {
        const ushort_t* xp = (const ushort_t*)X + (size_t)(row0 + lr) * 128 + lk * 8;
        #pragma unroll
        for (int ks = 0; ks < 4; ++ks) a[ks] = *(const bf16x8*)(xp + ks * 32);
    } else {
        const float* xp = (const float*)X + (size_t)(row0 + lr) * 128 + lk * 8;
        #pragma unroll
        for (int ks = 0; ks < 4; ++ks)
            #pragma unroll
            for (int j = 0; j < 8; ++j) a[ks][j] = (short)f2bf(xp[ks * 32 + j]);
    }

    f32x4 acc[4] = {{0.f,0.f,0.f,0.f},{0.f,0.f,0.f,0.f},{0.f,0.f,0.f,0.f},{0.f,0.f,0.f,0.f}};
    const int col0 = w * 64;
    #pragma unroll
    for (int ks = 0; ks < 4; ++ks) {
        #pragma unroll
        for (int nt = 0; nt < 4; ++nt) {
            bf16x8 b = *(const bf16x8*)(WT + (size_t)(col0 + nt * 16 + lr) * 128 + ks * 32 + lk * 8);
            acc[nt] = __builtin_amdgcn_mfma_f32_16x16x32_bf16(a[ks], b, acc[nt], 0, 0, 0);
        }
    }
    #pragma unroll
    for (int nt = 0; nt < 4; ++nt)
        #pragma unroll
        for (int r = 0; r < 4; ++r)
            Zb[(size_t)(row0 + lk * 4 + r) * HD + col0 + nt * 16 + lr] = f2bf(acc[nt][r]);

    if (alp) {
        float a0 = alp[col0 + lr], a1 = alp[col0 + 16 + lr],
              a2 = alp[col0 + 32 + lr], a3 = alp[col0 + 48 + lr];
        #pragma unroll
        for (int r = 0; r < 4; ++r) {
            float v = acc[0][r] * a0 + acc[1][r] * a1 + acc[2][r] * a2 + acc[3][r] * a3;
            v += __shfl_xor(v, 1, 64); v += __shfl_xor(v, 2, 64);
            v += __shfl_xor(v, 4, 64); v += __shfl_xor(v, 8, 64);
            if (lr == r) elo[(size_t)(row0 + lk * 4 + r) * 4 + w] = v;
        }
    }
    if (arp) {
        float a0 = arp[col0 + lr], a1 = arp[col0 + 16 + lr],
              a2 = arp[col0 + 32 + lr], a3 = arp[col0 + 48 + lr];
        #pragma unroll
        for (int r = 0; r < 4; ++r) {
            float v = acc[0][r] * a0 + acc[1][r] * a1 + acc[2][r] * a2 + acc[3][r] * a3;
            v += __shfl_xor(v, 1, 64); v += __shfl_xor(v, 2, 64);
            v += __shfl_xor(v, 4, 64); v += __shfl_xor(v, 8, 64);
            if (lr == r) ero[(size_t)(row0 + lk * 4 + r) * 4 + w] = v;
        }
    }
}

// ---------------- MFMA GEMM L2 + fused el/er epilogue (H=1) ----------------
__global__ __launch_bounds__(256) void mgemm2(const ushort_t* __restrict__ Hb,
                                              const ushort_t* __restrict__ WT,
                                              ushort_t* __restrict__ Zb,
                                              const float* __restrict__ alp,
                                              const float* __restrict__ arp,
                                              float* __restrict__ elo,
                                              float* __restrict__ ero, int N) {
    const int w = threadIdx.x >> 6, l = threadIdx.x & 63;
    const int row0 = blockIdx.x * 64 + w * 16;
    if (row0 >= N) return;
    const int lr = l & 15, lk = l >> 4;
    const ushort_t* ap = Hb + (size_t)(row0 + lr) * 256 + lk * 8;

    f32x4 acc[4] = {{0.f,0.f,0.f,0.f},{0.f,0.f,0.f,0.f},{0.f,0.f,0.f,0.f},{0.f,0.f,0.f,0.f}};
    #pragma unroll
    for (int ks = 0; ks < 8; ++ks) {
        bf16x8 a = *(const bf16x8*)(ap + ks * 32);
        #pragma unroll
        for (int nt = 0; nt < 4; ++nt) {
            bf16x8 b = *(const bf16x8*)(WT + (size_t)(nt * 16 + lr) * 256 + ks * 32 + lk * 8);
            acc[nt] = __builtin_amdgcn_mfma_f32_16x16x32_bf16(a, b, acc[nt], 0, 0, 0);
        }
    }
    #pragma unroll
    for (int nt = 0; nt < 4; ++nt)
        #pragma unroll
        for (int r = 0; r < 4; ++r)
            Zb[(size_t)(row0 + lk * 4 + r) * DOUT + nt * 16 + lr] = f2bf(acc[nt][r]);

    if (alp) {
        float a0 = alp[lr], a1 = alp[16 + lr], a2 = alp[32 + lr], a3 = alp[48 + lr];
        #pragma unroll
        for (int r = 0; r < 4; ++r) {
            float v = acc[0][r] * a0 + acc[1][r] * a1 + acc[2][r] * a2 + acc[3][r] * a3;
            v += __shfl_xor(v, 1, 64); v += __shfl_xor(v, 2, 64);
            v += __shfl_xor(v, 4, 64); v += __shfl_xor(v, 8, 64);
            if (lr == r) elo[row0 + lk * 4 + r] = v;
        }
    }
    if (arp) {
        float a0 = arp[lr], a1 = arp[16 + lr], a2 = arp[32 + lr], a3 = arp[48 + lr];
        #pragma unroll
        for (int r = 0; r < 4; ++r) {
            float v = acc[0][r] * a0 + acc[1][r] * a1 + acc[2][r] * a2 + acc[3][r] * a3;
            v += __shfl_xor(v, 1, 64); v += __shfl_xor(v, 2, 64);
            v += __shfl_xor(v, 4, 64); v += __shfl_xor(v, 8, 64);
            if (lr == r) ero[row0 + lk * 4 + r] = v;
        }
    }
}

// ---------------- elr1: single q-dot per node (rel-dst projections only) ----------------
__global__ __launch_bounds__(256) void elr1(const void* __restrict__ X,
                                            const int* __restrict__ flagp,
                                            const float* __restrict__ q0,
                                            float* __restrict__ o0,
                                            int N, int D, int Hh) {
    __shared__ float qs[512];
    const int tid = threadIdx.x;
    const int f = flagp ? flagp[0] : 0;
    const int tot = D * Hh;
    for (int i = tid; i < tot; i += 256) {
        int k, h;
        if (Hh == 4) { k = i >> 2; h = i & 3; } else { k = i; h = 0; }
        qs[h * D + k] = q0[i];
    }
    __syncthreads();
    const int wid = tid >> 6, lane = tid & 63;
    const int n = blockIdx.x * 4 + wid;
    if (n >= N) return;
    const int J = D >> 6;
    float x[4];
    for (int j = 0; j < J; ++j) x[j] = ldf(X, (size_t)n * D + j * 64 + lane, f);
    for (int h = 0; h < Hh; ++h) {
        float v = 0.f;
        for (int j = 0; j < J; ++j) v += x[j] * qs[h * D + j * 64 + lane];
        #pragma unroll
        for (int o = 32; o > 0; o >>= 1) v += __shfl_down(v, o, 64);
        if (lane == 0) o0[n * Hh + h] = v;
    }
}

// ---------------- fused CSR gather, layer 1 (H=4, D=256) ----------------
template <int MODE>
__global__ __launch_bounds__(256) void gat1(const int* __restrict__ rp,
                                            const unsigned* __restrict__ adj,
                                            const ushort_t* __restrict__ zb,
                                            const float* __restrict__ el,
                                            const float* __restrict__ er,
                                            const float* __restrict__ bias,
                                            ushort_t* __restrict__ H, int N) {
    __shared__ float atl[4][CAP * 4];
    __shared__ int   snl[4][CAP];
    const int w = threadIdx.x >> 6, lane = threadIdx.x & 63;
    const int n = blockIdx.x * 4 + w;
    if (n >= N) return;
    const int h = lane >> 4;
    const int beg = rp[n], deg = rp[n + 1] - beg;
    const float4* el4 = (const float4*)el;
    const float4 ern = ((const float4*)er)[n];

    float4 ss = make_float4(0.f, 0.f, 0.f, 0.f);
    for (int base = 0; base < deg; base += 64) {
        int i = base + lane;
        if (i < deg) {
            unsigned ae = adj[beg + i];
            int sn = ae & 0xFFFF;
            float4 e = el4[sn];
            float x0 = lrelu_exp(e.x + ern.x);
            float x1 = lrelu_exp(e.y + ern.y);
            float x2 = lrelu_exp(e.z + ern.z);
            float x3 = lrelu_exp(e.w + ern.w);
            ss.x += x0; ss.y += x1; ss.z += x2; ss.w += x3;
            if (i < CAP) {
                float ew = bf2f((ushort_t)(ae >> 16));
                float4* dst4 = (float4*)&atl[w][i * 4];
                *dst4 = make_float4(x0 * ew, x1 * ew, x2 * ew, x3 * ew);
                snl[w][i] = sn;
            }
        }
    }
    #pragma unroll
    for (int o = 32; o > 0; o >>= 1) {
        ss.x += __shfl_xor(ss.x, o, 64);
        ss.y += __shfl_xor(ss.y, o, 64);
        ss.z += __shfl_xor(ss.z, o, 64);
        ss.w += __shfl_xor(ss.w, o, 64);
    }
    const float sh = (h == 0) ? ss.x : (h == 1) ? ss.y : (h == 2) ? ss.z : ss.w;
    const float inv = 1.f / (sh + 1e-9f);
    const float erh = (h == 0) ? ern.x : (h == 1) ? ern.y : (h == 2) ? ern.z : ern.w;

    float a0 = 0.f, a1 = 0.f, a2 = 0.f, a3 = 0.f;
    #pragma unroll 2
    for (int i = 0; i < deg; ++i) {
        int sn; float atv;
        if (i < CAP) {
            sn = snl[w][i];
            atv = atl[w][i * 4 + h];
        } else {
            unsigned ae = adj[beg + i];
            sn = ae & 0xFFFF;
            atv = lrelu_exp(el[sn * 4 + h] + erh) * bf2f((ushort_t)(ae >> 16));
        }
        ushort4 zv = *(const ushort4*)(zb + (size_t)sn * HD + lane * 4);
        a0 += bf2f(zv.x) * atv; a1 += bf2f(zv.y) * atv;
        a2 += bf2f(zv.z) * atv; a3 += bf2f(zv.w) * atv;
    }
    float4 b = *(const float4*)(bias + lane * 4);
    a0 = a0 * inv + b.x; a1 = a1 * inv + b.y;
    a2 = a2 * inv + b.z; a3 = a3 * inv + b.w;

    ushort_t* hp = H + (size_t)n * HD + lane * 4;
    ushort4 o;
    if (MODE == 0) {
        o.x = f2bf(a0 > 0.f ? a0 : 0.f); o.y = f2bf(a1 > 0.f ? a1 : 0.f);
        o.z = f2bf(a2 > 0.f ? a2 : 0.f); o.w = f2bf(a3 > 0.f ? a3 : 0.f);
    } else if (MODE == 1) {
        o.x = f2bf(a0 > 0.f ? a0 : expm1f(a0)); o.y = f2bf(a1 > 0.f ? a1 : expm1f(a1));
        o.z = f2bf(a2 > 0.f ? a2 : expm1f(a2)); o.w = f2bf(a3 > 0.f ? a3 : expm1f(a3));
    } else {
        ushort4 hw = *(const ushort4*)hp;
        float v0 = (bf2f(hw.x) + (a0 > 0.f ? a0 : expm1f(a0))) * 0.5f;
        float v1 = (bf2f(hw.y) + (a1 > 0.f ? a1 : expm1f(a1))) * 0.5f;
        float v2 = (bf2f(hw.z) + (a2 > 0.f ? a2 : expm1f(a2))) * 0.5f;
        float v3 = (bf2f(hw.w) + (a3 > 0.f ? a3 : expm1f(a3))) * 0.5f;
        o.x = f2bf(v0 > 0.f ? v0 : 0.f); o.y = f2bf(v1 > 0.f ? v1 : 0.f);
        o.z = f2bf(v2 > 0.f ? v2 : 0.f); o.w = f2bf(v3 > 0.f ? v3 : 0.f);
    }
    *(ushort4*)hp = o;
}

// ---------------- fused CSR gather + epilogue, layer 2 (H=1, D=64) ----------------
template <int MODE>
__global__ __launch_bounds__(256) void gat2(const int* __restrict__ rp,
                                            const unsigned* __restrict__ adj,
                                            const ushort_t* __restrict__ zb,
                                            const float* __restrict__ el,
                                            const float* __restrict__ er,
                                            const float* __restrict__ b1,
                                            const float* __restrict__ b2,
                                            float* __restrict__ ACC,
                                            void* __restrict__ out,
                                            const int* __restrict__ flagp, int N) {
    __shared__ float atl[4][CAP];
    __shared__ int   snl[4][CAP];
    const int w = threadIdx.x >> 6, lane = threadIdx.x & 63;
    const int n = blockIdx.x * 4 + w;
    if (n >= N) return;
    const int beg = rp[n], deg = rp[n + 1] - beg;
    const float ern = er[n];

    float ssum = 0.f;
    for (int base = 0; base < deg; base += 64) {
        int i = base + lane;
        if (i < deg) {
            unsigned ae = adj[beg + i];
            int sn = ae & 0xFFFF;
            float x = lrelu_exp(el[sn] + ern);
            ssum += x;
            if (i < CAP) {
                atl[w][i] = x * bf2f((ushort_t)(ae >> 16));
                snl[w][i] = sn;
            }
        }
    }
    #pragma unroll
    for (int o = 32; o > 0; o >>= 1) ssum += __shfl_xor(ssum, o, 64);
    const float inv = 1.f / (ssum + 1e-9f);

    float a = 0.f;
    #pragma unroll 2
    for (int i = 0; i < deg; ++i) {
        int sn; float atv;
        if (i < CAP) {
            sn = snl[w][i];
            atv = atl[w][i];
        } else {
            unsigned ae = adj[beg + i];
            sn = ae & 0xFFFF;
            atv = lrelu_exp(el[sn] + ern) * bf2f((ushort_t)(ae >> 16));
        }
        a += bf2f(zb[(size_t)sn * DOUT + lane]) * atv;
    }
    a *= inv;

    if (MODE == 0) {
        float v = a + b1[lane];
        size_t o = (size_t)n * DOUT + lane;
        if (flagp[0]) ((float*)out)[o] = v;
        else ((ushort_t*)out)[o] = f2bf(v);
    } else if (MODE == 1) {
        ACC[(size_t)n * DOUT + lane] = a;
    } else {
        float v = ((ACC[(size_t)n * DOUT + lane] + b1[lane]) + (a + b2[lane])) * 0.5f;
        size_t o = (size_t)N_AC * DOUT + (size_t)n * DOUT + lane;
        if (flagp[0]) ((float*)out)[o] = v;
        else ((ushort_t*)out)[o] = f2bf(v);
    }
}

// ---------------- host launch ----------------
extern "C" void kernel_launch(void* const* d_in, const int* in_sizes, int n_in,
                              void* d_out, int out_size, void* d_ws, size_t ws_size,
                              hipStream_t stream) {
    (void)in_sizes; (void)n_in; (void)out_size; (void)ws_size;

    const void* x_ac = d_in[0];
    const void* x_w  = d_in[1];
    const void* ew_tic = d_in[2];
    const void* ew_w   = d_in[3];
    const void* ew_rel = d_in[4];
    const int* src_tic = (const int*)d_in[29];
    const int* dst_tic = (const int*)d_in[30];
    const int* src_w   = (const int*)d_in[31];
    const int* dst_w   = (const int*)d_in[32];
    const int* src_rel = (const int*)d_in[33];
    const int* dst_rel = (const int*)d_in[34];

    float* ws = (float*)d_ws;
    int* FLAG = (int*)ws;

    float* PAR = ws + 16;
    const int o_W1t = 1000000, o_W1w = 1032768, o_W1r = 1065536;
    const int o_W2t = 1098304, o_W2w = 1114688, o_W2r = 1131072;
    const int o_al1t = 1147456, o_ar1t = 1147712, o_al1w = 1147968, o_ar1w = 1148224,
              o_al1r = 1148480, o_ar1r = 1148736;
    const int o_b1t = 1148992, o_b1w = 1149248, o_b1r = 1149504;
    const int o_al2t = 1149760, o_ar2t = 1149824, o_al2w = 1149888, o_ar2w = 1149952,
              o_al2r = 1150016, o_ar2r = 1150080;
    const int o_b2t = 1150144, o_b2w = 1150208, o_b2r = 1150272;
    const int o_qer1r = 1150400, o_qer2r = 1150912;

    float* EB   = ws + 1160016;
    float* ELt  = EB;
    float* ERt  = EB + 160000;
    float* ELw  = EB + 320000;
    float* ERw  = EB + 400000;
    float* ELr  = EB + 480000;
    float* ERr  = EB + 640000;
    float* E2tl = EB + 720000;
    float* E2tr = EB + 760000;
    float* E2wl = EB + 800000;
    float* E2wr = EB + 820000;
    float* E2rl = EB + 840000;
    float* E2rr = EB + 880000;
    float* ACC = ws + 2060016;                   // 1,280,000
    ushort_t* Zb  = (ushort_t*)(ws + 3340016);   // 10.24M bf16
    ushort_t* Hac = (ushort_t*)(ws + 8460016);   // 40000x256 bf16
    ushort_t* Hw  = (ushort_t*)(ws + 13580016);  // 20000x256 bf16
    ushort_t* WT  = (ushort_t*)(ws + 16140016);  // 147456 bf16
    const int t_W1t = 0, t_W1w = 32768, t_W1r = 65536,
              t_W2t = 98304, t_W2w = 114688, t_W2r = 131072;
    int* IB = (int*)(ws + 16213760);
    int* rp   = IB;                              // N_ALL + 1
    int* cnt  = IB + 80064;                      // N_ALL
    int* bsum = IB + 160128;                     // 512
    unsigned* adj = (unsigned*)(IB + 160704);    // E_ALL x 4B
    int* rank = IB + 1160704;                    // E_ALL
    // end: IB + 2,160,704 ints -> ws + 18,374,464 floats = 73.5 MB

    // ---- P0: dtype, params, q vectors, packed W^T ----
    detect_dtype<<<1, 256, 0, stream>>>((const ushort_t*)x_ac, FLAG);

    CvtTab ct;
    const int srcIdx[24] = {5,6,7,8, 9,10,11,12, 13,14,15,16,
                            17,18,19,20, 21,22,23,24, 25,26,27,28};
    const int sizes[24] = {32768,256,256,256, 32768,256,256,256, 32768,256,256,256,
                           16384,64,64,64, 16384,64,64,64, 16384,64,64,64};
    const int offs[24] = {o_W1t,o_al1t,o_ar1t,o_b1t, o_W1w,o_al1w,o_ar1w,o_b1w,
                          o_W1r,o_al1r,o_ar1r,o_b1r,
                          o_W2t,o_al2t,o_ar2t,o_b2t, o_W2w,o_al2w,o_ar2w,o_b2w,
                          o_W2r,o_al2r,o_ar2r,o_b2r};
    for (int i = 0; i < 24; ++i) { ct.src[i] = d_in[srcIdx[i]]; ct.n[i] = sizes[i]; ct.off[i] = offs[i]; }
    cvt_inputs<<<24 * 8, 256, 0, stream>>>(ct, PAR, FLAG);

    QTab qt;
    qt.woff[0] = o_W1r; qt.aoff[0] = o_ar1r; qt.qoff[0] = o_qer1r; qt.K[0] = 128; qt.Hh[0] = 4;
    qt.woff[1] = o_W2r; qt.aoff[1] = o_ar2r; qt.qoff[1] = o_qer2r; qt.K[1] = 256; qt.Hh[1] = 1;
    make_q<<<2, 256, 0, stream>>>(qt, PAR);

    PTab pt;
    const int pw[6] = {o_W1t, o_W1w, o_W1r, o_W2t, o_W2w, o_W2r};
    const int ptf[6] = {t_W1t, t_W1w, t_W1r, t_W2t, t_W2w, t_W2r};
    for (int i = 0; i < 6; ++i) {
        pt.woff[i] = pw[i]; pt.toff[i] = ptf[i];
        pt.Klog[i] = (i < 3) ? 7 : 8; pt.N[i] = (i < 3) ? 256 : 64;
    }
    pack_wt<<<6 * 16, 256, 0, stream>>>(pt, PAR, WT);

    // ---- P0b: merged CSR build (rank-based, atomic-free fill) ----
    {
        const int B = (N_ALL + 255) / 256;   // 313
        hipMemsetAsync(cnt, 0, N_ALL * 4, stream);
        count3<<<(E_ALL + 255) / 256, 256, 0, stream>>>(dst_tic, dst_w, dst_rel, cnt, rank);
        scan_bsum<<<B, 256, 0, stream>>>(cnt, bsum, N_ALL);
        scan_top<<<1, 512, 0, stream>>>(bsum, B);
        scan_out<<<B, 256, 0, stream>>>(cnt, bsum, rp, N_ALL);
        fill3<<<8 * ((E_ALL + FCH - 1) / FCH), 256, 0, stream>>>(
            src_tic, dst_tic, ew_tic, src_w, dst_w, ew_w, src_rel, dst_rel, ew_rel,
            FLAG, rp, rank, adj);
    }
    const int* rp_tic = rp;
    const int* rp_w   = rp + N_AC;
    const int* rp_rel = rp + N_AC + N_W;

    // rel-dst er for layer 1 (x_w with q = W1r·ar1r)
    elr1<<<N_W / 4, 256, 0, stream>>>(x_w, FLAG, PAR + o_qer1r, ERr, N_W, 128, 4);

    // ---- P1: tic GAT layer 1 -> Hac ----
    mgemm1<<<N_AC / 16, 256, 0, stream>>>(x_ac, FLAG, WT + t_W1t, Zb,
                                          PAR + o_al1t, PAR + o_ar1t, ELt, ERt, N_AC);
    gat1<0><<<N_AC / 4, 256, 0, stream>>>(rp_tic, adj, Zb, ELt, ERt, PAR + o_b1t, Hac, N_AC);

    // ---- P2: w GAT layer 1 -> Hw (elu) ----
    mgemm1<<<N_W / 16, 256, 0, stream>>>(x_w, FLAG, WT + t_W1w, Zb,
                                         PAR + o_al1w, PAR + o_ar1w, ELw, ERw, N_W);
    gat1<1><<<N_W / 4, 256, 0, stream>>>(rp_w, adj, Zb, ELw, ERw, PAR + o_b1w, Hw, N_W);

    // ---- P3: rel GAT layer 1; combine -> Hw = h_word ----
    mgemm1<<<N_AC / 16, 256, 0, stream>>>(x_ac, FLAG, WT + t_W1r, Zb,
                                          PAR + o_al1r, nullptr, ELr, nullptr, N_AC);
    gat1<2><<<N_W / 4, 256, 0, stream>>>(rp_rel, adj, Zb, ELr, ERr, PAR + o_b1r, Hw, N_W);

    // rel-dst er for layer 2 (Hw with q = W2r·ar2r)
    elr1<<<N_W / 4, 256, 0, stream>>>(Hw, nullptr, PAR + o_qer2r, E2rr, N_W, 256, 1);

    // ---- P4: tic GAT layer 2 -> out[0 : 40000*64] ----
    mgemm2<<<(N_AC + 63) / 64, 256, 0, stream>>>(Hac, WT + t_W2t, Zb,
                                                 PAR + o_al2t, PAR + o_ar2t, E2tl, E2tr, N_AC);
    gat2<0><<<N_AC / 4, 256, 0, stream>>>(rp_tic, adj, Zb, E2tl, E2tr,
                                          PAR + o_b2t, nullptr, ACC, d_out, FLAG, N_AC);

    // ---- P5: w GAT layer 2 -> ACC ----
    mgemm2<<<(N_W + 63) / 64, 256, 0, stream>>>(Hw, WT + t_W2w, Zb,
                                                PAR + o_al2w, PAR + o_ar2w, E2wl, E2wr, N_W);
    gat2<1><<<N_W / 4, 256, 0, stream>>>(rp_w, adj, Zb, E2wl, E2wr,
                                         nullptr, nullptr, ACC, d_out, FLAG, N_W);

    // ---- P6: rel GAT layer 2; combine -> out word ----
    mgemm2<<<(N_AC + 63) / 64, 256, 0, stream>>>(Hac, WT + t_W2r, Zb,
                                                 PAR + o_al2r, nullptr, E2rl, nullptr, N_AC);
    gat2<2><<<N_W / 4, 256, 0, stream>>>(rp_rel, adj, Zb, E2rl, E2rr,
                                         PAR + o_b2w, PAR + o_b2r, ACC, d_out, FLAG, N_W);
}

// Round 10
// 400.723 us; speedup vs baseline: 11.1582x; 1.0787x over previous
//
#include <hip/hip_runtime.h>
#include <hip/hip_bf16.h>

typedef unsigned short ushort_t;
typedef __attribute__((ext_vector_type(8))) short bf16x8;
typedef __attribute__((ext_vector_type(4))) float f32x4;

// ---------------- constants ----------------
#define N_AC 40000
#define N_W  20000
#define D_IN 128
#define NH   4
#define HD   256   // NH*DH
#define DOUT 64
#define E_TIC 400000
#define E_W   200000
#define E_REL 400000
#define E_ALL 1000000
#define N_ALL 80000
#define NEG 0.2f
#define CAP 96     // max expected degree ~55 (Poisson lambda<=20); fallback recomputes
#define FCH 4096

__device__ __forceinline__ float bf2f(ushort_t u) {
    return __uint_as_float(((unsigned int)u) << 16);
}
__device__ __forceinline__ ushort_t f2bf(float v) {
    unsigned u = __float_as_uint(v);
    unsigned r = (u + 0x7fffu + ((u >> 16) & 1u)) >> 16;
    return (ushort_t)r;
}
__device__ __forceinline__ float ldf(const void* p, size_t i, int f) {
    return f ? ((const float*)p)[i] : bf2f(((const ushort_t*)p)[i]);
}
__device__ __forceinline__ float lrelu_exp(float v) {
    v = v > 0.f ? v : NEG * v;
    return __expf(v);
}

// ---------------- dtype autodetect ----------------
__global__ void detect_dtype(const ushort_t* __restrict__ x, int* __restrict__ flag) {
    __shared__ int hit;
    if (threadIdx.x == 0) hit = 0;
    __syncthreads();
    for (int i = threadIdx.x; i < 4096; i += 256) {
        float v = bf2f(x[i]);
        if (!(fabsf(v) <= 1e4f)) atomicOr(&hit, 1);
    }
    __syncthreads();
    if (threadIdx.x == 0) flag[0] = hit ? 1 : 0;
}

// ---------------- canonicalize 24 small param tensors to f32 ----------------
struct CvtTab { const void* src[24]; int n[24]; int off[24]; };
__global__ __launch_bounds__(256) void cvt_inputs(CvtTab t, float* __restrict__ par,
                                                  const int* __restrict__ flagp) {
    int ent = blockIdx.x >> 3, sub = blockIdx.x & 7;
    int f = flagp[0];
    const void* s = t.src[ent];
    int n = t.n[ent];
    float* d = par + t.off[ent];
    for (int i = sub * 256 + threadIdx.x; i < n; i += 8 * 256)
        d[i] = f ? ((const float*)s)[i] : bf2f(((const ushort_t*)s)[i]);
}

// ---------------- q vectors (rel-dst cases only) ----------------
struct QTab { int woff[2]; int aoff[2]; int qoff[2]; int K[2]; int Hh[2]; };
__global__ __launch_bounds__(256) void make_q(QTab t, float* __restrict__ par) {
    int b = blockIdx.x;
    int k = threadIdx.x;
    int K = t.K[b], Hh = t.Hh[b];
    if (k >= K) return;
    const float* W = par + t.woff[b];
    const float* a = par + t.aoff[b];
    float* q = par + t.qoff[b];
    int HDc = Hh * 64;
    for (int h = 0; h < Hh; ++h) {
        float s = 0.f;
        for (int d = 0; d < 64; ++d) s += W[(size_t)k * HDc + h * 64 + d] * a[h * 64 + d];
        q[k * Hh + h] = s;
    }
}

// ---------------- pack W^T to bf16 (N x K row-major) ----------------
struct PTab { int woff[6]; int toff[6]; int Klog[6]; int N[6]; };
__global__ __launch_bounds__(256) void pack_wt(PTab t, const float* __restrict__ par,
                                               ushort_t* __restrict__ wt) {
    int m = blockIdx.x >> 4, sub = blockIdx.x & 15;
    int Klog = t.Klog[m], K = 1 << Klog, Nn = t.N[m];
    int tot = K * Nn;
    const float* Wp = par + t.woff[m];
    ushort_t* d = wt + t.toff[m];
    for (int i = sub * 256 + threadIdx.x; i < tot; i += 16 * 256) {
        int n = i >> Klog, k = i & (K - 1);
        d[i] = f2bf(Wp[(size_t)k * Nn + n]);
    }
}

// ---------------- merged CSR build ----------------
__global__ __launch_bounds__(256) void count3(const int* __restrict__ d0,
                                              const int* __restrict__ d1,
                                              const int* __restrict__ d2,
                                              int* __restrict__ cnt,
                                              int* __restrict__ rank) {
    int e = blockIdx.x * 256 + threadIdx.x;
    if (e >= E_ALL) return;
    int g;
    if (e < E_TIC) g = d0[e];
    else if (e < E_TIC + E_W) g = N_AC + d1[e - E_TIC];
    else g = N_AC + N_W + d2[e - E_TIC - E_W];
    rank[e] = atomicAdd(&cnt[g], 1);
}

__global__ __launch_bounds__(256) void scan_bsum(const int* __restrict__ cnt,
                                                 int* __restrict__ bsum, int N) {
    __shared__ int red[256];
    int i = blockIdx.x * 256 + threadIdx.x;
    red[threadIdx.x] = (i < N) ? cnt[i] : 0;
    __syncthreads();
    #pragma unroll
    for (int o = 128; o > 0; o >>= 1) {
        if (threadIdx.x < o) red[threadIdx.x] += red[threadIdx.x + o];
        __syncthreads();
    }
    if (threadIdx.x == 0) bsum[blockIdx.x] = red[0];
}

__global__ __launch_bounds__(512) void scan_top(int* __restrict__ bsum, int B) {
    __shared__ int sc[512];
    const int t = threadIdx.x;
    int v = (t < B) ? bsum[t] : 0;
    sc[t] = v;
    __syncthreads();
    #pragma unroll
    for (int o = 1; o < 512; o <<= 1) {
        int u = (t >= o) ? sc[t - o] : 0;
        __syncthreads();
        sc[t] += u;
        __syncthreads();
    }
    if (t < B) bsum[t] = sc[t] - v;
}

__global__ __launch_bounds__(256) void scan_out(const int* __restrict__ cnt,
                                                const int* __restrict__ bsum,
                                                int* __restrict__ rowptr, int N) {
    __shared__ int sc[256];
    const int t = threadIdx.x;
    int i = blockIdx.x * 256 + t;
    int v = (i < N) ? cnt[i] : 0;
    sc[t] = v;
    __syncthreads();
    #pragma unroll
    for (int o = 1; o < 256; o <<= 1) {
        int u = (t >= o) ? sc[t - o] : 0;
        __syncthreads();
        sc[t] += u;
        __syncthreads();
    }
    int ex = sc[t] - v + bsum[blockIdx.x];
    if (i < N) {
        rowptr[i] = ex;
        if (i == N - 1) rowptr[N] = ex + v;
    }
}

// atomic-free, dst-range-partitioned fill. adj entry: (src:16)|(ew_bf16:16)
__global__ __launch_bounds__(256) void fill3(const int* __restrict__ s0, const int* __restrict__ d0, const void* __restrict__ w0,
                                             const int* __restrict__ s1, const int* __restrict__ d1, const void* __restrict__ w1,
                                             const int* __restrict__ s2, const int* __restrict__ d2, const void* __restrict__ w2,
                                             const int* __restrict__ flagp,
                                             const int* __restrict__ rp,
                                             const int* __restrict__ rank,
                                             unsigned* __restrict__ adj) {
    const int CB[9] = {0, 12500, 25000, 37500, 50000, 61250, 67500, 73750, 80000};
    const int cls = blockIdx.x & 7;
    const int lo = CB[cls], hi = CB[cls + 1];
    const int f = flagp[0];
    const int e0 = (blockIdx.x >> 3) * FCH;
    for (int i = threadIdx.x; i < FCH; i += 256) {
        int e = e0 + i;
        if (e >= E_ALL) return;
        int g;
        if (e < E_TIC) g = d0[e];
        else if (e < E_TIC + E_W) g = N_AC + d1[e - E_TIC];
        else g = N_AC + N_W + d2[e - E_TIC - E_W];
        if (g < lo || g >= hi) continue;
        int sn; float ew;
        if (e < E_TIC) { sn = s0[e]; ew = ldf(w0, e, f); }
        else if (e < E_TIC + E_W) { int le = e - E_TIC; sn = s1[le]; ew = ldf(w1, le, f); }
        else { int le = e - E_TIC - E_W; sn = s2[le]; ew = ldf(w2, le, f); }
        int pos = rp[g] + rank[e];
        adj[pos] = (unsigned)(sn & 0xFFFF) | ((unsigned)f2bf(ew) << 16);
    }
}

// ---------------- MFMA GEMM L1 + fused el/er epilogue ----------------
__global__ __launch_bounds__(256) void mgemm1(const void* __restrict__ X,
                                              const int* __restrict__ flagp,
                                              const ushort_t* __restrict__ WT,
                                              ushort_t* __restrict__ Zb,
                                              const float* __restrict__ alp,
                                              const float* __restrict__ arp,
                                              float* __restrict__ elo,
                                              float* __restrict__ ero, int N) {
    const int w = threadIdx.x >> 6, l = threadIdx.x & 63;
    const int row0 = blockIdx.x * 16;
    const int lr = l & 15, lk = l >> 4;
    const int f = flagp[0];

    bf16x8 a[4];
    if (!f) {
        const ushort_t* xp = (const ushort_t*)X + (size_t)(row0 + lr) * 128 + lk * 8;
        #pragma unroll
        for (int ks = 0; ks < 4; ++ks) a[ks] = *(const bf16x8*)(xp + ks * 32);
    } else {
        const float* xp = (const float*)X + (size_t)(row0 + lr) * 128 + lk * 8;
        #pragma unroll
        for (int ks = 0; ks < 4; ++ks)
            #pragma unroll
            for (int j = 0; j < 8; ++j) a[ks][j] = (short)f2bf(xp[ks * 32 + j]);
    }

    f32x4 acc[4] = {{0.f,0.f,0.f,0.f},{0.f,0.f,0.f,0.f},{0.f,0.f,0.f,0.f},{0.f,0.f,0.f,0.f}};
    const int col0 = w * 64;
    #pragma unroll
    for (int ks = 0; ks < 4; ++ks) {
        #pragma unroll
        for (int nt = 0; nt < 4; ++nt) {
            bf16x8 b = *(const bf16x8*)(WT + (size_t)(col0 + nt * 16 + lr) * 128 + ks * 32 + lk * 8);
            acc[nt] = __builtin_amdgcn_mfma_f32_16x16x32_bf16(a[ks], b, acc[nt], 0, 0, 0);
        }
    }
    #pragma unroll
    for (int nt = 0; nt < 4; ++nt)
        #pragma unroll
        for (int r = 0; r < 4; ++r)
            Zb[(size_t)(row0 + lk * 4 + r) * HD + col0 + nt * 16 + lr] = f2bf(acc[nt][r]);

    if (alp) {
        float a0 = alp[col0 + lr], a1 = alp[col0 + 16 + lr],
              a2 = alp[col0 + 32 + lr], a3 = alp[col0 + 48 + lr];
        #pragma unroll
        for (int r = 0; r < 4; ++r) {
            float v = acc[0][r] * a0 + acc[1][r] * a1 + acc[2][r] * a2 + acc[3][r] * a3;
            v += __shfl_xor(v, 1, 64); v += __shfl_xor(v, 2, 64);
            v += __shfl_xor(v, 4, 64); v += __shfl_xor(v, 8, 64);
            if (lr == r) elo[(size_t)(row0 + lk * 4 + r) * 4 + w] = v;
        }
    }
    if (arp) {
        float a0 = arp[col0 + lr], a1 = arp[col0 + 16 + lr],
              a2 = arp[col0 + 32 + lr], a3 = arp[col0 + 48 + lr];
        #pragma unroll
        for (int r = 0; r < 4; ++r) {
            float v = acc[0][r] * a0 + acc[1][r] * a1 + acc[2][r] * a2 + acc[3][r] * a3;
            v += __shfl_xor(v, 1, 64); v += __shfl_xor(v, 2, 64);
            v += __shfl_xor(v, 4, 64); v += __shfl_xor(v, 8, 64);
            if (lr == r) ero[(size_t)(row0 + lk * 4 + r) * 4 + w] = v;
        }
    }
}

// ---------------- MFMA GEMM L2 fused over 3 etype segments ----------------
struct G2 {
    const ushort_t* Hb[3]; const ushort_t* WT[3]; ushort_t* Zc[3];
    const float* al[3]; const float* ar[3]; float* el[3]; float* er[3];
    int N[3]; int b1, b2;   // segment boundaries in blocks
};
__global__ __launch_bounds__(256) void mgemm2_all(G2 t) {
    int s, b;
    if (blockIdx.x < (unsigned)t.b1) { s = 0; b = blockIdx.x; }
    else if (blockIdx.x < (unsigned)t.b2) { s = 1; b = blockIdx.x - t.b1; }
    else { s = 2; b = blockIdx.x - t.b2; }
    const int w = threadIdx.x >> 6, l = threadIdx.x & 63;
    const int row0 = b * 64 + w * 16;
    if (row0 >= t.N[s]) return;
    const int lr = l & 15, lk = l >> 4;
    const ushort_t* ap = t.Hb[s] + (size_t)(row0 + lr) * 256 + lk * 8;
    const ushort_t* WT = t.WT[s];

    f32x4 acc[4] = {{0.f,0.f,0.f,0.f},{0.f,0.f,0.f,0.f},{0.f,0.f,0.f,0.f},{0.f,0.f,0.f,0.f}};
    #pragma unroll
    for (int ks = 0; ks < 8; ++ks) {
        bf16x8 a = *(const bf16x8*)(ap + ks * 32);
        #pragma unroll
        for (int nt = 0; nt < 4; ++nt) {
            bf16x8 bb = *(const bf16x8*)(WT + (size_t)(nt * 16 + lr) * 256 + ks * 32 + lk * 8);
            acc[nt] = __builtin_amdgcn_mfma_f32_16x16x32_bf16(a, bb, acc[nt], 0, 0, 0);
        }
    }
    ushort_t* Zc = t.Zc[s];
    #pragma unroll
    for (int nt = 0; nt < 4; ++nt)
        #pragma unroll
        for (int r = 0; r < 4; ++r)
            Zc[(size_t)(row0 + lk * 4 + r) * DOUT + nt * 16 + lr] = f2bf(acc[nt][r]);

    if (t.al[s]) {
        const float* alp = t.al[s];
        float a0 = alp[lr], a1 = alp[16 + lr], a2 = alp[32 + lr], a3 = alp[48 + lr];
        #pragma unroll
        for (int r = 0; r < 4; ++r) {
            float v = acc[0][r] * a0 + acc[1][r] * a1 + acc[2][r] * a2 + acc[3][r] * a3;
            v += __shfl_xor(v, 1, 64); v += __shfl_xor(v, 2, 64);
            v += __shfl_xor(v, 4, 64); v += __shfl_xor(v, 8, 64);
            if (lr == r) t.el[s][row0 + lk * 4 + r] = v;
        }
    }
    if (t.ar[s]) {
        const float* arp = t.ar[s];
        float a0 = arp[lr], a1 = arp[16 + lr], a2 = arp[32 + lr], a3 = arp[48 + lr];
        #pragma unroll
        for (int r = 0; r < 4; ++r) {
            float v = acc[0][r] * a0 + acc[1][r] * a1 + acc[2][r] * a2 + acc[3][r] * a3;
            v += __shfl_xor(v, 1, 64); v += __shfl_xor(v, 2, 64);
            v += __shfl_xor(v, 4, 64); v += __shfl_xor(v, 8, 64);
            if (lr == r) t.er[s][row0 + lk * 4 + r] = v;
        }
    }
}

// ---------------- elr1: single q-dot per node ----------------
__global__ __launch_bounds__(256) void elr1(const void* __restrict__ X,
                                            const int* __restrict__ flagp,
                                            const float* __restrict__ q0,
                                            float* __restrict__ o0,
                                            int N, int D, int Hh) {
    __shared__ float qs[512];
    const int tid = threadIdx.x;
    const int f = flagp ? flagp[0] : 0;
    const int tot = D * Hh;
    for (int i = tid; i < tot; i += 256) {
        int k, h;
        if (Hh == 4) { k = i >> 2; h = i & 3; } else { k = i; h = 0; }
        qs[h * D + k] = q0[i];
    }
    __syncthreads();
    const int wid = tid >> 6, lane = tid & 63;
    const int n = blockIdx.x * 4 + wid;
    if (n >= N) return;
    const int J = D >> 6;
    float x[4];
    for (int j = 0; j < J; ++j) x[j] = ldf(X, (size_t)n * D + j * 64 + lane, f);
    for (int h = 0; h < Hh; ++h) {
        float v = 0.f;
        for (int j = 0; j < J; ++j) v += x[j] * qs[h * D + j * 64 + lane];
        #pragma unroll
        for (int o = 32; o > 0; o >>= 1) v += __shfl_down(v, o, 64);
        if (lane == 0) o0[n * Hh + h] = v;
    }
}

// ---------------- fused CSR gather, layer 1 (H=4, D=256) ----------------
template <int MODE>
__global__ __launch_bounds__(256) void gat1(const int* __restrict__ rp,
                                            const unsigned* __restrict__ adj,
                                            const ushort_t* __restrict__ zb,
                                            const float* __restrict__ el,
                                            const float* __restrict__ er,
                                            const float* __restrict__ bias,
                                            ushort_t* __restrict__ H, int N) {
    __shared__ float atl[4][CAP * 4];
    __shared__ int   snl[4][CAP];
    const int w = threadIdx.x >> 6, lane = threadIdx.x & 63;
    const int n = blockIdx.x * 4 + w;
    if (n >= N) return;
    const int h = lane >> 4;
    const int beg = rp[n], deg = rp[n + 1] - beg;
    const float4* el4 = (const float4*)el;
    const float4 ern = ((const float4*)er)[n];

    float4 ss = make_float4(0.f, 0.f, 0.f, 0.f);
    for (int base = 0; base < deg; base += 64) {
        int i = base + lane;
        if (i < deg) {
            unsigned ae = adj[beg + i];
            int sn = ae & 0xFFFF;
            float4 e = el4[sn];
            float x0 = lrelu_exp(e.x + ern.x);
            float x1 = lrelu_exp(e.y + ern.y);
            float x2 = lrelu_exp(e.z + ern.z);
            float x3 = lrelu_exp(e.w + ern.w);
            ss.x += x0; ss.y += x1; ss.z += x2; ss.w += x3;
            if (i < CAP) {
                float ew = bf2f((ushort_t)(ae >> 16));
                float4* dst4 = (float4*)&atl[w][i * 4];
                *dst4 = make_float4(x0 * ew, x1 * ew, x2 * ew, x3 * ew);
                snl[w][i] = sn;
            }
        }
    }
    #pragma unroll
    for (int o = 32; o > 0; o >>= 1) {
        ss.x += __shfl_xor(ss.x, o, 64);
        ss.y += __shfl_xor(ss.y, o, 64);
        ss.z += __shfl_xor(ss.z, o, 64);
        ss.w += __shfl_xor(ss.w, o, 64);
    }
    const float sh = (h == 0) ? ss.x : (h == 1) ? ss.y : (h == 2) ? ss.z : ss.w;
    const float inv = 1.f / (sh + 1e-9f);
    const float erh = (h == 0) ? ern.x : (h == 1) ? ern.y : (h == 2) ? ern.z : ern.w;

    float a0 = 0.f, a1 = 0.f, a2 = 0.f, a3 = 0.f;
    #pragma unroll 4
    for (int i = 0; i < deg; ++i) {
        int sn; float atv;
        if (i < CAP) {
            sn = snl[w][i];
            atv = atl[w][i * 4 + h];
        } else {
            unsigned ae = adj[beg + i];
            sn = ae & 0xFFFF;
            atv = lrelu_exp(el[sn * 4 + h] + erh) * bf2f((ushort_t)(ae >> 16));
        }
        ushort4 zv = *(const ushort4*)(zb + (size_t)sn * HD + lane * 4);
        a0 += bf2f(zv.x) * atv; a1 += bf2f(zv.y) * atv;
        a2 += bf2f(zv.z) * atv; a3 += bf2f(zv.w) * atv;
    }
    float4 b = *(const float4*)(bias + lane * 4);
    a0 = a0 * inv + b.x; a1 = a1 * inv + b.y;
    a2 = a2 * inv + b.z; a3 = a3 * inv + b.w;

    ushort_t* hp = H + (size_t)n * HD + lane * 4;
    ushort4 o;
    if (MODE == 0) {
        o.x = f2bf(a0 > 0.f ? a0 : 0.f); o.y = f2bf(a1 > 0.f ? a1 : 0.f);
        o.z = f2bf(a2 > 0.f ? a2 : 0.f); o.w = f2bf(a3 > 0.f ? a3 : 0.f);
    } else if (MODE == 1) {
        o.x = f2bf(a0 > 0.f ? a0 : expm1f(a0)); o.y = f2bf(a1 > 0.f ? a1 : expm1f(a1));
        o.z = f2bf(a2 > 0.f ? a2 : expm1f(a2)); o.w = f2bf(a3 > 0.f ? a3 : expm1f(a3));
    } else {
        ushort4 hw = *(const ushort4*)hp;
        float v0 = (bf2f(hw.x) + (a0 > 0.f ? a0 : expm1f(a0))) * 0.5f;
        float v1 = (bf2f(hw.y) + (a1 > 0.f ? a1 : expm1f(a1))) * 0.5f;
        float v2 = (bf2f(hw.z) + (a2 > 0.f ? a2 : expm1f(a2))) * 0.5f;
        float v3 = (bf2f(hw.w) + (a3 > 0.f ? a3 : expm1f(a3))) * 0.5f;
        o.x = f2bf(v0 > 0.f ? v0 : 0.f); o.y = f2bf(v1 > 0.f ? v1 : 0.f);
        o.z = f2bf(v2 > 0.f ? v2 : 0.f); o.w = f2bf(v3 > 0.f ? v3 : 0.f);
    }
    *(ushort4*)hp = o;
}

// ---------------- fused CSR gather layer 2 over 3 segments ----------------
// seg 0 (tic): out = a + b2t -> d_out ; seg 1 (w): ACCw = a ; seg 2 (rel): ACCr = a
struct GA2 {
    const int* rp[3]; const ushort_t* zc[3]; const float* el[3]; const float* er[3];
    int N[3]; int b1, b2;
};
__global__ __launch_bounds__(256) void gat2_all(GA2 t, const unsigned* __restrict__ adj,
                                                const float* __restrict__ b2t,
                                                float* __restrict__ ACCw,
                                                float* __restrict__ ACCr,
                                                void* __restrict__ out,
                                                const int* __restrict__ flagp) {
    __shared__ float atl[4][CAP];
    __shared__ int   snl[4][CAP];
    int s, b;
    if (blockIdx.x < (unsigned)t.b1) { s = 0; b = blockIdx.x; }
    else if (blockIdx.x < (unsigned)t.b2) { s = 1; b = blockIdx.x - t.b1; }
    else { s = 2; b = blockIdx.x - t.b2; }
    const int w = threadIdx.x >> 6, lane = threadIdx.x & 63;
    const int n = b * 4 + w;
    if (n >= t.N[s]) return;
    const int* rp = t.rp[s];
    const float* el = t.el[s];
    const ushort_t* zb = t.zc[s];
    const int beg = rp[n], deg = rp[n + 1] - beg;
    const float ern = t.er[s][n];

    float ssum = 0.f;
    for (int base = 0; base < deg; base += 64) {
        int i = base + lane;
        if (i < deg) {
            unsigned ae = adj[beg + i];
            int sn = ae & 0xFFFF;
            float x = lrelu_exp(el[sn] + ern);
            ssum += x;
            if (i < CAP) {
                atl[w][i] = x * bf2f((ushort_t)(ae >> 16));
                snl[w][i] = sn;
            }
        }
    }
    #pragma unroll
    for (int o = 32; o > 0; o >>= 1) ssum += __shfl_xor(ssum, o, 64);
    const float inv = 1.f / (ssum + 1e-9f);

    float a = 0.f;
    #pragma unroll 4
    for (int i = 0; i < deg; ++i) {
        int sn; float atv;
        if (i < CAP) {
            sn = snl[w][i];
            atv = atl[w][i];
        } else {
            unsigned ae = adj[beg + i];
            sn = ae & 0xFFFF;
            atv = lrelu_exp(el[sn] + ern) * bf2f((ushort_t)(ae >> 16));
        }
        a += bf2f(zb[(size_t)sn * DOUT + lane]) * atv;
    }
    a *= inv;

    if (s == 0) {
        float v = a + b2t[lane];
        size_t o = (size_t)n * DOUT + lane;
        if (flagp[0]) ((float*)out)[o] = v;
        else ((ushort_t*)out)[o] = f2bf(v);
    } else if (s == 1) {
        ACCw[(size_t)n * DOUT + lane] = a;
    } else {
        ACCr[(size_t)n * DOUT + lane] = a;
    }
}

__global__ __launch_bounds__(256) void out_word(const float* __restrict__ aw,
                                                const float* __restrict__ bw,
                                                const float* __restrict__ ar_,
                                                const float* __restrict__ br,
                                                void* __restrict__ out,
                                                const int* __restrict__ flagp, int total) {
    int i = blockIdx.x * 256 + threadIdx.x;
    if (i >= total) return;
    int c = i & 63;
    float v = ((aw[i] + bw[c]) + (ar_[i] + br[c])) * 0.5f;
    size_t o = (size_t)N_AC * DOUT + i;
    if (flagp[0]) ((float*)out)[o] = v;
    else ((ushort_t*)out)[o] = f2bf(v);
}

// ---------------- host launch ----------------
extern "C" void kernel_launch(void* const* d_in, const int* in_sizes, int n_in,
                              void* d_out, int out_size, void* d_ws, size_t ws_size,
                              hipStream_t stream) {
    (void)in_sizes; (void)n_in; (void)out_size; (void)ws_size;

    const void* x_ac = d_in[0];
    const void* x_w  = d_in[1];
    const void* ew_tic = d_in[2];
    const void* ew_w   = d_in[3];
    const void* ew_rel = d_in[4];
    const int* src_tic = (const int*)d_in[29];
    const int* dst_tic = (const int*)d_in[30];
    const int* src_w   = (const int*)d_in[31];
    const int* dst_w   = (const int*)d_in[32];
    const int* src_rel = (const int*)d_in[33];
    const int* dst_rel = (const int*)d_in[34];

    float* ws = (float*)d_ws;
    int* FLAG = (int*)ws;

    float* PAR = ws + 16;
    const int o_W1t = 1000000, o_W1w = 1032768, o_W1r = 1065536;
    const int o_W2t = 1098304, o_W2w = 1114688, o_W2r = 1131072;
    const int o_al1t = 1147456, o_ar1t = 1147712, o_al1w = 1147968, o_ar1w = 1148224,
              o_al1r = 1148480, o_ar1r = 1148736;
    const int o_b1t = 1148992, o_b1w = 1149248, o_b1r = 1149504;
    const int o_al2t = 1149760, o_ar2t = 1149824, o_al2w = 1149888, o_ar2w = 1149952,
              o_al2r = 1150016, o_ar2r = 1150080;
    const int o_b2t = 1150144, o_b2w = 1150208, o_b2r = 1150272;
    const int o_qer1r = 1150400, o_qer2r = 1150912;

    float* EB   = ws + 1160016;
    float* ELt  = EB;
    float* ERt  = EB + 160000;
    float* ELw  = EB + 320000;
    float* ERw  = EB + 400000;
    float* ELr  = EB + 480000;
    float* ERr  = EB + 640000;
    float* E2tl = EB + 720000;
    float* E2tr = EB + 760000;
    float* E2wl = EB + 800000;
    float* E2wr = EB + 820000;
    float* E2rl = EB + 840000;
    float* E2rr = EB + 880000;
    float* ACC = ws + 2060016;                   // 1,280,000 (ACCw)
    ushort_t* Zb  = (ushort_t*)(ws + 3340016);   // 10.24M bf16
    ushort_t* Hac = (ushort_t*)(ws + 8460016);   // 40000x256 bf16
    ushort_t* Hw  = (ushort_t*)(ws + 13580016);  // 20000x256 bf16
    ushort_t* WT  = (ushort_t*)(ws + 16140016);  // 147456 bf16
    const int t_W1t = 0, t_W1w = 32768, t_W1r = 65536,
              t_W2t = 98304, t_W2w = 114688, t_W2r = 131072;
    int* IB = (int*)(ws + 16213760);
    int* rp   = IB;                              // N_ALL + 1
    int* cnt  = IB + 80064;                      // N_ALL
    int* bsum = IB + 160128;                     // 512
    unsigned* adj = (unsigned*)(IB + 160704);    // E_ALL x 4B
    int* rank = IB + 1160704;                    // E_ALL
    float* ACCr = ws + 18374464;                 // 1,280,000
    // end: ws + 19,654,464 floats = 78.6 MB

    // layer-2 z buffers inside Zb region
    ushort_t* Zc_tic = Zb;                       // 40000*64
    ushort_t* Zc_w   = Zb + 2560000;             // 20000*64
    ushort_t* Zc_r   = Zb + 3840000;             // 40000*64

    // ---- P0: dtype, params, q vectors, packed W^T ----
    detect_dtype<<<1, 256, 0, stream>>>((const ushort_t*)x_ac, FLAG);

    CvtTab ct;
    const int srcIdx[24] = {5,6,7,8, 9,10,11,12, 13,14,15,16,
                            17,18,19,20, 21,22,23,24, 25,26,27,28};
    const int sizes[24] = {32768,256,256,256, 32768,256,256,256, 32768,256,256,256,
                           16384,64,64,64, 16384,64,64,64, 16384,64,64,64};
    const int offs[24] = {o_W1t,o_al1t,o_ar1t,o_b1t, o_W1w,o_al1w,o_ar1w,o_b1w,
                          o_W1r,o_al1r,o_ar1r,o_b1r,
                          o_W2t,o_al2t,o_ar2t,o_b2t, o_W2w,o_al2w,o_ar2w,o_b2w,
                          o_W2r,o_al2r,o_ar2r,o_b2r};
    for (int i = 0; i < 24; ++i) { ct.src[i] = d_in[srcIdx[i]]; ct.n[i] = sizes[i]; ct.off[i] = offs[i]; }
    cvt_inputs<<<24 * 8, 256, 0, stream>>>(ct, PAR, FLAG);

    QTab qt;
    qt.woff[0] = o_W1r; qt.aoff[0] = o_ar1r; qt.qoff[0] = o_qer1r; qt.K[0] = 128; qt.Hh[0] = 4;
    qt.woff[1] = o_W2r; qt.aoff[1] = o_ar2r; qt.qoff[1] = o_qer2r; qt.K[1] = 256; qt.Hh[1] = 1;
    make_q<<<2, 256, 0, stream>>>(qt, PAR);

    PTab pt;
    const int pw[6] = {o_W1t, o_W1w, o_W1r, o_W2t, o_W2w, o_W2r};
    const int ptf[6] = {t_W1t, t_W1w, t_W1r, t_W2t, t_W2w, t_W2r};
    for (int i = 0; i < 6; ++i) {
        pt.woff[i] = pw[i]; pt.toff[i] = ptf[i];
        pt.Klog[i] = (i < 3) ? 7 : 8; pt.N[i] = (i < 3) ? 256 : 64;
    }
    pack_wt<<<6 * 16, 256, 0, stream>>>(pt, PAR, WT);

    // ---- P0b: merged CSR build ----
    {
        const int B = (N_ALL + 255) / 256;   // 313
        hipMemsetAsync(cnt, 0, N_ALL * 4, stream);
        count3<<<(E_ALL + 255) / 256, 256, 0, stream>>>(dst_tic, dst_w, dst_rel, cnt, rank);
        scan_bsum<<<B, 256, 0, stream>>>(cnt, bsum, N_ALL);
        scan_top<<<1, 512, 0, stream>>>(bsum, B);
        scan_out<<<B, 256, 0, stream>>>(cnt, bsum, rp, N_ALL);
        fill3<<<8 * ((E_ALL + FCH - 1) / FCH), 256, 0, stream>>>(
            src_tic, dst_tic, ew_tic, src_w, dst_w, ew_w, src_rel, dst_rel, ew_rel,
            FLAG, rp, rank, adj);
    }
    const int* rp_tic = rp;
    const int* rp_w   = rp + N_AC;
    const int* rp_rel = rp + N_AC + N_W;

    // rel-dst er for layer 1
    elr1<<<N_W / 4, 256, 0, stream>>>(x_w, FLAG, PAR + o_qer1r, ERr, N_W, 128, 4);

    // ---- layer 1 ----
    mgemm1<<<N_AC / 16, 256, 0, stream>>>(x_ac, FLAG, WT + t_W1t, Zb,
                                          PAR + o_al1t, PAR + o_ar1t, ELt, ERt, N_AC);
    gat1<0><<<N_AC / 4, 256, 0, stream>>>(rp_tic, adj, Zb, ELt, ERt, PAR + o_b1t, Hac, N_AC);

    mgemm1<<<N_W / 16, 256, 0, stream>>>(x_w, FLAG, WT + t_W1w, Zb,
                                         PAR + o_al1w, PAR + o_ar1w, ELw, ERw, N_W);
    gat1<1><<<N_W / 4, 256, 0, stream>>>(rp_w, adj, Zb, ELw, ERw, PAR + o_b1w, Hw, N_W);

    mgemm1<<<N_AC / 16, 256, 0, stream>>>(x_ac, FLAG, WT + t_W1r, Zb,
                                          PAR + o_al1r, nullptr, ELr, nullptr, N_AC);
    gat1<2><<<N_W / 4, 256, 0, stream>>>(rp_rel, adj, Zb, ELr, ERr, PAR + o_b1r, Hw, N_W);

    // rel-dst er for layer 2
    elr1<<<N_W / 4, 256, 0, stream>>>(Hw, nullptr, PAR + o_qer2r, E2rr, N_W, 256, 1);

    // ---- layer 2: fused GEMMs ----
    G2 g2;
    g2.Hb[0] = Hac; g2.Hb[1] = Hw; g2.Hb[2] = Hac;
    g2.WT[0] = WT + t_W2t; g2.WT[1] = WT + t_W2w; g2.WT[2] = WT + t_W2r;
    g2.Zc[0] = Zc_tic; g2.Zc[1] = Zc_w; g2.Zc[2] = Zc_r;
    g2.al[0] = PAR + o_al2t; g2.al[1] = PAR + o_al2w; g2.al[2] = PAR + o_al2r;
    g2.ar[0] = PAR + o_ar2t; g2.ar[1] = PAR + o_ar2w; g2.ar[2] = nullptr;
    g2.el[0] = E2tl; g2.el[1] = E2wl; g2.el[2] = E2rl;
    g2.er[0] = E2tr; g2.er[1] = E2wr; g2.er[2] = nullptr;
    g2.N[0] = N_AC; g2.N[1] = N_W; g2.N[2] = N_AC;
    const int nb0 = (N_AC + 63) / 64, nb1 = (N_W + 63) / 64, nb2 = (N_AC + 63) / 64;
    g2.b1 = nb0; g2.b2 = nb0 + nb1;
    mgemm2_all<<<nb0 + nb1 + nb2, 256, 0, stream>>>(g2);

    // ---- layer 2: fused gathers + word combine ----
    GA2 ga;
    ga.rp[0] = rp_tic; ga.rp[1] = rp_w; ga.rp[2] = rp_rel;
    ga.zc[0] = Zc_tic; ga.zc[1] = Zc_w; ga.zc[2] = Zc_r;
    ga.el[0] = E2tl; ga.el[1] = E2wl; ga.el[2] = E2rl;
    ga.er[0] = E2tr; ga.er[1] = E2wr; ga.er[2] = E2rr;
    ga.N[0] = N_AC; ga.N[1] = N_W; ga.N[2] = N_W;
    const int gb0 = N_AC / 4, gb1 = N_W / 4, gb2 = N_W / 4;
    ga.b1 = gb0; ga.b2 = gb0 + gb1;
    gat2_all<<<gb0 + gb1 + gb2, 256, 0, stream>>>(ga, adj, PAR + o_b2t, ACC, ACCr, d_out, FLAG);

    out_word<<<(N_W * DOUT) / 256, 256, 0, stream>>>(ACC, PAR + o_b2w, ACCr, PAR + o_b2r,
                                                     d_out, FLAG, N_W * DOUT);
}